// Round 8
// baseline (877.304 us; speedup 1.0000x reference)
//
#include <hip/hip_runtime.h>
#include <hip/hip_bf16.h>
#include <math.h>

typedef unsigned short u16;
typedef unsigned int   u32;
typedef short v8s __attribute__((ext_vector_type(8)));
typedef float v4f __attribute__((ext_vector_type(4)));
#define DEV static __device__ __forceinline__

DEV float u2f(u16 u){ union{u32 i; float f;} v; v.i = ((u32)u)<<16; return v.f; }
DEV u16   f2u(float f){ union{float ff; u32 i;} v; v.ff = f; u32 r = v.i + 0x7fffu + ((v.i>>16)&1u); return (u16)(r>>16); }
DEV float lrelu02(float x){ return x > 0.f ? x : 0.2f*x; }
DEV float lrelu01(float x){ return x > 0.f ? x : 0.01f*x; }
DEV float wred_max(float v){
  #pragma unroll
  for (int o = 32; o > 0; o >>= 1) v = fmaxf(v, __shfl_xor(v, o, 64));
  return v;
}
DEV float wred_sum(float v){
  #pragma unroll
  for (int o = 32; o > 0; o >>= 1) v += __shfl_xor(v, o, 64);
  return v;
}

constexpr int B_   = 8;
constexpr int P_   = 32;
constexpr int N0_  = 10000;
constexpr int NODES = B_ * N0_;      // 80000
constexpr int E_   = 160000;
constexpr int NE_  = E_ + N0_;       // 170000

// ---------------- utility ----------------
__global__ void k_zero(int* __restrict__ p, int n){
  int i = blockIdx.x*blockDim.x + threadIdx.x;
  if (i < n) p[i] = 0;
}

// weight transpose+cast: dst[n][k] (bf16, padded) from src[k][n] (f32)
__global__ void k_wt(u16* __restrict__ dst, const float* __restrict__ src,
                     int NR, int NKp, int Nsrc, int Klim, int mode){
  int i = blockIdx.x*blockDim.x + threadIdx.x;
  if (i >= NR*NKp) return;
  int n = i / NKp, k = i - n*NKp;
  float v = 0.f;
  if (n < Nsrc){
    if (mode == 0){ if (k < Klim) v = src[(size_t)k*Nsrc + n]; }
    else {
      if (k < 136) v = src[(size_t)k*Nsrc + n];
      else if (k >= 160 && k < 296) v = src[(size_t)(k-24)*Nsrc + n];
    }
  }
  dst[i] = f2u(v);
}

// attention linearity vectors: asrc(h1)=feat·(W1 a);  asrc2(h2)=g1·(W2 a2)
__global__ void k_va(const float* __restrict__ W1, const float* __restrict__ as1, const float* __restrict__ ad1,
                     const float* __restrict__ W2, const float* __restrict__ as2, const float* __restrict__ ad2,
                     float* __restrict__ va1s, float* __restrict__ va1d,
                     float* __restrict__ va2s, float* __restrict__ va2d){
  int t = blockIdx.x*blockDim.x + threadIdx.x;
  if (t >= 272) return;
  int hh = t / 136, k = t - hh*136;
  float s = 0.f, d = 0.f;
  for (int c = 0; c < 136; c++){
    float w = W1[(size_t)k*272 + hh*136 + c];
    s = fmaf(w, as1[hh*136 + c], s);
    d = fmaf(w, ad1[hh*136 + c], d);
  }
  va1s[t] = s; va1d[t] = d;                 // layout [hh*136 + k]
  float s2 = 0.f, d2 = 0.f;
  for (int c = 0; c < 136; c++){
    float w = W2[(size_t)t*136 + c];
    s2 = fmaf(w, as2[c], s2);
    d2 = fmaf(w, ad2[c], d2);
  }
  va2s[t] = s2; va2d[t] = d2;
}

// ---------------- backbone ----------------
DEV void load_convw(float* lw, const float* wl1, const float* wl2, const float* wp1,
                    const float* wp2, const float* wg, int tid, int nth){
  for (int i = tid; i < 384; i += nth){
    float v;
    if      (i < 24)  v = wl1[i];
    else if (i < 64)  v = wl2[i-24];
    else if (i < 88)  v = wp1[i-64];
    else if (i < 128) v = wp2[i-88];
    else              v = wg [i-128];
    lw[i] = v;
  }
}

template<int KS,int DIL,int T>
DEV void conv_stats(const float* xc, const float* wk, float& s, float& q){
  #pragma unroll
  for (int t = 0; t < T; t++){
    float v = 0.f;
    #pragma unroll
    for (int j = 0; j < KS; j++) v = fmaf(wk[j], xc[t + j*DIL], v);
    s += v; q = fmaf(v, v, q);
  }
}

__global__ void __launch_bounds__(256) k_bn_stats(
    const float* __restrict__ x,
    const float* __restrict__ wl1, const float* __restrict__ wl2,
    const float* __restrict__ wp1, const float* __restrict__ wp2,
    const float* __restrict__ wg,
    float* __restrict__ gsum, float* __restrict__ gsq)
{
  __shared__ float lw[384];
  __shared__ float lacc[80];
  const int tid = threadIdx.x;
  load_convw(lw, wl1, wl2, wp1, wp2, wg, tid, 256);
  if (tid < 80) lacc[tid] = 0.f;
  __syncthreads();

  int gid = blockIdx.x*256 + tid;
  float xc[P_];
  if (gid < NODES){
    int b = gid / N0_, n = gid - b*N0_;
    const float* xp = x + (size_t)b*P_*N0_ + n;
    #pragma unroll
    for (int p = 0; p < P_; p++) xc[p] = xp[(size_t)p*N0_];
  } else {
    #pragma unroll
    for (int p = 0; p < P_; p++) xc[p] = 0.f;
  }
  const int lane = tid & 63;

  auto red = [&](int ch, float s, float q){
    #pragma unroll
    for (int o = 32; o > 0; o >>= 1){ s += __shfl_down(s,o,64); q += __shfl_down(q,o,64); }
    if (lane == 0){ atomicAdd(&lacc[ch], s); atomicAdd(&lacc[40+ch], q); }
  };

  #pragma unroll
  for (int k = 0; k < 8; k++){ float s=0,q=0; conv_stats<3,1,30>(xc, lw      + k*3 , s,q); red(k,     s,q); }
  #pragma unroll
  for (int k = 0; k < 8; k++){ float s=0,q=0; conv_stats<5,1,28>(xc, lw + 24 + k*5 , s,q); red(8+k,   s,q); }
  #pragma unroll
  for (int k = 0; k < 8; k++){ float s=0,q=0; conv_stats<3,2,28>(xc, lw + 64 + k*3 , s,q); red(16+k,  s,q); }
  #pragma unroll
  for (int k = 0; k < 8; k++){ float s=0,q=0; conv_stats<5,2,24>(xc, lw + 88 + k*5 , s,q); red(24+k,  s,q); }
  #pragma unroll
  for (int k = 0; k < 8; k++){ float s=0,q=0; conv_stats<32,1,1>(xc, lw + 128+ k*32, s,q); red(32+k,  s,q); }

  __syncthreads();
  if (tid < 40)      atomicAdd(&gsum[tid],    lacc[tid]);
  else if (tid < 80) atomicAdd(&gsq [tid-40], lacc[tid]);
}

__global__ void k_bn_fin(const float* __restrict__ gsum, const float* __restrict__ gsq,
                         float* __restrict__ sA, float* __restrict__ sB,
                         const float* g0, const float* g1, const float* g2, const float* g3, const float* g4,
                         const float* e0, const float* e1, const float* e2, const float* e3, const float* e4)
{
  int t = threadIdx.x;
  if (t >= 40) return;
  int bi = t >> 3, k = t & 7;
  const int Ts[5] = {30,28,28,24,1};
  float cnt  = (float)NODES * (float)Ts[bi];
  float mean = gsum[t] / cnt;
  float var  = gsq[t] / cnt - mean*mean;
  const float* gp = bi==0?g0: bi==1?g1: bi==2?g2: bi==3?g3: g4;
  const float* ep = bi==0?e0: bi==1?e1: bi==2?e2: bi==3?e3: e4;
  float a = gp[k] * rsqrtf(fmaxf(var, 0.f) + 1e-5f);
  sA[t] = a;
  sB[t] = ep[k] - a*mean;
}

template<int KS,int DIL,int T>
DEV void conv_pool4(const float* xc, const float* wk, float A, float Bc, float* o4){
  float y[T];
  #pragma unroll
  for (int t = 0; t < T; t++){
    float v = 0.f;
    #pragma unroll
    for (int j = 0; j < KS; j++) v = fmaf(wk[j], xc[t + j*DIL], v);
    y[t] = fmaf(A, v, Bc);
  }
  #pragma unroll
  for (int i = 0; i < 4; i++){
    const int lo = (i*T)/4, hi = ((i+1)*T + 3)/4;
    float m = y[lo];
    #pragma unroll
    for (int t = 0; t < T; t++){ if (t > lo && t < hi) m = fmaxf(m, y[t]); }
    o4[i] = m;
  }
}

// writes feat row-major [m][160] bf16 (tanh applied) + fused layer-1 attention dots
__global__ void __launch_bounds__(256) k_feat(
    const float* __restrict__ x,
    const float* __restrict__ wl1, const float* __restrict__ wl2,
    const float* __restrict__ wp1, const float* __restrict__ wp2,
    const float* __restrict__ wg,
    const float* __restrict__ sA, const float* __restrict__ sB,
    const float* __restrict__ va1s, const float* __restrict__ va1d,
    u16* __restrict__ feat, float* __restrict__ asrc1, float* __restrict__ adst1,
    int base, int m)
{
  __shared__ float lw[384];
  __shared__ float lA[40], lB[40];
  const int tid = threadIdx.x;
  load_convw(lw, wl1, wl2, wp1, wp2, wg, tid, 256);
  if (tid < 40){ lA[tid] = sA[tid]; lB[tid] = sB[tid]; }
  __syncthreads();

  int gid = blockIdx.x*256 + tid;
  if (gid >= m) return;
  int g = base + gid;
  int b = g / N0_, n = g - b*N0_;
  float xc[P_];
  const float* xp = x + (size_t)b*P_*N0_ + n;
  #pragma unroll
  for (int p = 0; p < P_; p++) xc[p] = xp[(size_t)p*N0_];

  u32 pk[4];
  float dt[4] = {0.f,0.f,0.f,0.f};       // s0,d0,s1,d1
  u16* orow = feat + (size_t)gid*160;
  auto emit = [&](int ch, float v){
    float t = tanhf(v);
    dt[0] = fmaf(t, va1s[ch],     dt[0]);
    dt[1] = fmaf(t, va1d[ch],     dt[1]);
    dt[2] = fmaf(t, va1s[136+ch], dt[2]);
    dt[3] = fmaf(t, va1d[136+ch], dt[3]);
    u16 h = f2u(t);
    int s = ch & 7;
    if ((s & 1) == 0) pk[s>>1] = h;
    else              pk[s>>1] |= ((u32)h) << 16;
    if (s == 7) *(uint4*)(orow + (ch - 7)) = make_uint4(pk[0],pk[1],pk[2],pk[3]);
  };

  float o4[4];
  #pragma unroll
  for (int k = 0; k < 8; k++){
    conv_pool4<3,1,30>(xc, lw + k*3, lA[k], lB[k], o4);
    #pragma unroll
    for (int i = 0; i < 4; i++) emit(k*4+i, o4[i]);
  }
  #pragma unroll
  for (int k = 0; k < 8; k++){
    conv_pool4<5,1,28>(xc, lw + 24 + k*5, lA[8+k], lB[8+k], o4);
    #pragma unroll
    for (int i = 0; i < 4; i++) emit(32 + k*4+i, o4[i]);
  }
  #pragma unroll
  for (int k = 0; k < 8; k++){
    conv_pool4<3,2,28>(xc, lw + 64 + k*3, lA[16+k], lB[16+k], o4);
    #pragma unroll
    for (int i = 0; i < 4; i++) emit(64 + k*4+i, o4[i]);
  }
  #pragma unroll
  for (int k = 0; k < 8; k++){
    conv_pool4<5,2,24>(xc, lw + 88 + k*5, lA[24+k], lB[24+k], o4);
    #pragma unroll
    for (int i = 0; i < 4; i++) emit(96 + k*4+i, o4[i]);
  }
  #pragma unroll
  for (int k = 0; k < 8; k++){
    float v = 0.f;
    #pragma unroll
    for (int j = 0; j < 32; j++) v = fmaf(lw[128 + k*32 + j], xc[j], v);
    emit(128 + k, fmaf(lA[32+k], v, lB[32+k]));
  }
  asrc1[(size_t)gid*2]   = dt[0];
  asrc1[(size_t)gid*2+1] = dt[2];
  adst1[(size_t)gid*2]   = dt[1];
  adst1[(size_t)gid*2+1] = dt[3];
}

// ---------------- CSR ----------------
__global__ void k_count(const int* __restrict__ ei, int* __restrict__ counts){
  int e = blockIdx.x*blockDim.x + threadIdx.x;
  if (e >= NE_) return;
  int dst = (e < E_) ? ei[E_ + e] : (e - E_);
  atomicAdd(&counts[dst], 1);
}

__global__ void __launch_bounds__(1024) k_scan(const int* __restrict__ counts, int* __restrict__ offs){
  __shared__ int part[1024];
  int t = threadIdx.x;
  int loc[10]; int s = 0;
  #pragma unroll
  for (int i = 0; i < 10; i++){
    int idx = t*10 + i;
    int c = (idx < N0_) ? counts[idx] : 0;
    loc[i] = s; s += c;
  }
  part[t] = s;
  __syncthreads();
  for (int o = 1; o < 1024; o <<= 1){
    int v = (t >= o) ? part[t-o] : 0;
    __syncthreads();
    part[t] += v;
    __syncthreads();
  }
  int pre = (t == 0) ? 0 : part[t-1];
  #pragma unroll
  for (int i = 0; i < 10; i++){
    int idx = t*10 + i;
    if (idx < N0_) offs[idx] = pre + loc[i];
  }
  if (t == 0) offs[N0_] = part[1023];
}

__global__ void k_scatter(const int* __restrict__ ei, const int* __restrict__ offs,
                          int* __restrict__ cursor, int* __restrict__ srcl){
  int e = blockIdx.x*blockDim.x + threadIdx.x;
  if (e >= NE_) return;
  int src, dst;
  if (e < E_){ src = ei[e]; dst = ei[E_ + e]; } else { src = dst = e - E_; }
  int pos = atomicAdd(&cursor[dst], 1);
  srcl[offs[dst] + pos] = src;
}

// ---------------- MFMA GEMM: A[m][K] bf16 row-major, BT[n][K] bf16 ----------------
// EPI 0: C bf16 plain; EPI 1: C bf16 lrelu01(+bias); EPI 2: fused head — out[r] = Σ_col lrelu01(acc+bias)*w2v + bo2
template<int KT1,int KT2,int NT,int EPI>
__global__ void __launch_bounds__(256) k_mfma(
    const u16* __restrict__ A1, int sA1,
    const u16* __restrict__ A2, int sA2,
    const u16* __restrict__ BT, int sBT,
    u16* __restrict__ C, int sC, int nbase,
    const float* __restrict__ bias, int m,
    const float* __restrict__ w2v, const float* __restrict__ bo2p, float* __restrict__ fout)
{
  const int wv = threadIdx.x >> 6, lane = threadIdx.x & 63;
  const int quad = lane >> 4, l15 = lane & 15;
  const int mb = blockIdx.x*256 + wv*64;
  int ar[4];
  #pragma unroll
  for (int mt = 0; mt < 4; mt++) ar[mt] = min(mb + mt*16 + l15, m-1);

  v4f acc[4][NT];
  #pragma unroll
  for (int mt = 0; mt < 4; mt++)
    #pragma unroll
    for (int nt = 0; nt < NT; nt++)
      acc[mt][nt] = (v4f){0.f,0.f,0.f,0.f};

  for (int kt = 0; kt < KT1+KT2; kt++){
    const u16* ab; int sA, koff;
    if (KT2 == 0 || kt < KT1){ ab = A1; sA = sA1; koff = kt*32; }
    else { ab = A2; sA = sA2; koff = (kt-KT1)*32; }
    v8s a[4];
    #pragma unroll
    for (int mt = 0; mt < 4; mt++)
      a[mt] = *(const v8s*)(ab + (size_t)ar[mt]*sA + koff + quad*8);
    if (KT2 > 0 && kt >= KT1){
      #pragma unroll
      for (int mt = 0; mt < 4; mt++)
        #pragma unroll
        for (int j = 0; j < 8; j++){
          float f = u2f((u16)a[mt][j]);
          f = f > 0.f ? f : 0.01f*f;
          a[mt][j] = (short)f2u(f);
        }
    }
    const int kb = kt*32 + quad*8;
    #pragma unroll
    for (int nt = 0; nt < NT; nt++){
      v8s b = *(const v8s*)(BT + (size_t)(nbase + nt*16 + l15)*sBT + kb);
      #pragma unroll
      for (int mt = 0; mt < 4; mt++)
        acc[mt][nt] = __builtin_amdgcn_mfma_f32_16x16x32_bf16(a[mt], b, acc[mt][nt], 0, 0, 0);
    }
  }

  if (EPI == 2){
    const float bo2v = bo2p[0];
    #pragma unroll
    for (int mt = 0; mt < 4; mt++){
      float part[4] = {0.f,0.f,0.f,0.f};
      #pragma unroll
      for (int nt = 0; nt < NT; nt++){
        const int col = nt*16 + l15;
        float wv2 = (col < 136) ? w2v[col] : 0.f;
        float bv  = bias[min(col,135)];
        #pragma unroll
        for (int i = 0; i < 4; i++){
          float xv = lrelu01(acc[mt][nt][i] + bv);
          part[i] = fmaf(xv, wv2, part[i]);
        }
      }
      #pragma unroll
      for (int i = 0; i < 4; i++){
        float v = part[i];
        v += __shfl_xor(v, 1, 64);
        v += __shfl_xor(v, 2, 64);
        v += __shfl_xor(v, 4, 64);
        v += __shfl_xor(v, 8, 64);
        int r = mb + mt*16 + quad*4 + i;
        if (l15 == 0 && r < m) fout[r] = v + bo2v;
      }
    }
    return;
  }

  #pragma unroll
  for (int mt = 0; mt < 4; mt++){
    const int r0 = mb + mt*16 + quad*4;
    #pragma unroll
    for (int nt = 0; nt < NT; nt++){
      const int col = nbase + nt*16 + l15;
      #pragma unroll
      for (int i = 0; i < 4; i++){
        int r = r0 + i;
        if (r < m){
          float xv = acc[mt][nt][i];
          if (EPI == 1){ xv += bias[min(col,135)]; xv = lrelu01(xv); }
          C[(size_t)r*sC + col] = f2u(xv);
        }
      }
    }
  }
}

// ---------------- GAT aggregation: one wave per (dst,b), XCD-swizzled, unroll-2 ----------------
// ATTN=1: also compute next-layer attention dots (asrc2/adst2) from the output row
template<int H,int CT,int LACT,int ATTN>
__global__ void __launch_bounds__(256) k_agg(const u16* __restrict__ h, int sh,
    const float* __restrict__ asrc, const float* __restrict__ adst,
    const int* __restrict__ offs, const int* __restrict__ srcl,
    const float* __restrict__ bias, u16* __restrict__ outp0, int so,
    const float* __restrict__ vas, const float* __restrict__ vad,
    float* __restrict__ as_out, float* __restrict__ ad_out,
    int cbMask, int cbShift)
{
  constexpr int CC   = CT/H;
  constexpr int VEC  = (CT >= 256) ? 4 : 2;
  constexpr int MAINC= 64*VEC;
  constexpr int REMV = (CT - MAINC)/VEC;

  const int wv = threadIdx.x >> 6, lane = threadIdx.x & 63;
  const int id = blockIdx.x;
  const int bb = id & cbMask;           // batch -> XCD locality
  const int dst = (id >> cbShift)*4 + wv;
  const int nbase = bb*N0_;
  const int node = nbase + dst;
  const int start = offs[dst], end = offs[dst+1];
  const int ne = end - start;

  float adh[H];
  #pragma unroll
  for (int hh = 0; hh < H; hh++) adh[hh] = adst[(size_t)node*H + hh];

  float accm[VEC], accr[VEC];
  #pragma unroll
  for (int i = 0; i < VEC; i++){ accm[i] = 0.f; accr[i] = 0.f; }

  const bool hi = (H == 2) && (VEC*lane >= CC);

  auto acc_edge = [&](int sj, float c0, float c1){
    const u16* hp = h + (size_t)sj*sh;
    float w  = hi ? c1 : c0;
    float wr = (H == 2) ? c1 : c0;
    if (VEC == 4){
      const ushort4 hv = *(const ushort4*)(hp + 4*lane);
      accm[0] = fmaf(w, u2f(hv.x), accm[0]);
      accm[1] = fmaf(w, u2f(hv.y), accm[1]);
      accm[2] = fmaf(w, u2f(hv.z), accm[2]);
      accm[3] = fmaf(w, u2f(hv.w), accm[3]);
      if (lane < REMV){
        const ushort4 hr = *(const ushort4*)(hp + MAINC + 4*lane);
        accr[0] = fmaf(wr, u2f(hr.x), accr[0]);
        accr[1] = fmaf(wr, u2f(hr.y), accr[1]);
        accr[2] = fmaf(wr, u2f(hr.z), accr[2]);
        accr[3] = fmaf(wr, u2f(hr.w), accr[3]);
      }
    } else {
      const ushort2 hv = *(const ushort2*)(hp + 2*lane);
      accm[0] = fmaf(w, u2f(hv.x), accm[0]);
      accm[1] = fmaf(w, u2f(hv.y), accm[1]);
      if (lane < REMV){
        const ushort2 hr = *(const ushort2*)(hp + MAINC + 2*lane);
        accr[0] = fmaf(wr, u2f(hr.x), accr[0]);
        accr[1] = fmaf(wr, u2f(hr.y), accr[1]);
      }
    }
  };

  // paired version: both loads issued before the FMA chains (static, ILP=2)
  auto acc_edge2 = [&](int sj0, float c00, float c10, int sj1, float c01, float c11){
    const u16* hp0 = h + (size_t)sj0*sh;
    const u16* hp1 = h + (size_t)sj1*sh;
    float w0  = hi ? c10 : c00;
    float w1  = hi ? c11 : c01;
    float wr0 = (H == 2) ? c10 : c00;
    float wr1 = (H == 2) ? c11 : c01;
    if (VEC == 4){
      const ushort4 a0 = *(const ushort4*)(hp0 + 4*lane);
      const ushort4 a1 = *(const ushort4*)(hp1 + 4*lane);
      accm[0] = fmaf(w0, u2f(a0.x), accm[0]);
      accm[1] = fmaf(w0, u2f(a0.y), accm[1]);
      accm[2] = fmaf(w0, u2f(a0.z), accm[2]);
      accm[3] = fmaf(w0, u2f(a0.w), accm[3]);
      accm[0] = fmaf(w1, u2f(a1.x), accm[0]);
      accm[1] = fmaf(w1, u2f(a1.y), accm[1]);
      accm[2] = fmaf(w1, u2f(a1.z), accm[2]);
      accm[3] = fmaf(w1, u2f(a1.w), accm[3]);
      if (lane < REMV){
        const ushort4 r0 = *(const ushort4*)(hp0 + MAINC + 4*lane);
        const ushort4 r1 = *(const ushort4*)(hp1 + MAINC + 4*lane);
        accr[0] = fmaf(wr0, u2f(r0.x), accr[0]);
        accr[1] = fmaf(wr0, u2f(r0.y), accr[1]);
        accr[2] = fmaf(wr0, u2f(r0.z), accr[2]);
        accr[3] = fmaf(wr0, u2f(r0.w), accr[3]);
        accr[0] = fmaf(wr1, u2f(r1.x), accr[0]);
        accr[1] = fmaf(wr1, u2f(r1.y), accr[1]);
        accr[2] = fmaf(wr1, u2f(r1.z), accr[2]);
        accr[3] = fmaf(wr1, u2f(r1.w), accr[3]);
      }
    } else {
      const ushort2 a0 = *(const ushort2*)(hp0 + 2*lane);
      const ushort2 a1 = *(const ushort2*)(hp1 + 2*lane);
      accm[0] = fmaf(w0, u2f(a0.x), accm[0]);
      accm[1] = fmaf(w0, u2f(a0.y), accm[1]);
      accm[0] = fmaf(w1, u2f(a1.x), accm[0]);
      accm[1] = fmaf(w1, u2f(a1.y), accm[1]);
      if (lane < REMV){
        const ushort2 r0 = *(const ushort2*)(hp0 + MAINC + 2*lane);
        const ushort2 r1 = *(const ushort2*)(hp1 + MAINC + 2*lane);
        accr[0] = fmaf(wr0, u2f(r0.x), accr[0]);
        accr[1] = fmaf(wr0, u2f(r0.y), accr[1]);
        accr[0] = fmaf(wr1, u2f(r1.x), accr[0]);
        accr[1] = fmaf(wr1, u2f(r1.y), accr[1]);
      }
    }
  };

  if (ne <= 64){
    const bool has = lane < ne;
    const int sn = nbase + (has ? srcl[start + lane] : 0);
    float al[H], p[H];
    #pragma unroll
    for (int hh = 0; hh < H; hh++)
      al[hh] = has ? lrelu02(asrc[(size_t)sn*H + hh] + adh[hh]) : -1e30f;
    float c0 = 0.f, c1 = 0.f;
    #pragma unroll
    for (int hh = 0; hh < H; hh++){
      float m = wred_max(al[hh]);
      p[hh] = has ? __expf(al[hh] - m) : 0.f;
      float sinv = 1.f/(wred_sum(p[hh]) + 1e-16f);
      if (hh == 0) c0 = p[0]*sinv; else c1 = p[1]*sinv;
    }
    if (H == 1) c1 = c0;
    int j = 0;
    for (; j + 1 < ne; j += 2){
      int   s0 = __shfl(sn, j, 64),  s1 = __shfl(sn, j+1, 64);
      float a0 = __shfl(c0, j, 64),  a1 = __shfl(c0, j+1, 64);
      float b0, b1;
      if (H == 2){ b0 = __shfl(c1, j, 64); b1 = __shfl(c1, j+1, 64); }
      else       { b0 = a0; b1 = a1; }
      acc_edge2(s0, a0, b0, s1, a1, b1);
    }
    if (j < ne)
      acc_edge(__shfl(sn, j, 64), __shfl(c0, j, 64), (H==2) ? __shfl(c1, j, 64) : __shfl(c0, j, 64));
  } else {
    float lm[H], m[H], sinv[H];
    #pragma unroll
    for (int hh = 0; hh < H; hh++) lm[hh] = -1e30f;
    for (int e = start + lane; e < end; e += 64){
      int sn = nbase + srcl[e];
      #pragma unroll
      for (int hh = 0; hh < H; hh++)
        lm[hh] = fmaxf(lm[hh], lrelu02(asrc[(size_t)sn*H + hh] + adh[hh]));
    }
    #pragma unroll
    for (int hh = 0; hh < H; hh++) m[hh] = wred_max(lm[hh]);
    float ls[H];
    #pragma unroll
    for (int hh = 0; hh < H; hh++) ls[hh] = 0.f;
    for (int e = start + lane; e < end; e += 64){
      int sn = nbase + srcl[e];
      #pragma unroll
      for (int hh = 0; hh < H; hh++)
        ls[hh] += __expf(lrelu02(asrc[(size_t)sn*H + hh] + adh[hh]) - m[hh]);
    }
    #pragma unroll
    for (int hh = 0; hh < H; hh++) sinv[hh] = 1.f/(wred_sum(ls[hh]) + 1e-16f);
    for (int cs = start; cs < end; cs += 64){
      int cnt = min(64, end - cs);
      bool has = lane < cnt;
      int sn = nbase + (has ? srcl[cs + lane] : 0);
      float c0 = 0.f, c1 = 0.f;
      if (has){
        #pragma unroll
        for (int hh = 0; hh < H; hh++){
          float p = __expf(lrelu02(asrc[(size_t)sn*H + hh] + adh[hh]) - m[hh]) * sinv[hh];
          if (hh == 0) c0 = p; else c1 = p;
        }
        if (H == 1) c1 = c0;
      }
      for (int j = 0; j < cnt; j++)
        acc_edge(__shfl(sn, j, 64), __shfl(c0, j, 64), (H==2) ? __shfl(c1, j, 64) : __shfl(c0, j, 64));
    }
  }

  u16* outp = outp0 + (size_t)node*so;
  float fm[VEC], fr[VEC];
  #pragma unroll
  for (int i = 0; i < VEC; i++){
    int c = VEC*lane + i;
    float r = accm[i] + bias[c];
    if (LACT) r = lrelu01(r);
    fm[i] = r;
  }
  if (lane < REMV){
    #pragma unroll
    for (int i = 0; i < VEC; i++){
      int cr = MAINC + VEC*lane + i;
      float r = accr[i] + bias[cr];
      if (LACT) r = lrelu01(r);
      fr[i] = r;
    }
  }
  if (VEC == 4){
    ushort4 st; st.x=f2u(fm[0]); st.y=f2u(fm[1]); st.z=f2u(fm[2]); st.w=f2u(fm[3]);
    *(ushort4*)(outp + 4*lane) = st;
    if (lane < REMV){
      ushort4 sr; sr.x=f2u(fr[0]); sr.y=f2u(fr[1]); sr.z=f2u(fr[2]); sr.w=f2u(fr[3]);
      *(ushort4*)(outp + MAINC + 4*lane) = sr;
    }
  } else {
    ushort2 st; st.x=f2u(fm[0]); st.y=f2u(fm[1]);
    *(ushort2*)(outp + 2*lane) = st;
    if (lane < REMV){
      ushort2 sr; sr.x=f2u(fr[0]); sr.y=f2u(fr[1]);
      *(ushort2*)(outp + MAINC + 2*lane) = sr;
    }
  }

  if (ATTN){
    float s = 0.f, d = 0.f;
    #pragma unroll
    for (int i = 0; i < VEC; i++){
      int c = VEC*lane + i;
      s = fmaf(fm[i], vas[c], s);
      d = fmaf(fm[i], vad[c], d);
    }
    if (lane < REMV){
      #pragma unroll
      for (int i = 0; i < VEC; i++){
        int cr = MAINC + VEC*lane + i;
        s = fmaf(fr[i], vas[cr], s);
        d = fmaf(fr[i], vad[cr], d);
      }
    }
    s = wred_sum(s); d = wred_sum(d);
    if (lane == 0){ as_out[node] = s; ad_out[node] = d; }
  }
}

// ---------------- launch ----------------
extern "C" void kernel_launch(void* const* d_in, const int* in_sizes, int n_in,
                              void* d_out, int out_size, void* d_ws, size_t ws_size,
                              hipStream_t stream)
{
  (void)in_sizes; (void)n_in; (void)out_size;
  const float* x    = (const float*)d_in[0];
  const float* wl1  = (const float*)d_in[1];
  const float* gl1  = (const float*)d_in[3];
  const float* bel1 = (const float*)d_in[4];
  const float* wl2  = (const float*)d_in[5];
  const float* gl2  = (const float*)d_in[7];
  const float* bel2 = (const float*)d_in[8];
  const float* wp1  = (const float*)d_in[9];
  const float* gp1  = (const float*)d_in[11];
  const float* bep1 = (const float*)d_in[12];
  const float* wp2  = (const float*)d_in[13];
  const float* gp2  = (const float*)d_in[15];
  const float* bep2 = (const float*)d_in[16];
  const float* wg   = (const float*)d_in[17];
  const float* gg   = (const float*)d_in[19];
  const float* beg  = (const float*)d_in[20];
  const float* W1   = (const float*)d_in[21];
  const float* as1  = (const float*)d_in[22];
  const float* ad1  = (const float*)d_in[23];
  const float* bb1  = (const float*)d_in[24];
  const float* W2   = (const float*)d_in[25];
  const float* as2  = (const float*)d_in[26];
  const float* ad2  = (const float*)d_in[27];
  const float* bb2  = (const float*)d_in[28];
  const float* Wo   = (const float*)d_in[29];
  const float* bo   = (const float*)d_in[30];
  const float* Wo2  = (const float*)d_in[31];
  const float* bo2  = (const float*)d_in[32];
  const int*   ei   = (const int*)d_in[33];

  const size_t STATIC_BYTES = 1310000;
  int nc = 1;
  while (nc < 8 && STATIC_BYTES + (size_t)2104*(NODES/nc) > ws_size) nc <<= 1;
  const int CB = B_/nc, CN = CB*N0_;
  int cbShift = 0; while ((1 << cbShift) < CB) cbShift++;
  const int cbMask = CB - 1;

  char* wsb = (char*)d_ws; size_t off = 0;
  auto alloc = [&](size_t nbytes)->void*{
    void* p = wsb + off; off = (off + nbytes + 255) & ~(size_t)255; return p;
  };
  int*   zbase  = (int*)  alloc(20080*sizeof(int));
  float* gsum   = (float*)zbase;
  float* gsq    = gsum + 40;
  int*   counts = zbase + 80;
  int*   cursor = counts + 10000;
  float* sA     = (float*)alloc(40*sizeof(float));
  float* sB     = (float*)alloc(40*sizeof(float));
  int*   offs   = (int*)  alloc(10001*sizeof(int));
  int*   srcl   = (int*)  alloc((size_t)NE_*sizeof(int));
  u16*   W1T    = (u16*)  alloc((size_t)272*160*2);
  u16*   W2T    = (u16*)  alloc((size_t)144*288*2);
  u16*   WoT    = (u16*)  alloc((size_t)144*320*2);
  float* va1s   = (float*)alloc(272*sizeof(float));
  float* va1d   = (float*)alloc(272*sizeof(float));
  float* va2s   = (float*)alloc(272*sizeof(float));
  float* va2d   = (float*)alloc(272*sizeof(float));
  u16*   feat   = (u16*)  alloc((size_t)CN*160*2);
  u16*   h1     = (u16*)  alloc((size_t)CN*288*2);
  u16*   g1     = (u16*)  alloc((size_t)CN*288*2);
  u16*   h2     = (u16*)  alloc((size_t)CN*144*2);
  u16*   g2l    = (u16*)  alloc((size_t)CN*160*2);
  float* asrc1  = (float*)alloc((size_t)CN*2*sizeof(float));
  float* adst1  = (float*)alloc((size_t)CN*2*sizeof(float));
  float* asrc2  = (float*)alloc((size_t)CN*sizeof(float));
  float* adst2  = (float*)alloc((size_t)CN*sizeof(float));

  k_zero<<<79,256,0,stream>>>(zbase, 20080);

  k_bn_stats<<<313,256,0,stream>>>(x, wl1,wl2,wp1,wp2,wg, gsum, gsq);
  k_bn_fin  <<<1,64,0,stream>>>(gsum, gsq, sA, sB, gl1,gl2,gp1,gp2,gg, bel1,bel2,bep1,bep2,beg);

  k_count  <<<665,256,0,stream>>>(ei, counts);
  k_scan   <<<1,1024,0,stream>>>(counts, offs);
  k_scatter<<<665,256,0,stream>>>(ei, offs, cursor, srcl);

  k_wt<<<171,256,0,stream>>>(W1T, W1, 272, 160, 272, 136, 0);
  k_wt<<<162,256,0,stream>>>(W2T, W2, 144, 288, 136, 272, 0);
  k_wt<<<180,256,0,stream>>>(WoT, Wo, 144, 320, 136, 0,   1);
  k_va<<<2,256,0,stream>>>(W1, as1, ad1, W2, as2, ad2, va1s, va1d, va2s, va2d);

  const int gx = (CN + 255)/256;
  const int aggB = 2500*CB;
  for (int c = 0; c < nc; c++){
    const int base = c*CN;

    k_feat<<<gx,256,0,stream>>>(x, wl1,wl2,wp1,wp2,wg, sA, sB, va1s, va1d,
                                feat, asrc1, adst1, base, CN);

    k_mfma<5,0,9,0><<<gx,256,0,stream>>>(feat,160, (const u16*)0,0, W1T,160, h1,288,   0, (const float*)0, CN,
                                         (const float*)0,(const float*)0,(float*)0);
    k_mfma<5,0,8,0><<<gx,256,0,stream>>>(feat,160, (const u16*)0,0, W1T,160, h1,288, 144, (const float*)0, CN,
                                         (const float*)0,(const float*)0,(float*)0);
    k_agg<2,272,0,1><<<aggB,256,0,stream>>>(h1,288, asrc1, adst1, offs, srcl, bb1, g1,288,
                                            va2s, va2d, asrc2, adst2, cbMask, cbShift);

    k_mfma<9,0,9,0><<<gx,256,0,stream>>>(g1,288, (const u16*)0,0, W2T,288, h2,144, 0, (const float*)0, CN,
                                         (const float*)0,(const float*)0,(float*)0);
    k_agg<1,136,1,0><<<aggB,256,0,stream>>>(h2,144, asrc2, adst2, offs, srcl, bb2, g2l,160,
                                            (const float*)0,(const float*)0,(float*)0,(float*)0, cbMask, cbShift);

    k_mfma<5,5,9,2><<<gx,256,0,stream>>>(g2l,160, feat,160, WoT,320, (u16*)0,0, 0, bo, CN,
                                         Wo2, bo2, (float*)d_out + base);
  }
}

// Round 9
// 594.845 us; speedup vs baseline: 1.4748x; 1.4748x over previous
//
#include <hip/hip_runtime.h>
#include <hip/hip_bf16.h>
#include <math.h>

typedef unsigned short u16;
typedef unsigned int   u32;
typedef short v8s __attribute__((ext_vector_type(8)));
typedef float v4f __attribute__((ext_vector_type(4)));
#define DEV static __device__ __forceinline__

DEV float u2f(u16 u){ union{u32 i; float f;} v; v.i = ((u32)u)<<16; return v.f; }
DEV u16   f2u(float f){ union{float ff; u32 i;} v; v.ff = f; u32 r = v.i + 0x7fffu + ((v.i>>16)&1u); return (u16)(r>>16); }
DEV float lrelu02(float x){ return x > 0.f ? x : 0.2f*x; }
DEV float lrelu01(float x){ return x > 0.f ? x : 0.01f*x; }
DEV float fast_tanh(float x){
  float cx = fminf(fmaxf(x, -15.f), 15.f);
  float e = __expf(2.f*cx);
  return (e - 1.f) * __builtin_amdgcn_rcpf(e + 1.f);
}
DEV float wred_max(float v){
  #pragma unroll
  for (int o = 32; o > 0; o >>= 1) v = fmaxf(v, __shfl_xor(v, o, 64));
  return v;
}
DEV float wred_sum(float v){
  #pragma unroll
  for (int o = 32; o > 0; o >>= 1) v += __shfl_xor(v, o, 64);
  return v;
}

constexpr int B_   = 8;
constexpr int P_   = 32;
constexpr int N0_  = 10000;
constexpr int NODES = B_ * N0_;      // 80000
constexpr int E_   = 160000;
constexpr int NE_  = E_ + N0_;       // 170000

// ---------------- utility ----------------
__global__ void k_zero(int* __restrict__ p, int n){
  int i = blockIdx.x*blockDim.x + threadIdx.x;
  if (i < n) p[i] = 0;
}

// weight transpose+cast: dst[n][k] (bf16, padded) from src[k][n] (f32)
__global__ void k_wt(u16* __restrict__ dst, const float* __restrict__ src,
                     int NR, int NKp, int Nsrc, int Klim, int mode){
  int i = blockIdx.x*blockDim.x + threadIdx.x;
  if (i >= NR*NKp) return;
  int n = i / NKp, k = i - n*NKp;
  float v = 0.f;
  if (n < Nsrc){
    if (mode == 0){ if (k < Klim) v = src[(size_t)k*Nsrc + n]; }
    else {
      if (k < 136) v = src[(size_t)k*Nsrc + n];
      else if (k >= 160 && k < 296) v = src[(size_t)(k-24)*Nsrc + n];
    }
  }
  dst[i] = f2u(v);
}

// attention linearity vectors: asrc(h1)=feat·(W1 a);  asrc2(h2)=g1·(W2 a2)
__global__ void k_va(const float* __restrict__ W1, const float* __restrict__ as1, const float* __restrict__ ad1,
                     const float* __restrict__ W2, const float* __restrict__ as2, const float* __restrict__ ad2,
                     float* __restrict__ va1s, float* __restrict__ va1d,
                     float* __restrict__ va2s, float* __restrict__ va2d){
  int t = blockIdx.x*blockDim.x + threadIdx.x;
  if (t >= 272) return;
  int hh = t / 136, k = t - hh*136;
  float s = 0.f, d = 0.f;
  for (int c = 0; c < 136; c++){
    float w = W1[(size_t)k*272 + hh*136 + c];
    s = fmaf(w, as1[hh*136 + c], s);
    d = fmaf(w, ad1[hh*136 + c], d);
  }
  va1s[t] = s; va1d[t] = d;                 // layout [hh*136 + k]
  float s2 = 0.f, d2 = 0.f;
  for (int c = 0; c < 136; c++){
    float w = W2[(size_t)t*136 + c];
    s2 = fmaf(w, as2[c], s2);
    d2 = fmaf(w, ad2[c], d2);
  }
  va2s[t] = s2; va2d[t] = d2;
}

// ---------------- backbone ----------------
DEV void load_convw(float* lw, const float* wl1, const float* wl2, const float* wp1,
                    const float* wp2, const float* wg, int tid, int nth){
  for (int i = tid; i < 384; i += nth){
    float v;
    if      (i < 24)  v = wl1[i];
    else if (i < 64)  v = wl2[i-24];
    else if (i < 88)  v = wp1[i-64];
    else if (i < 128) v = wp2[i-88];
    else              v = wg [i-128];
    lw[i] = v;
  }
}

template<int KS,int DIL,int T>
DEV void conv_stats(const float* xc, const float* wk, float& s, float& q){
  #pragma unroll
  for (int t = 0; t < T; t++){
    float v = 0.f;
    #pragma unroll
    for (int j = 0; j < KS; j++) v = fmaf(wk[j], xc[t + j*DIL], v);
    s += v; q = fmaf(v, v, q);
  }
}

__global__ void __launch_bounds__(256) k_bn_stats(
    const float* __restrict__ x,
    const float* __restrict__ wl1, const float* __restrict__ wl2,
    const float* __restrict__ wp1, const float* __restrict__ wp2,
    const float* __restrict__ wg,
    float* __restrict__ gsum, float* __restrict__ gsq)
{
  __shared__ float lw[384];
  __shared__ float lacc[80];
  const int tid = threadIdx.x;
  load_convw(lw, wl1, wl2, wp1, wp2, wg, tid, 256);
  if (tid < 80) lacc[tid] = 0.f;
  __syncthreads();

  int gid = blockIdx.x*256 + tid;
  float xc[P_];
  if (gid < NODES){
    int b = gid / N0_, n = gid - b*N0_;
    const float* xp = x + (size_t)b*P_*N0_ + n;
    #pragma unroll
    for (int p = 0; p < P_; p++) xc[p] = xp[(size_t)p*N0_];
  } else {
    #pragma unroll
    for (int p = 0; p < P_; p++) xc[p] = 0.f;
  }
  const int lane = tid & 63;

  auto red = [&](int ch, float s, float q){
    #pragma unroll
    for (int o = 32; o > 0; o >>= 1){ s += __shfl_down(s,o,64); q += __shfl_down(q,o,64); }
    if (lane == 0){ atomicAdd(&lacc[ch], s); atomicAdd(&lacc[40+ch], q); }
  };

  #pragma unroll
  for (int k = 0; k < 8; k++){ float s=0,q=0; conv_stats<3,1,30>(xc, lw      + k*3 , s,q); red(k,     s,q); }
  #pragma unroll
  for (int k = 0; k < 8; k++){ float s=0,q=0; conv_stats<5,1,28>(xc, lw + 24 + k*5 , s,q); red(8+k,   s,q); }
  #pragma unroll
  for (int k = 0; k < 8; k++){ float s=0,q=0; conv_stats<3,2,28>(xc, lw + 64 + k*3 , s,q); red(16+k,  s,q); }
  #pragma unroll
  for (int k = 0; k < 8; k++){ float s=0,q=0; conv_stats<5,2,24>(xc, lw + 88 + k*5 , s,q); red(24+k,  s,q); }
  #pragma unroll
  for (int k = 0; k < 8; k++){ float s=0,q=0; conv_stats<32,1,1>(xc, lw + 128+ k*32, s,q); red(32+k,  s,q); }

  __syncthreads();
  if (tid < 40)      atomicAdd(&gsum[tid],    lacc[tid]);
  else if (tid < 80) atomicAdd(&gsq [tid-40], lacc[tid]);
}

__global__ void k_bn_fin(const float* __restrict__ gsum, const float* __restrict__ gsq,
                         float* __restrict__ sA, float* __restrict__ sB,
                         const float* g0, const float* g1, const float* g2, const float* g3, const float* g4,
                         const float* e0, const float* e1, const float* e2, const float* e3, const float* e4)
{
  int t = threadIdx.x;
  if (t >= 40) return;
  int bi = t >> 3, k = t & 7;
  const int Ts[5] = {30,28,28,24,1};
  float cnt  = (float)NODES * (float)Ts[bi];
  float mean = gsum[t] / cnt;
  float var  = gsq[t] / cnt - mean*mean;
  const float* gp = bi==0?g0: bi==1?g1: bi==2?g2: bi==3?g3: g4;
  const float* ep = bi==0?e0: bi==1?e1: bi==2?e2: bi==3?e3: e4;
  float a = gp[k] * rsqrtf(fmaxf(var, 0.f) + 1e-5f);
  sA[t] = a;
  sB[t] = ep[k] - a*mean;
}

template<int KS,int DIL,int T>
DEV void conv_pool4(const float* xc, const float* wk, float A, float Bc, float* o4){
  float y[T];
  #pragma unroll
  for (int t = 0; t < T; t++){
    float v = 0.f;
    #pragma unroll
    for (int j = 0; j < KS; j++) v = fmaf(wk[j], xc[t + j*DIL], v);
    y[t] = fmaf(A, v, Bc);
  }
  #pragma unroll
  for (int i = 0; i < 4; i++){
    const int lo = (i*T)/4, hi = ((i+1)*T + 3)/4;
    float m = y[lo];
    #pragma unroll
    for (int t = 0; t < T; t++){ if (t > lo && t < hi) m = fmaxf(m, y[t]); }
    o4[i] = m;
  }
}

// feat row-major [m][160] bf16 (tanh) + fused layer-1 attention dots.
// 2 waves per 64-node group: half0 = l1+l2 (ch 0..63), half1 = p1+p2+g (ch 64..135).
__global__ void __launch_bounds__(256) k_feat(
    const float* __restrict__ x,
    const float* __restrict__ wl1, const float* __restrict__ wl2,
    const float* __restrict__ wp1, const float* __restrict__ wp2,
    const float* __restrict__ wg,
    const float* __restrict__ sA, const float* __restrict__ sB,
    const float* __restrict__ va1s, const float* __restrict__ va1d,
    u16* __restrict__ feat, float* __restrict__ asrc1, float* __restrict__ adst1,
    int base, int m)
{
  __shared__ float lw[384];
  __shared__ float lA[40], lB[40];
  __shared__ float lvs[272], lvd[272];
  __shared__ float sdt[128][4];
  const int tid = threadIdx.x;
  load_convw(lw, wl1, wl2, wp1, wp2, wg, tid, 256);
  if (tid < 40){ lA[tid] = sA[tid]; lB[tid] = sB[tid]; }
  for (int i = tid; i < 272; i += 256){ lvs[i] = va1s[i]; lvd[i] = va1d[i]; }
  __syncthreads();

  const int lane = tid & 63, wv = tid >> 6;
  const int nodeLocal = (wv >> 1)*64 + lane;     // 0..127
  const int half = wv & 1;                       // wave-uniform
  const int nodeIdx = blockIdx.x*128 + nodeLocal;
  const bool act = nodeIdx < m;
  const int gcl = base + (act ? nodeIdx : (m-1));
  int b = gcl / N0_, n = gcl - b*N0_;
  float xc[P_];
  const float* xp = x + (size_t)b*P_*N0_ + n;
  #pragma unroll
  for (int p = 0; p < P_; p++) xc[p] = xp[(size_t)p*N0_];

  float dt[4] = {0.f,0.f,0.f,0.f};       // s0,d0,s1,d1 (partial)
  u32 pk[4];
  u16* orow = feat + (size_t)nodeIdx*160;
  auto emit = [&](int ch, float v){
    float t = fast_tanh(v);
    dt[0] = fmaf(t, lvs[ch],     dt[0]);
    dt[1] = fmaf(t, lvd[ch],     dt[1]);
    dt[2] = fmaf(t, lvs[136+ch], dt[2]);
    dt[3] = fmaf(t, lvd[136+ch], dt[3]);
    u16 h = f2u(t);
    int s = ch & 7;
    if ((s & 1) == 0) pk[s>>1] = h;
    else              pk[s>>1] |= ((u32)h) << 16;
    if (s == 7 && act) *(uint4*)(orow + (ch - 7)) = make_uint4(pk[0],pk[1],pk[2],pk[3]);
  };

  float o4[4];
  if (half == 0){
    #pragma unroll
    for (int k = 0; k < 8; k++){
      conv_pool4<3,1,30>(xc, lw + k*3, lA[k], lB[k], o4);
      #pragma unroll
      for (int i = 0; i < 4; i++) emit(k*4+i, o4[i]);
    }
    #pragma unroll
    for (int k = 0; k < 8; k++){
      conv_pool4<5,1,28>(xc, lw + 24 + k*5, lA[8+k], lB[8+k], o4);
      #pragma unroll
      for (int i = 0; i < 4; i++) emit(32 + k*4+i, o4[i]);
    }
  } else {
    #pragma unroll
    for (int k = 0; k < 8; k++){
      conv_pool4<3,2,28>(xc, lw + 64 + k*3, lA[16+k], lB[16+k], o4);
      #pragma unroll
      for (int i = 0; i < 4; i++) emit(64 + k*4+i, o4[i]);
    }
    #pragma unroll
    for (int k = 0; k < 8; k++){
      conv_pool4<5,2,24>(xc, lw + 88 + k*5, lA[24+k], lB[24+k], o4);
      #pragma unroll
      for (int i = 0; i < 4; i++) emit(96 + k*4+i, o4[i]);
    }
    #pragma unroll
    for (int k = 0; k < 8; k++){
      float v = 0.f;
      #pragma unroll
      for (int j = 0; j < 32; j++) v = fmaf(lw[128 + k*32 + j], xc[j], v);
      emit(128 + k, fmaf(lA[32+k], v, lB[32+k]));
    }
  }

  if (half == 1){
    sdt[nodeLocal][0] = dt[0]; sdt[nodeLocal][1] = dt[1];
    sdt[nodeLocal][2] = dt[2]; sdt[nodeLocal][3] = dt[3];
  }
  __syncthreads();
  if (half == 0 && act){
    float s0 = dt[0] + sdt[nodeLocal][0];
    float d0 = dt[1] + sdt[nodeLocal][1];
    float s1 = dt[2] + sdt[nodeLocal][2];
    float d1 = dt[3] + sdt[nodeLocal][3];
    asrc1[(size_t)nodeIdx*2]   = s0;
    asrc1[(size_t)nodeIdx*2+1] = s1;
    adst1[(size_t)nodeIdx*2]   = d0;
    adst1[(size_t)nodeIdx*2+1] = d1;
  }
}

// ---------------- CSR ----------------
__global__ void k_count(const int* __restrict__ ei, int* __restrict__ counts){
  int e = blockIdx.x*blockDim.x + threadIdx.x;
  if (e >= NE_) return;
  int dst = (e < E_) ? ei[E_ + e] : (e - E_);
  atomicAdd(&counts[dst], 1);
}

__global__ void __launch_bounds__(1024) k_scan(const int* __restrict__ counts, int* __restrict__ offs){
  __shared__ int part[1024];
  int t = threadIdx.x;
  int loc[10]; int s = 0;
  #pragma unroll
  for (int i = 0; i < 10; i++){
    int idx = t*10 + i;
    int c = (idx < N0_) ? counts[idx] : 0;
    loc[i] = s; s += c;
  }
  part[t] = s;
  __syncthreads();
  for (int o = 1; o < 1024; o <<= 1){
    int v = (t >= o) ? part[t-o] : 0;
    __syncthreads();
    part[t] += v;
    __syncthreads();
  }
  int pre = (t == 0) ? 0 : part[t-1];
  #pragma unroll
  for (int i = 0; i < 10; i++){
    int idx = t*10 + i;
    if (idx < N0_) offs[idx] = pre + loc[i];
  }
  if (t == 0) offs[N0_] = part[1023];
}

__global__ void k_scatter(const int* __restrict__ ei, const int* __restrict__ offs,
                          int* __restrict__ cursor, int* __restrict__ srcl){
  int e = blockIdx.x*blockDim.x + threadIdx.x;
  if (e >= NE_) return;
  int src, dst;
  if (e < E_){ src = ei[e]; dst = ei[E_ + e]; } else { src = dst = e - E_; }
  int pos = atomicAdd(&cursor[dst], 1);
  srcl[offs[dst] + pos] = src;
}

// ---------------- MFMA GEMM: A[m][K] bf16 row-major, BT[n][K] bf16 ----------------
// EPI 0: C bf16 plain; EPI 1: C bf16 lrelu01(+bias); EPI 2: fused head — out[r] = Σ_col lrelu01(acc+bias)*w2v + bo2
template<int KT1,int KT2,int NT,int EPI>
__global__ void __launch_bounds__(256) k_mfma(
    const u16* __restrict__ A1, int sA1,
    const u16* __restrict__ A2, int sA2,
    const u16* __restrict__ BT, int sBT,
    u16* __restrict__ C, int sC, int nbase,
    const float* __restrict__ bias, int m,
    const float* __restrict__ w2v, const float* __restrict__ bo2p, float* __restrict__ fout)
{
  const int wv = threadIdx.x >> 6, lane = threadIdx.x & 63;
  const int quad = lane >> 4, l15 = lane & 15;
  const int mb = blockIdx.x*256 + wv*64;
  int ar[4];
  #pragma unroll
  for (int mt = 0; mt < 4; mt++) ar[mt] = min(mb + mt*16 + l15, m-1);

  v4f acc[4][NT];
  #pragma unroll
  for (int mt = 0; mt < 4; mt++)
    #pragma unroll
    for (int nt = 0; nt < NT; nt++)
      acc[mt][nt] = (v4f){0.f,0.f,0.f,0.f};

  for (int kt = 0; kt < KT1+KT2; kt++){
    const u16* ab; int sA, koff;
    if (KT2 == 0 || kt < KT1){ ab = A1; sA = sA1; koff = kt*32; }
    else { ab = A2; sA = sA2; koff = (kt-KT1)*32; }
    v8s a[4];
    #pragma unroll
    for (int mt = 0; mt < 4; mt++)
      a[mt] = *(const v8s*)(ab + (size_t)ar[mt]*sA + koff + quad*8);
    if (KT2 > 0 && kt >= KT1){
      #pragma unroll
      for (int mt = 0; mt < 4; mt++)
        #pragma unroll
        for (int j = 0; j < 8; j++){
          float f = u2f((u16)a[mt][j]);
          f = f > 0.f ? f : 0.01f*f;
          a[mt][j] = (short)f2u(f);
        }
    }
    const int kb = kt*32 + quad*8;
    #pragma unroll
    for (int nt = 0; nt < NT; nt++){
      v8s b = *(const v8s*)(BT + (size_t)(nbase + nt*16 + l15)*sBT + kb);
      #pragma unroll
      for (int mt = 0; mt < 4; mt++)
        acc[mt][nt] = __builtin_amdgcn_mfma_f32_16x16x32_bf16(a[mt], b, acc[mt][nt], 0, 0, 0);
    }
  }

  if (EPI == 2){
    const float bo2v = bo2p[0];
    #pragma unroll
    for (int mt = 0; mt < 4; mt++){
      float part[4] = {0.f,0.f,0.f,0.f};
      #pragma unroll
      for (int nt = 0; nt < NT; nt++){
        const int col = nt*16 + l15;
        float wv2 = (col < 136) ? w2v[col] : 0.f;
        float bv  = bias[min(col,135)];
        #pragma unroll
        for (int i = 0; i < 4; i++){
          float xv = lrelu01(acc[mt][nt][i] + bv);
          part[i] = fmaf(xv, wv2, part[i]);
        }
      }
      #pragma unroll
      for (int i = 0; i < 4; i++){
        float v = part[i];
        v += __shfl_xor(v, 1, 64);
        v += __shfl_xor(v, 2, 64);
        v += __shfl_xor(v, 4, 64);
        v += __shfl_xor(v, 8, 64);
        int r = mb + mt*16 + quad*4 + i;
        if (l15 == 0 && r < m) fout[r] = v + bo2v;
      }
    }
    return;
  }

  #pragma unroll
  for (int mt = 0; mt < 4; mt++){
    const int r0 = mb + mt*16 + quad*4;
    #pragma unroll
    for (int nt = 0; nt < NT; nt++){
      const int col = nbase + nt*16 + l15;
      #pragma unroll
      for (int i = 0; i < 4; i++){
        int r = r0 + i;
        if (r < m){
          float xv = acc[mt][nt][i];
          if (EPI == 1){ xv += bias[min(col,135)]; xv = lrelu01(xv); }
          C[(size_t)r*sC + col] = f2u(xv);
        }
      }
    }
  }
}

// ---------------- GAT aggregation: one wave per (dst,b), XCD-swizzled, unroll-2 ----------------
// ATTN=1: also compute next-layer attention dots (asrc2/adst2) from the output row
template<int H,int CT,int LACT,int ATTN>
__global__ void __launch_bounds__(256) k_agg(const u16* __restrict__ h, int sh,
    const float* __restrict__ asrc, const float* __restrict__ adst,
    const int* __restrict__ offs, const int* __restrict__ srcl,
    const float* __restrict__ bias, u16* __restrict__ outp0, int so,
    const float* __restrict__ vas, const float* __restrict__ vad,
    float* __restrict__ as_out, float* __restrict__ ad_out,
    int cbMask, int cbShift)
{
  constexpr int CC   = CT/H;
  constexpr int VEC  = (CT >= 256) ? 4 : 2;
  constexpr int MAINC= 64*VEC;
  constexpr int REMV = (CT - MAINC)/VEC;

  const int wv = threadIdx.x >> 6, lane = threadIdx.x & 63;
  const int id = blockIdx.x;
  const int bb = id & cbMask;           // batch -> XCD locality
  const int dst = (id >> cbShift)*4 + wv;
  const int nbase = bb*N0_;
  const int node = nbase + dst;
  const int start = offs[dst], end = offs[dst+1];
  const int ne = end - start;

  float adh[H];
  #pragma unroll
  for (int hh = 0; hh < H; hh++) adh[hh] = adst[(size_t)node*H + hh];

  float accm[VEC], accr[VEC];
  #pragma unroll
  for (int i = 0; i < VEC; i++){ accm[i] = 0.f; accr[i] = 0.f; }

  const bool hi = (H == 2) && (VEC*lane >= CC);

  auto acc_edge = [&](int sj, float c0, float c1){
    const u16* hp = h + (size_t)sj*sh;
    float w  = hi ? c1 : c0;
    float wr = (H == 2) ? c1 : c0;
    if (VEC == 4){
      const ushort4 hv = *(const ushort4*)(hp + 4*lane);
      accm[0] = fmaf(w, u2f(hv.x), accm[0]);
      accm[1] = fmaf(w, u2f(hv.y), accm[1]);
      accm[2] = fmaf(w, u2f(hv.z), accm[2]);
      accm[3] = fmaf(w, u2f(hv.w), accm[3]);
      if (lane < REMV){
        const ushort4 hr = *(const ushort4*)(hp + MAINC + 4*lane);
        accr[0] = fmaf(wr, u2f(hr.x), accr[0]);
        accr[1] = fmaf(wr, u2f(hr.y), accr[1]);
        accr[2] = fmaf(wr, u2f(hr.z), accr[2]);
        accr[3] = fmaf(wr, u2f(hr.w), accr[3]);
      }
    } else {
      const ushort2 hv = *(const ushort2*)(hp + 2*lane);
      accm[0] = fmaf(w, u2f(hv.x), accm[0]);
      accm[1] = fmaf(w, u2f(hv.y), accm[1]);
      if (lane < REMV){
        const ushort2 hr = *(const ushort2*)(hp + MAINC + 2*lane);
        accr[0] = fmaf(wr, u2f(hr.x), accr[0]);
        accr[1] = fmaf(wr, u2f(hr.y), accr[1]);
      }
    }
  };

  // paired version: both loads issued before the FMA chains (static, ILP=2)
  auto acc_edge2 = [&](int sj0, float c00, float c10, int sj1, float c01, float c11){
    const u16* hp0 = h + (size_t)sj0*sh;
    const u16* hp1 = h + (size_t)sj1*sh;
    float w0  = hi ? c10 : c00;
    float w1  = hi ? c11 : c01;
    float wr0 = (H == 2) ? c10 : c00;
    float wr1 = (H == 2) ? c11 : c01;
    if (VEC == 4){
      const ushort4 a0 = *(const ushort4*)(hp0 + 4*lane);
      const ushort4 a1 = *(const ushort4*)(hp1 + 4*lane);
      accm[0] = fmaf(w0, u2f(a0.x), accm[0]);
      accm[1] = fmaf(w0, u2f(a0.y), accm[1]);
      accm[2] = fmaf(w0, u2f(a0.z), accm[2]);
      accm[3] = fmaf(w0, u2f(a0.w), accm[3]);
      accm[0] = fmaf(w1, u2f(a1.x), accm[0]);
      accm[1] = fmaf(w1, u2f(a1.y), accm[1]);
      accm[2] = fmaf(w1, u2f(a1.z), accm[2]);
      accm[3] = fmaf(w1, u2f(a1.w), accm[3]);
      if (lane < REMV){
        const ushort4 r0 = *(const ushort4*)(hp0 + MAINC + 4*lane);
        const ushort4 r1 = *(const ushort4*)(hp1 + MAINC + 4*lane);
        accr[0] = fmaf(wr0, u2f(r0.x), accr[0]);
        accr[1] = fmaf(wr0, u2f(r0.y), accr[1]);
        accr[2] = fmaf(wr0, u2f(r0.z), accr[2]);
        accr[3] = fmaf(wr0, u2f(r0.w), accr[3]);
        accr[0] = fmaf(wr1, u2f(r1.x), accr[0]);
        accr[1] = fmaf(wr1, u2f(r1.y), accr[1]);
        accr[2] = fmaf(wr1, u2f(r1.z), accr[2]);
        accr[3] = fmaf(wr1, u2f(r1.w), accr[3]);
      }
    } else {
      const ushort2 a0 = *(const ushort2*)(hp0 + 2*lane);
      const ushort2 a1 = *(const ushort2*)(hp1 + 2*lane);
      accm[0] = fmaf(w0, u2f(a0.x), accm[0]);
      accm[1] = fmaf(w0, u2f(a0.y), accm[1]);
      accm[0] = fmaf(w1, u2f(a1.x), accm[0]);
      accm[1] = fmaf(w1, u2f(a1.y), accm[1]);
      if (lane < REMV){
        const ushort2 r0 = *(const ushort2*)(hp0 + MAINC + 2*lane);
        const ushort2 r1 = *(const ushort2*)(hp1 + MAINC + 2*lane);
        accr[0] = fmaf(wr0, u2f(r0.x), accr[0]);
        accr[1] = fmaf(wr0, u2f(r0.y), accr[1]);
        accr[0] = fmaf(wr1, u2f(r1.x), accr[0]);
        accr[1] = fmaf(wr1, u2f(r1.y), accr[1]);
      }
    }
  };

  if (ne <= 64){
    const bool has = lane < ne;
    const int sn = nbase + (has ? srcl[start + lane] : 0);
    float al[H], p[H];
    #pragma unroll
    for (int hh = 0; hh < H; hh++)
      al[hh] = has ? lrelu02(asrc[(size_t)sn*H + hh] + adh[hh]) : -1e30f;
    float c0 = 0.f, c1 = 0.f;
    #pragma unroll
    for (int hh = 0; hh < H; hh++){
      float m = wred_max(al[hh]);
      p[hh] = has ? __expf(al[hh] - m) : 0.f;
      float sinv = 1.f/(wred_sum(p[hh]) + 1e-16f);
      if (hh == 0) c0 = p[0]*sinv; else c1 = p[1]*sinv;
    }
    if (H == 1) c1 = c0;
    int j = 0;
    for (; j + 1 < ne; j += 2){
      int   s0 = __shfl(sn, j, 64),  s1 = __shfl(sn, j+1, 64);
      float a0 = __shfl(c0, j, 64),  a1 = __shfl(c0, j+1, 64);
      float b0, b1;
      if (H == 2){ b0 = __shfl(c1, j, 64); b1 = __shfl(c1, j+1, 64); }
      else       { b0 = a0; b1 = a1; }
      acc_edge2(s0, a0, b0, s1, a1, b1);
    }
    if (j < ne)
      acc_edge(__shfl(sn, j, 64), __shfl(c0, j, 64), (H==2) ? __shfl(c1, j, 64) : __shfl(c0, j, 64));
  } else {
    float lm[H], m[H], sinv[H];
    #pragma unroll
    for (int hh = 0; hh < H; hh++) lm[hh] = -1e30f;
    for (int e = start + lane; e < end; e += 64){
      int sn = nbase + srcl[e];
      #pragma unroll
      for (int hh = 0; hh < H; hh++)
        lm[hh] = fmaxf(lm[hh], lrelu02(asrc[(size_t)sn*H + hh] + adh[hh]));
    }
    #pragma unroll
    for (int hh = 0; hh < H; hh++) m[hh] = wred_max(lm[hh]);
    float ls[H];
    #pragma unroll
    for (int hh = 0; hh < H; hh++) ls[hh] = 0.f;
    for (int e = start + lane; e < end; e += 64){
      int sn = nbase + srcl[e];
      #pragma unroll
      for (int hh = 0; hh < H; hh++)
        ls[hh] += __expf(lrelu02(asrc[(size_t)sn*H + hh] + adh[hh]) - m[hh]);
    }
    #pragma unroll
    for (int hh = 0; hh < H; hh++) sinv[hh] = 1.f/(wred_sum(ls[hh]) + 1e-16f);
    for (int cs = start; cs < end; cs += 64){
      int cnt = min(64, end - cs);
      bool has = lane < cnt;
      int sn = nbase + (has ? srcl[cs + lane] : 0);
      float c0 = 0.f, c1 = 0.f;
      if (has){
        #pragma unroll
        for (int hh = 0; hh < H; hh++){
          float p = __expf(lrelu02(asrc[(size_t)sn*H + hh] + adh[hh]) - m[hh]) * sinv[hh];
          if (hh == 0) c0 = p; else c1 = p;
        }
        if (H == 1) c1 = c0;
      }
      for (int j = 0; j < cnt; j++)
        acc_edge(__shfl(sn, j, 64), __shfl(c0, j, 64), (H==2) ? __shfl(c1, j, 64) : __shfl(c0, j, 64));
    }
  }

  u16* outp = outp0 + (size_t)node*so;
  float fm[VEC], fr[VEC];
  #pragma unroll
  for (int i = 0; i < VEC; i++){
    int c = VEC*lane + i;
    float r = accm[i] + bias[c];
    if (LACT) r = lrelu01(r);
    fm[i] = r;
  }
  if (lane < REMV){
    #pragma unroll
    for (int i = 0; i < VEC; i++){
      int cr = MAINC + VEC*lane + i;
      float r = accr[i] + bias[cr];
      if (LACT) r = lrelu01(r);
      fr[i] = r;
    }
  }
  if (VEC == 4){
    ushort4 st; st.x=f2u(fm[0]); st.y=f2u(fm[1]); st.z=f2u(fm[2]); st.w=f2u(fm[3]);
    *(ushort4*)(outp + 4*lane) = st;
    if (lane < REMV){
      ushort4 sr; sr.x=f2u(fr[0]); sr.y=f2u(fr[1]); sr.z=f2u(fr[2]); sr.w=f2u(fr[3]);
      *(ushort4*)(outp + MAINC + 4*lane) = sr;
    }
  } else {
    ushort2 st; st.x=f2u(fm[0]); st.y=f2u(fm[1]);
    *(ushort2*)(outp + 2*lane) = st;
    if (lane < REMV){
      ushort2 sr; sr.x=f2u(fr[0]); sr.y=f2u(fr[1]);
      *(ushort2*)(outp + MAINC + 2*lane) = sr;
    }
  }

  if (ATTN){
    float s = 0.f, d = 0.f;
    #pragma unroll
    for (int i = 0; i < VEC; i++){
      int c = VEC*lane + i;
      s = fmaf(fm[i], vas[c], s);
      d = fmaf(fm[i], vad[c], d);
    }
    if (lane < REMV){
      #pragma unroll
      for (int i = 0; i < VEC; i++){
        int cr = MAINC + VEC*lane + i;
        s = fmaf(fr[i], vas[cr], s);
        d = fmaf(fr[i], vad[cr], d);
      }
    }
    s = wred_sum(s); d = wred_sum(d);
    if (lane == 0){ as_out[node] = s; ad_out[node] = d; }
  }
}

// ---------------- launch ----------------
extern "C" void kernel_launch(void* const* d_in, const int* in_sizes, int n_in,
                              void* d_out, int out_size, void* d_ws, size_t ws_size,
                              hipStream_t stream)
{
  (void)in_sizes; (void)n_in; (void)out_size;
  const float* x    = (const float*)d_in[0];
  const float* wl1  = (const float*)d_in[1];
  const float* gl1  = (const float*)d_in[3];
  const float* bel1 = (const float*)d_in[4];
  const float* wl2  = (const float*)d_in[5];
  const float* gl2  = (const float*)d_in[7];
  const float* bel2 = (const float*)d_in[8];
  const float* wp1  = (const float*)d_in[9];
  const float* gp1  = (const float*)d_in[11];
  const float* bep1 = (const float*)d_in[12];
  const float* wp2  = (const float*)d_in[13];
  const float* gp2  = (const float*)d_in[15];
  const float* bep2 = (const float*)d_in[16];
  const float* wg   = (const float*)d_in[17];
  const float* gg   = (const float*)d_in[19];
  const float* beg  = (const float*)d_in[20];
  const float* W1   = (const float*)d_in[21];
  const float* as1  = (const float*)d_in[22];
  const float* ad1  = (const float*)d_in[23];
  const float* bb1  = (const float*)d_in[24];
  const float* W2   = (const float*)d_in[25];
  const float* as2  = (const float*)d_in[26];
  const float* ad2  = (const float*)d_in[27];
  const float* bb2  = (const float*)d_in[28];
  const float* Wo   = (const float*)d_in[29];
  const float* bo   = (const float*)d_in[30];
  const float* Wo2  = (const float*)d_in[31];
  const float* bo2  = (const float*)d_in[32];
  const int*   ei   = (const int*)d_in[33];

  const size_t STATIC_BYTES = 1310000;
  int nc = 1;
  while (nc < 8 && STATIC_BYTES + (size_t)2104*(NODES/nc) > ws_size) nc <<= 1;
  const int CB = B_/nc, CN = CB*N0_;
  int cbShift = 0; while ((1 << cbShift) < CB) cbShift++;
  const int cbMask = CB - 1;

  char* wsb = (char*)d_ws; size_t off = 0;
  auto alloc = [&](size_t nbytes)->void*{
    void* p = wsb + off; off = (off + nbytes + 255) & ~(size_t)255; return p;
  };
  int*   zbase  = (int*)  alloc(20080*sizeof(int));
  float* gsum   = (float*)zbase;
  float* gsq    = gsum + 40;
  int*   counts = zbase + 80;
  int*   cursor = counts + 10000;
  float* sA     = (float*)alloc(40*sizeof(float));
  float* sB     = (float*)alloc(40*sizeof(float));
  int*   offs   = (int*)  alloc(10001*sizeof(int));
  int*   srcl   = (int*)  alloc((size_t)NE_*sizeof(int));
  u16*   W1T    = (u16*)  alloc((size_t)272*160*2);
  u16*   W2T    = (u16*)  alloc((size_t)144*288*2);
  u16*   WoT    = (u16*)  alloc((size_t)144*320*2);
  float* va1s   = (float*)alloc(272*sizeof(float));
  float* va1d   = (float*)alloc(272*sizeof(float));
  float* va2s   = (float*)alloc(272*sizeof(float));
  float* va2d   = (float*)alloc(272*sizeof(float));
  u16*   feat   = (u16*)  alloc((size_t)CN*160*2);
  u16*   h1     = (u16*)  alloc((size_t)CN*288*2);
  u16*   g1     = (u16*)  alloc((size_t)CN*288*2);
  u16*   h2     = (u16*)  alloc((size_t)CN*144*2);
  u16*   g2l    = (u16*)  alloc((size_t)CN*160*2);
  float* asrc1  = (float*)alloc((size_t)CN*2*sizeof(float));
  float* adst1  = (float*)alloc((size_t)CN*2*sizeof(float));
  float* asrc2  = (float*)alloc((size_t)CN*sizeof(float));
  float* adst2  = (float*)alloc((size_t)CN*sizeof(float));

  k_zero<<<79,256,0,stream>>>(zbase, 20080);

  k_bn_stats<<<313,256,0,stream>>>(x, wl1,wl2,wp1,wp2,wg, gsum, gsq);
  k_bn_fin  <<<1,64,0,stream>>>(gsum, gsq, sA, sB, gl1,gl2,gp1,gp2,gg, bel1,bel2,bep1,bep2,beg);

  k_count  <<<665,256,0,stream>>>(ei, counts);
  k_scan   <<<1,1024,0,stream>>>(counts, offs);
  k_scatter<<<665,256,0,stream>>>(ei, offs, cursor, srcl);

  k_wt<<<171,256,0,stream>>>(W1T, W1, 272, 160, 272, 136, 0);
  k_wt<<<162,256,0,stream>>>(W2T, W2, 144, 288, 136, 272, 0);
  k_wt<<<180,256,0,stream>>>(WoT, Wo, 144, 320, 136, 0,   1);
  k_va<<<2,256,0,stream>>>(W1, as1, ad1, W2, as2, ad2, va1s, va1d, va2s, va2d);

  const int gx  = (CN + 255)/256;
  const int gx2 = (CN + 127)/128;
  const int aggB = 2500*CB;
  for (int c = 0; c < nc; c++){
    const int base = c*CN;

    k_feat<<<gx2,256,0,stream>>>(x, wl1,wl2,wp1,wp2,wg, sA, sB, va1s, va1d,
                                 feat, asrc1, adst1, base, CN);

    k_mfma<5,0,9,0><<<gx,256,0,stream>>>(feat,160, (const u16*)0,0, W1T,160, h1,288,   0, (const float*)0, CN,
                                         (const float*)0,(const float*)0,(float*)0);
    k_mfma<5,0,8,0><<<gx,256,0,stream>>>(feat,160, (const u16*)0,0, W1T,160, h1,288, 144, (const float*)0, CN,
                                         (const float*)0,(const float*)0,(float*)0);
    k_agg<2,272,0,1><<<aggB,256,0,stream>>>(h1,288, asrc1, adst1, offs, srcl, bb1, g1,288,
                                            va2s, va2d, asrc2, adst2, cbMask, cbShift);

    k_mfma<9,0,9,0><<<gx,256,0,stream>>>(g1,288, (const u16*)0,0, W2T,288, h2,144, 0, (const float*)0, CN,
                                         (const float*)0,(const float*)0,(float*)0);
    k_agg<1,136,1,0><<<aggB,256,0,stream>>>(h2,144, asrc2, adst2, offs, srcl, bb2, g2l,160,
                                            (const float*)0,(const float*)0,(float*)0,(float*)0, cbMask, cbShift);

    k_mfma<5,5,9,2><<<gx,256,0,stream>>>(g2l,160, feat,160, WoT,320, (u16*)0,0, 0, bo, CN,
                                         Wo2, bo2, (float*)d_out + base);
  }
}

// Round 10
// 561.797 us; speedup vs baseline: 1.5616x; 1.0588x over previous
//
#include <hip/hip_runtime.h>
#include <hip/hip_bf16.h>
#include <math.h>

typedef unsigned short u16;
typedef unsigned int   u32;
typedef short v8s __attribute__((ext_vector_type(8)));
typedef float v4f __attribute__((ext_vector_type(4)));
#define DEV static __device__ __forceinline__

DEV float u2f(u16 u){ union{u32 i; float f;} v; v.i = ((u32)u)<<16; return v.f; }
DEV u16   f2u(float f){ union{float ff; u32 i;} v; v.ff = f; u32 r = v.i + 0x7fffu + ((v.i>>16)&1u); return (u16)(r>>16); }
DEV float lrelu02(float x){ return x > 0.f ? x : 0.2f*x; }
DEV float lrelu01(float x){ return x > 0.f ? x : 0.01f*x; }
DEV float fast_tanh(float x){
  float cx = fminf(fmaxf(x, -15.f), 15.f);
  float e = __expf(2.f*cx);
  return (e - 1.f) * __builtin_amdgcn_rcpf(e + 1.f);
}
DEV float wred_max(float v){
  #pragma unroll
  for (int o = 32; o > 0; o >>= 1) v = fmaxf(v, __shfl_xor(v, o, 64));
  return v;
}
DEV float wred_sum(float v){
  #pragma unroll
  for (int o = 32; o > 0; o >>= 1) v += __shfl_xor(v, o, 64);
  return v;
}

constexpr int B_   = 8;
constexpr int P_   = 32;
constexpr int N0_  = 10000;
constexpr int NODES = B_ * N0_;      // 80000
constexpr int E_   = 160000;
constexpr int NE_  = E_ + N0_;       // 170000

// ---------------- utility ----------------
__global__ void k_zero(int* __restrict__ p, int n){
  int i = blockIdx.x*blockDim.x + threadIdx.x;
  if (i < n) p[i] = 0;
}

// weight transpose+cast for head: WoT[n][k] bf16 (mode 1 split)
__global__ void k_wt(u16* __restrict__ dst, const float* __restrict__ src,
                     int NR, int NKp, int Nsrc, int Klim, int mode){
  int i = blockIdx.x*blockDim.x + threadIdx.x;
  if (i >= NR*NKp) return;
  int n = i / NKp, k = i - n*NKp;
  float v = 0.f;
  if (n < Nsrc){
    if (mode == 0){ if (k < Klim) v = src[(size_t)k*Nsrc + n]; }
    else {
      if (k < 136) v = src[(size_t)k*Nsrc + n];
      else if (k >= 160 && k < 296) v = src[(size_t)(k-24)*Nsrc + n];
    }
  }
  dst[i] = f2u(v);
}

// W12T[n][kk] bf16 (144 x 288): fused W1@W2 per head-block; pads zero.
// kk<136: head0 k=kk ; 136<=kk<272: head1 k=kk-136
__global__ void k_w12(const float* __restrict__ W1, const float* __restrict__ W2,
                      u16* __restrict__ W12T){
  int i = blockIdx.x*blockDim.x + threadIdx.x;
  if (i >= 144*288) return;
  int n = i / 288, kk = i - n*288;
  float v = 0.f;
  if (n < 136 && kk < 272){
    int hh = kk / 136, k = kk - hh*136;
    for (int c = 0; c < 136; c++)
      v = fmaf(W1[(size_t)k*272 + hh*136 + c], W2[(size_t)(hh*136+c)*136 + n], v);
  }
  W12T[i] = f2u(v);
}

// attention linearity vectors: va1 = W1 a1 (272); va2 = W2 a2 (272)
__global__ void k_va(const float* __restrict__ W1, const float* __restrict__ as1, const float* __restrict__ ad1,
                     const float* __restrict__ W2, const float* __restrict__ as2, const float* __restrict__ ad2,
                     float* __restrict__ va1s, float* __restrict__ va1d,
                     float* __restrict__ va2s, float* __restrict__ va2d){
  int t = blockIdx.x*blockDim.x + threadIdx.x;
  if (t >= 272) return;
  int hh = t / 136, k = t - hh*136;
  float s = 0.f, d = 0.f;
  for (int c = 0; c < 136; c++){
    float w = W1[(size_t)k*272 + hh*136 + c];
    s = fmaf(w, as1[hh*136 + c], s);
    d = fmaf(w, ad1[hh*136 + c], d);
  }
  va1s[t] = s; va1d[t] = d;                 // layout [hh*136 + k]
  float s2 = 0.f, d2 = 0.f;
  for (int c = 0; c < 136; c++){
    float w = W2[(size_t)t*136 + c];
    s2 = fmaf(w, as2[c], s2);
    d2 = fmaf(w, ad2[c], d2);
  }
  va2s[t] = s2; va2d[t] = d2;
}

// chained: v2''[kk] = (W1_headblock @ va2)[kk] (272); cc = {bb1·va2s, bb1·va2d};
// b12[n] = bb1 @ W2 (136)
__global__ void k_va2(const float* __restrict__ W1, const float* __restrict__ W2,
                      const float* __restrict__ bb1,
                      const float* __restrict__ va2s, const float* __restrict__ va2d,
                      float* __restrict__ v2ss, float* __restrict__ v2dd,
                      float* __restrict__ cc, float* __restrict__ b12){
  int t = blockIdx.x*blockDim.x + threadIdx.x;
  if (t < 272){
    int hh = t/136, k = t - hh*136;
    float s=0.f, d=0.f;
    for (int c = 0; c < 136; c++){
      float w = W1[(size_t)k*272 + hh*136 + c];
      s = fmaf(w, va2s[hh*136+c], s);
      d = fmaf(w, va2d[hh*136+c], d);
    }
    v2ss[t] = s; v2dd[t] = d;
  } else if (t == 272){
    float s=0.f, d=0.f;
    for (int m = 0; m < 272; m++){
      s = fmaf(bb1[m], va2s[m], s);
      d = fmaf(bb1[m], va2d[m], d);
    }
    cc[0] = s; cc[1] = d;
  } else if (t >= 288 && t < 288+136){
    int n = t - 288;
    float v = 0.f;
    for (int m = 0; m < 272; m++) v = fmaf(bb1[m], W2[(size_t)m*136 + n], v);
    b12[n] = v;
  }
}

// ---------------- backbone ----------------
DEV void load_convw(float* lw, const float* wl1, const float* wl2, const float* wp1,
                    const float* wp2, const float* wg, int tid, int nth){
  for (int i = tid; i < 384; i += nth){
    float v;
    if      (i < 24)  v = wl1[i];
    else if (i < 64)  v = wl2[i-24];
    else if (i < 88)  v = wp1[i-64];
    else if (i < 128) v = wp2[i-88];
    else              v = wg [i-128];
    lw[i] = v;
  }
}

template<int KS,int DIL,int T>
DEV void conv_stats(const float* xc, const float* wk, float& s, float& q){
  #pragma unroll
  for (int t = 0; t < T; t++){
    float v = 0.f;
    #pragma unroll
    for (int j = 0; j < KS; j++) v = fmaf(wk[j], xc[t + j*DIL], v);
    s += v; q = fmaf(v, v, q);
  }
}

__global__ void __launch_bounds__(256) k_bn_stats(
    const float* __restrict__ x,
    const float* __restrict__ wl1, const float* __restrict__ wl2,
    const float* __restrict__ wp1, const float* __restrict__ wp2,
    const float* __restrict__ wg,
    float* __restrict__ gsum, float* __restrict__ gsq)
{
  __shared__ float lw[384];
  __shared__ float lacc[80];
  const int tid = threadIdx.x;
  load_convw(lw, wl1, wl2, wp1, wp2, wg, tid, 256);
  if (tid < 80) lacc[tid] = 0.f;
  __syncthreads();

  int gid = blockIdx.x*256 + tid;
  float xc[P_];
  if (gid < NODES){
    int b = gid / N0_, n = gid - b*N0_;
    const float* xp = x + (size_t)b*P_*N0_ + n;
    #pragma unroll
    for (int p = 0; p < P_; p++) xc[p] = xp[(size_t)p*N0_];
  } else {
    #pragma unroll
    for (int p = 0; p < P_; p++) xc[p] = 0.f;
  }
  const int lane = tid & 63;

  auto red = [&](int ch, float s, float q){
    #pragma unroll
    for (int o = 32; o > 0; o >>= 1){ s += __shfl_down(s,o,64); q += __shfl_down(q,o,64); }
    if (lane == 0){ atomicAdd(&lacc[ch], s); atomicAdd(&lacc[40+ch], q); }
  };

  #pragma unroll
  for (int k = 0; k < 8; k++){ float s=0,q=0; conv_stats<3,1,30>(xc, lw      + k*3 , s,q); red(k,     s,q); }
  #pragma unroll
  for (int k = 0; k < 8; k++){ float s=0,q=0; conv_stats<5,1,28>(xc, lw + 24 + k*5 , s,q); red(8+k,   s,q); }
  #pragma unroll
  for (int k = 0; k < 8; k++){ float s=0,q=0; conv_stats<3,2,28>(xc, lw + 64 + k*3 , s,q); red(16+k,  s,q); }
  #pragma unroll
  for (int k = 0; k < 8; k++){ float s=0,q=0; conv_stats<5,2,24>(xc, lw + 88 + k*5 , s,q); red(24+k,  s,q); }
  #pragma unroll
  for (int k = 0; k < 8; k++){ float s=0,q=0; conv_stats<32,1,1>(xc, lw + 128+ k*32, s,q); red(32+k,  s,q); }

  __syncthreads();
  if (tid < 40)      atomicAdd(&gsum[tid],    lacc[tid]);
  else if (tid < 80) atomicAdd(&gsq [tid-40], lacc[tid]);
}

__global__ void k_bn_fin(const float* __restrict__ gsum, const float* __restrict__ gsq,
                         float* __restrict__ sA, float* __restrict__ sB,
                         const float* g0, const float* g1, const float* g2, const float* g3, const float* g4,
                         const float* e0, const float* e1, const float* e2, const float* e3, const float* e4)
{
  int t = threadIdx.x;
  if (t >= 40) return;
  int bi = t >> 3, k = t & 7;
  const int Ts[5] = {30,28,28,24,1};
  float cnt  = (float)NODES * (float)Ts[bi];
  float mean = gsum[t] / cnt;
  float var  = gsq[t] / cnt - mean*mean;
  const float* gp = bi==0?g0: bi==1?g1: bi==2?g2: bi==3?g3: g4;
  const float* ep = bi==0?e0: bi==1?e1: bi==2?e2: bi==3?e3: e4;
  float a = gp[k] * rsqrtf(fmaxf(var, 0.f) + 1e-5f);
  sA[t] = a;
  sB[t] = ep[k] - a*mean;
}

template<int KS,int DIL,int T>
DEV void conv_pool4(const float* xc, const float* wk, float A, float Bc, float* o4){
  float y[T];
  #pragma unroll
  for (int t = 0; t < T; t++){
    float v = 0.f;
    #pragma unroll
    for (int j = 0; j < KS; j++) v = fmaf(wk[j], xc[t + j*DIL], v);
    y[t] = fmaf(A, v, Bc);
  }
  #pragma unroll
  for (int i = 0; i < 4; i++){
    const int lo = (i*T)/4, hi = ((i+1)*T + 3)/4;
    float m = y[lo];
    #pragma unroll
    for (int t = 0; t < T; t++){ if (t > lo && t < hi) m = fmaxf(m, y[t]); }
    o4[i] = m;
  }
}

// feat row-major [m][160] bf16 (tanh) + fused layer-1 attention dots.
__global__ void __launch_bounds__(256) k_feat(
    const float* __restrict__ x,
    const float* __restrict__ wl1, const float* __restrict__ wl2,
    const float* __restrict__ wp1, const float* __restrict__ wp2,
    const float* __restrict__ wg,
    const float* __restrict__ sA, const float* __restrict__ sB,
    const float* __restrict__ va1s, const float* __restrict__ va1d,
    u16* __restrict__ feat, float* __restrict__ asrc1, float* __restrict__ adst1,
    int base, int m)
{
  __shared__ float lw[384];
  __shared__ float lA[40], lB[40];
  __shared__ float lvs[272], lvd[272];
  __shared__ float sdt[128][4];
  const int tid = threadIdx.x;
  load_convw(lw, wl1, wl2, wp1, wp2, wg, tid, 256);
  if (tid < 40){ lA[tid] = sA[tid]; lB[tid] = sB[tid]; }
  for (int i = tid; i < 272; i += 256){ lvs[i] = va1s[i]; lvd[i] = va1d[i]; }
  __syncthreads();

  const int lane = tid & 63, wv = tid >> 6;
  const int nodeLocal = (wv >> 1)*64 + lane;     // 0..127
  const int half = wv & 1;                       // wave-uniform
  const int nodeIdx = blockIdx.x*128 + nodeLocal;
  const bool act = nodeIdx < m;
  const int gcl = base + (act ? nodeIdx : (m-1));
  int b = gcl / N0_, n = gcl - b*N0_;
  float xc[P_];
  const float* xp = x + (size_t)b*P_*N0_ + n;
  #pragma unroll
  for (int p = 0; p < P_; p++) xc[p] = xp[(size_t)p*N0_];

  float dt[4] = {0.f,0.f,0.f,0.f};       // s0,d0,s1,d1 (partial)
  u32 pk[4];
  u16* orow = feat + (size_t)nodeIdx*160;
  auto emit = [&](int ch, float v){
    float t = fast_tanh(v);
    dt[0] = fmaf(t, lvs[ch],     dt[0]);
    dt[1] = fmaf(t, lvd[ch],     dt[1]);
    dt[2] = fmaf(t, lvs[136+ch], dt[2]);
    dt[3] = fmaf(t, lvd[136+ch], dt[3]);
    u16 h = f2u(t);
    int s = ch & 7;
    if ((s & 1) == 0) pk[s>>1] = h;
    else              pk[s>>1] |= ((u32)h) << 16;
    if (s == 7 && act) *(uint4*)(orow + (ch - 7)) = make_uint4(pk[0],pk[1],pk[2],pk[3]);
  };

  float o4[4];
  if (half == 0){
    #pragma unroll
    for (int k = 0; k < 8; k++){
      conv_pool4<3,1,30>(xc, lw + k*3, lA[k], lB[k], o4);
      #pragma unroll
      for (int i = 0; i < 4; i++) emit(k*4+i, o4[i]);
    }
    #pragma unroll
    for (int k = 0; k < 8; k++){
      conv_pool4<5,1,28>(xc, lw + 24 + k*5, lA[8+k], lB[8+k], o4);
      #pragma unroll
      for (int i = 0; i < 4; i++) emit(32 + k*4+i, o4[i]);
    }
  } else {
    #pragma unroll
    for (int k = 0; k < 8; k++){
      conv_pool4<3,2,28>(xc, lw + 64 + k*3, lA[16+k], lB[16+k], o4);
      #pragma unroll
      for (int i = 0; i < 4; i++) emit(64 + k*4+i, o4[i]);
    }
    #pragma unroll
    for (int k = 0; k < 8; k++){
      conv_pool4<5,2,24>(xc, lw + 88 + k*5, lA[24+k], lB[24+k], o4);
      #pragma unroll
      for (int i = 0; i < 4; i++) emit(96 + k*4+i, o4[i]);
    }
    #pragma unroll
    for (int k = 0; k < 8; k++){
      float v = 0.f;
      #pragma unroll
      for (int j = 0; j < 32; j++) v = fmaf(lw[128 + k*32 + j], xc[j], v);
      emit(128 + k, fmaf(lA[32+k], v, lB[32+k]));
    }
  }

  if (half == 1){
    sdt[nodeLocal][0] = dt[0]; sdt[nodeLocal][1] = dt[1];
    sdt[nodeLocal][2] = dt[2]; sdt[nodeLocal][3] = dt[3];
  }
  __syncthreads();
  if (half == 0 && act){
    asrc1[(size_t)nodeIdx*2]   = dt[0] + sdt[nodeLocal][0];
    asrc1[(size_t)nodeIdx*2+1] = dt[2] + sdt[nodeLocal][2];
    adst1[(size_t)nodeIdx*2]   = dt[1] + sdt[nodeLocal][1];
    adst1[(size_t)nodeIdx*2+1] = dt[3] + sdt[nodeLocal][3];
  }
}

// ---------------- CSR ----------------
__global__ void k_count(const int* __restrict__ ei, int* __restrict__ counts){
  int e = blockIdx.x*blockDim.x + threadIdx.x;
  if (e >= NE_) return;
  int dst = (e < E_) ? ei[E_ + e] : (e - E_);
  atomicAdd(&counts[dst], 1);
}

__global__ void __launch_bounds__(1024) k_scan(const int* __restrict__ counts, int* __restrict__ offs){
  __shared__ int part[1024];
  int t = threadIdx.x;
  int loc[10]; int s = 0;
  #pragma unroll
  for (int i = 0; i < 10; i++){
    int idx = t*10 + i;
    int c = (idx < N0_) ? counts[idx] : 0;
    loc[i] = s; s += c;
  }
  part[t] = s;
  __syncthreads();
  for (int o = 1; o < 1024; o <<= 1){
    int v = (t >= o) ? part[t-o] : 0;
    __syncthreads();
    part[t] += v;
    __syncthreads();
  }
  int pre = (t == 0) ? 0 : part[t-1];
  #pragma unroll
  for (int i = 0; i < 10; i++){
    int idx = t*10 + i;
    if (idx < N0_) offs[idx] = pre + loc[i];
  }
  if (t == 0) offs[N0_] = part[1023];
}

__global__ void k_scatter(const int* __restrict__ ei, const int* __restrict__ offs,
                          int* __restrict__ cursor, int* __restrict__ srcl){
  int e = blockIdx.x*blockDim.x + threadIdx.x;
  if (e >= NE_) return;
  int src, dst;
  if (e < E_){ src = ei[e]; dst = ei[E_ + e]; } else { src = dst = e - E_; }
  int pos = atomicAdd(&cursor[dst], 1);
  srcl[offs[dst] + pos] = src;
}

// ---------------- MFMA GEMM: A[m][K] bf16 row-major, BT[n][K] bf16 ----------------
// EPI 0: plain; EPI 1: lrelu01(+bias); EPI 3: +bias only; EPI 2: fused head dot
template<int KT1,int KT2,int NT,int EPI>
__global__ void __launch_bounds__(256) k_mfma(
    const u16* __restrict__ A1, int sA1,
    const u16* __restrict__ A2, int sA2,
    const u16* __restrict__ BT, int sBT,
    u16* __restrict__ C, int sC, int nbase,
    const float* __restrict__ bias, int m,
    const float* __restrict__ w2v, const float* __restrict__ bo2p, float* __restrict__ fout)
{
  const int wv = threadIdx.x >> 6, lane = threadIdx.x & 63;
  const int quad = lane >> 4, l15 = lane & 15;
  const int mb = blockIdx.x*256 + wv*64;
  int ar[4];
  #pragma unroll
  for (int mt = 0; mt < 4; mt++) ar[mt] = min(mb + mt*16 + l15, m-1);

  v4f acc[4][NT];
  #pragma unroll
  for (int mt = 0; mt < 4; mt++)
    #pragma unroll
    for (int nt = 0; nt < NT; nt++)
      acc[mt][nt] = (v4f){0.f,0.f,0.f,0.f};

  for (int kt = 0; kt < KT1+KT2; kt++){
    const u16* ab; int sA, koff;
    if (KT2 == 0 || kt < KT1){ ab = A1; sA = sA1; koff = kt*32; }
    else { ab = A2; sA = sA2; koff = (kt-KT1)*32; }
    v8s a[4];
    #pragma unroll
    for (int mt = 0; mt < 4; mt++)
      a[mt] = *(const v8s*)(ab + (size_t)ar[mt]*sA + koff + quad*8);
    if (KT2 > 0 && kt >= KT1){
      #pragma unroll
      for (int mt = 0; mt < 4; mt++)
        #pragma unroll
        for (int j = 0; j < 8; j++){
          float f = u2f((u16)a[mt][j]);
          f = f > 0.f ? f : 0.01f*f;
          a[mt][j] = (short)f2u(f);
        }
    }
    const int kb = kt*32 + quad*8;
    #pragma unroll
    for (int nt = 0; nt < NT; nt++){
      v8s b = *(const v8s*)(BT + (size_t)(nbase + nt*16 + l15)*sBT + kb);
      #pragma unroll
      for (int mt = 0; mt < 4; mt++)
        acc[mt][nt] = __builtin_amdgcn_mfma_f32_16x16x32_bf16(a[mt], b, acc[mt][nt], 0, 0, 0);
    }
  }

  if (EPI == 2){
    const float bo2v = bo2p[0];
    #pragma unroll
    for (int mt = 0; mt < 4; mt++){
      float part[4] = {0.f,0.f,0.f,0.f};
      #pragma unroll
      for (int nt = 0; nt < NT; nt++){
        const int col = nt*16 + l15;
        float wv2 = (col < 136) ? w2v[col] : 0.f;
        float bv  = bias[min(col,135)];
        #pragma unroll
        for (int i = 0; i < 4; i++){
          float xv = lrelu01(acc[mt][nt][i] + bv);
          part[i] = fmaf(xv, wv2, part[i]);
        }
      }
      #pragma unroll
      for (int i = 0; i < 4; i++){
        float v = part[i];
        v += __shfl_xor(v, 1, 64);
        v += __shfl_xor(v, 2, 64);
        v += __shfl_xor(v, 4, 64);
        v += __shfl_xor(v, 8, 64);
        int r = mb + mt*16 + quad*4 + i;
        if (l15 == 0 && r < m) fout[r] = v + bo2v;
      }
    }
    return;
  }

  #pragma unroll
  for (int mt = 0; mt < 4; mt++){
    const int r0 = mb + mt*16 + quad*4;
    #pragma unroll
    for (int nt = 0; nt < NT; nt++){
      const int col = nbase + nt*16 + l15;
      #pragma unroll
      for (int i = 0; i < 4; i++){
        int r = r0 + i;
        if (r < m){
          float xv = acc[mt][nt][i];
          if (EPI == 1){ xv += bias[min(col,135)]; xv = lrelu01(xv); }
          if (EPI == 3){ xv += bias[min(col,135)]; }
          C[(size_t)r*sC + col] = f2u(xv);
        }
      }
    }
  }
}

// ---------------- layer-1 GAT aggregation on feat (gather once, 2 head accumulators) ----------------
// out aggF[node][288]: head0 ch c at [c], head1 at [136+c] (pads 272..287 untouched).
// epilogue: asrc2/adst2 = aggF·v2'' + cc  (linearity through W1+bb1)
__global__ void __launch_bounds__(256) k_agg1(const u16* __restrict__ feat,
    const float* __restrict__ asrc, const float* __restrict__ adst,
    const int* __restrict__ offs, const int* __restrict__ srcl,
    u16* __restrict__ aggF,
    const float* __restrict__ v2s, const float* __restrict__ v2d,
    const float* __restrict__ cc,
    float* __restrict__ as_out, float* __restrict__ ad_out,
    int cbMask, int cbShift)
{
  const int wv = threadIdx.x >> 6, lane = threadIdx.x & 63;
  const int id = blockIdx.x;
  const int bb = id & cbMask;
  const int dst = (id >> cbShift)*4 + wv;
  const int nbase = bb*N0_;
  const int node = nbase + dst;
  const int start = offs[dst], end = offs[dst+1];
  const int ne = end - start;

  const float ad0 = adst[(size_t)node*2], ad1v = adst[(size_t)node*2+1];

  float am0h0=0,am1h0=0,am0h1=0,am1h1=0;
  float ar0h0=0,ar1h0=0,ar0h1=0,ar1h1=0;

  auto acc_edge = [&](int sj, float c0, float c1){
    const u16* fp = feat + (size_t)sj*160;
    const ushort2 hv = *(const ushort2*)(fp + 2*lane);
    float f0 = u2f(hv.x), f1 = u2f(hv.y);
    am0h0 = fmaf(c0, f0, am0h0); am1h0 = fmaf(c0, f1, am1h0);
    am0h1 = fmaf(c1, f0, am0h1); am1h1 = fmaf(c1, f1, am1h1);
    if (lane < 4){
      const ushort2 hr = *(const ushort2*)(fp + 128 + 2*lane);
      float r0 = u2f(hr.x), r1 = u2f(hr.y);
      ar0h0 = fmaf(c0, r0, ar0h0); ar1h0 = fmaf(c0, r1, ar1h0);
      ar0h1 = fmaf(c1, r0, ar0h1); ar1h1 = fmaf(c1, r1, ar1h1);
    }
  };
  auto acc_edge2 = [&](int sj0, float c00, float c10, int sj1, float c01, float c11){
    const u16* fp0 = feat + (size_t)sj0*160;
    const u16* fp1 = feat + (size_t)sj1*160;
    const ushort2 a0 = *(const ushort2*)(fp0 + 2*lane);
    const ushort2 a1 = *(const ushort2*)(fp1 + 2*lane);
    float f00 = u2f(a0.x), f01 = u2f(a0.y);
    float f10 = u2f(a1.x), f11 = u2f(a1.y);
    am0h0 = fmaf(c00, f00, am0h0); am1h0 = fmaf(c00, f01, am1h0);
    am0h1 = fmaf(c10, f00, am0h1); am1h1 = fmaf(c10, f01, am1h1);
    am0h0 = fmaf(c01, f10, am0h0); am1h0 = fmaf(c01, f11, am1h0);
    am0h1 = fmaf(c11, f10, am0h1); am1h1 = fmaf(c11, f11, am1h1);
    if (lane < 4){
      const ushort2 r0 = *(const ushort2*)(fp0 + 128 + 2*lane);
      const ushort2 r1 = *(const ushort2*)(fp1 + 128 + 2*lane);
      float g00 = u2f(r0.x), g01 = u2f(r0.y);
      float g10 = u2f(r1.x), g11 = u2f(r1.y);
      ar0h0 = fmaf(c00, g00, ar0h0); ar1h0 = fmaf(c00, g01, ar1h0);
      ar0h1 = fmaf(c10, g00, ar0h1); ar1h1 = fmaf(c10, g01, ar1h1);
      ar0h0 = fmaf(c01, g10, ar0h0); ar1h0 = fmaf(c01, g11, ar1h0);
      ar0h1 = fmaf(c11, g10, ar0h1); ar1h1 = fmaf(c11, g11, ar1h1);
    }
  };

  if (ne <= 64){
    const bool has = lane < ne;
    const int sn = nbase + (has ? srcl[start + lane] : 0);
    float al0 = has ? lrelu02(asrc[(size_t)sn*2]   + ad0)  : -1e30f;
    float al1 = has ? lrelu02(asrc[(size_t)sn*2+1] + ad1v) : -1e30f;
    float m0 = wred_max(al0);
    float p0 = has ? __expf(al0 - m0) : 0.f;
    float c0 = p0 * (1.f/(wred_sum(p0) + 1e-16f));
    float m1 = wred_max(al1);
    float p1 = has ? __expf(al1 - m1) : 0.f;
    float c1 = p1 * (1.f/(wred_sum(p1) + 1e-16f));
    int j = 0;
    for (; j + 1 < ne; j += 2){
      int   s0 = __shfl(sn, j, 64),  s1 = __shfl(sn, j+1, 64);
      float a0 = __shfl(c0, j, 64),  a1 = __shfl(c0, j+1, 64);
      float b0 = __shfl(c1, j, 64),  b1 = __shfl(c1, j+1, 64);
      acc_edge2(s0, a0, b0, s1, a1, b1);
    }
    if (j < ne)
      acc_edge(__shfl(sn, j, 64), __shfl(c0, j, 64), __shfl(c1, j, 64));
  } else {
    float lm0 = -1e30f, lm1 = -1e30f;
    for (int e = start + lane; e < end; e += 64){
      int sn = nbase + srcl[e];
      lm0 = fmaxf(lm0, lrelu02(asrc[(size_t)sn*2]   + ad0));
      lm1 = fmaxf(lm1, lrelu02(asrc[(size_t)sn*2+1] + ad1v));
    }
    float m0 = wred_max(lm0), m1 = wred_max(lm1);
    float ls0 = 0.f, ls1 = 0.f;
    for (int e = start + lane; e < end; e += 64){
      int sn = nbase + srcl[e];
      ls0 += __expf(lrelu02(asrc[(size_t)sn*2]   + ad0)  - m0);
      ls1 += __expf(lrelu02(asrc[(size_t)sn*2+1] + ad1v) - m1);
    }
    float si0 = 1.f/(wred_sum(ls0) + 1e-16f);
    float si1 = 1.f/(wred_sum(ls1) + 1e-16f);
    for (int cs2 = start; cs2 < end; cs2 += 64){
      int cnt = min(64, end - cs2);
      bool has = lane < cnt;
      int sn = nbase + (has ? srcl[cs2 + lane] : 0);
      float c0 = 0.f, c1 = 0.f;
      if (has){
        c0 = __expf(lrelu02(asrc[(size_t)sn*2]   + ad0)  - m0) * si0;
        c1 = __expf(lrelu02(asrc[(size_t)sn*2+1] + ad1v) - m1) * si1;
      }
      for (int j = 0; j < cnt; j++)
        acc_edge(__shfl(sn, j, 64), __shfl(c0, j, 64), __shfl(c1, j, 64));
    }
  }

  // store aggF + fused layer-2 attention dots
  u16* outp = aggF + (size_t)node*288;
  {
    int c = 2*lane;
    ushort2 s0; s0.x = f2u(am0h0); s0.y = f2u(am1h0);
    *(ushort2*)(outp + c) = s0;
    ushort2 s1; s1.x = f2u(am0h1); s1.y = f2u(am1h1);
    *(ushort2*)(outp + 136 + c) = s1;
    if (lane < 4){
      int cr = 128 + 2*lane;
      ushort2 r0; r0.x = f2u(ar0h0); r0.y = f2u(ar1h0);
      *(ushort2*)(outp + cr) = r0;
      ushort2 r1; r1.x = f2u(ar0h1); r1.y = f2u(ar1h1);
      *(ushort2*)(outp + 136 + cr) = r1;
    }
  }
  {
    int c = 2*lane;
    float s = am0h0*v2s[c] + am1h0*v2s[c+1] + am0h1*v2s[136+c] + am1h1*v2s[136+c+1];
    float d = am0h0*v2d[c] + am1h0*v2d[c+1] + am0h1*v2d[136+c] + am1h1*v2d[136+c+1];
    if (lane < 4){
      int cr = 128 + 2*lane;
      s += ar0h0*v2s[cr] + ar1h0*v2s[cr+1] + ar0h1*v2s[136+cr] + ar1h1*v2s[136+cr+1];
      d += ar0h0*v2d[cr] + ar1h0*v2d[cr+1] + ar0h1*v2d[136+cr] + ar1h1*v2d[136+cr+1];
    }
    s = wred_sum(s); d = wred_sum(d);
    if (lane == 0){ as_out[node] = s + cc[0]; ad_out[node] = d + cc[1]; }
  }
}

// ---------------- generic GAT aggregation (used for layer 2, H=1) ----------------
template<int H,int CT,int LACT,int ATTN>
__global__ void __launch_bounds__(256) k_agg(const u16* __restrict__ h, int sh,
    const float* __restrict__ asrc, const float* __restrict__ adst,
    const int* __restrict__ offs, const int* __restrict__ srcl,
    const float* __restrict__ bias, u16* __restrict__ outp0, int so,
    const float* __restrict__ vas, const float* __restrict__ vad,
    float* __restrict__ as_out, float* __restrict__ ad_out,
    int cbMask, int cbShift)
{
  constexpr int CC   = CT/H;
  constexpr int VEC  = (CT >= 256) ? 4 : 2;
  constexpr int MAINC= 64*VEC;
  constexpr int REMV = (CT - MAINC)/VEC;

  const int wv = threadIdx.x >> 6, lane = threadIdx.x & 63;
  const int id = blockIdx.x;
  const int bb = id & cbMask;
  const int dst = (id >> cbShift)*4 + wv;
  const int nbase = bb*N0_;
  const int node = nbase + dst;
  const int start = offs[dst], end = offs[dst+1];
  const int ne = end - start;

  float adh[H];
  #pragma unroll
  for (int hh = 0; hh < H; hh++) adh[hh] = adst[(size_t)node*H + hh];

  float accm[VEC], accr[VEC];
  #pragma unroll
  for (int i = 0; i < VEC; i++){ accm[i] = 0.f; accr[i] = 0.f; }

  const bool hi = (H == 2) && (VEC*lane >= CC);

  auto acc_edge = [&](int sj, float c0, float c1){
    const u16* hp = h + (size_t)sj*sh;
    float w  = hi ? c1 : c0;
    float wr = (H == 2) ? c1 : c0;
    const ushort2 hv = *(const ushort2*)(hp + 2*lane);
    accm[0] = fmaf(w, u2f(hv.x), accm[0]);
    accm[1] = fmaf(w, u2f(hv.y), accm[1]);
    if (lane < REMV){
      const ushort2 hr = *(const ushort2*)(hp + MAINC + 2*lane);
      accr[0] = fmaf(wr, u2f(hr.x), accr[0]);
      accr[1] = fmaf(wr, u2f(hr.y), accr[1]);
    }
  };
  auto acc_edge2 = [&](int sj0, float c00, float c10, int sj1, float c01, float c11){
    const u16* hp0 = h + (size_t)sj0*sh;
    const u16* hp1 = h + (size_t)sj1*sh;
    float w0  = hi ? c10 : c00;
    float w1  = hi ? c11 : c01;
    float wr0 = (H == 2) ? c10 : c00;
    float wr1 = (H == 2) ? c11 : c01;
    const ushort2 a0 = *(const ushort2*)(hp0 + 2*lane);
    const ushort2 a1 = *(const ushort2*)(hp1 + 2*lane);
    accm[0] = fmaf(w0, u2f(a0.x), accm[0]);
    accm[1] = fmaf(w0, u2f(a0.y), accm[1]);
    accm[0] = fmaf(w1, u2f(a1.x), accm[0]);
    accm[1] = fmaf(w1, u2f(a1.y), accm[1]);
    if (lane < REMV){
      const ushort2 r0 = *(const ushort2*)(hp0 + MAINC + 2*lane);
      const ushort2 r1 = *(const ushort2*)(hp1 + MAINC + 2*lane);
      accr[0] = fmaf(wr0, u2f(r0.x), accr[0]);
      accr[1] = fmaf(wr0, u2f(r0.y), accr[1]);
      accr[0] = fmaf(wr1, u2f(r1.x), accr[0]);
      accr[1] = fmaf(wr1, u2f(r1.y), accr[1]);
    }
  };

  if (ne <= 64){
    const bool has = lane < ne;
    const int sn = nbase + (has ? srcl[start + lane] : 0);
    float al[H], p[H];
    #pragma unroll
    for (int hh = 0; hh < H; hh++)
      al[hh] = has ? lrelu02(asrc[(size_t)sn*H + hh] + adh[hh]) : -1e30f;
    float c0 = 0.f, c1 = 0.f;
    #pragma unroll
    for (int hh = 0; hh < H; hh++){
      float m = wred_max(al[hh]);
      p[hh] = has ? __expf(al[hh] - m) : 0.f;
      float sinv = 1.f/(wred_sum(p[hh]) + 1e-16f);
      if (hh == 0) c0 = p[0]*sinv; else c1 = p[1]*sinv;
    }
    if (H == 1) c1 = c0;
    int j = 0;
    for (; j + 1 < ne; j += 2){
      int   s0 = __shfl(sn, j, 64),  s1 = __shfl(sn, j+1, 64);
      float a0 = __shfl(c0, j, 64),  a1 = __shfl(c0, j+1, 64);
      float b0, b1;
      if (H == 2){ b0 = __shfl(c1, j, 64); b1 = __shfl(c1, j+1, 64); }
      else       { b0 = a0; b1 = a1; }
      acc_edge2(s0, a0, b0, s1, a1, b1);
    }
    if (j < ne)
      acc_edge(__shfl(sn, j, 64), __shfl(c0, j, 64), (H==2) ? __shfl(c1, j, 64) : __shfl(c0, j, 64));
  } else {
    float lm[H], m[H], sinv[H];
    #pragma unroll
    for (int hh = 0; hh < H; hh++) lm[hh] = -1e30f;
    for (int e = start + lane; e < end; e += 64){
      int sn = nbase + srcl[e];
      #pragma unroll
      for (int hh = 0; hh < H; hh++)
        lm[hh] = fmaxf(lm[hh], lrelu02(asrc[(size_t)sn*H + hh] + adh[hh]));
    }
    #pragma unroll
    for (int hh = 0; hh < H; hh++) m[hh] = wred_max(lm[hh]);
    float ls[H];
    #pragma unroll
    for (int hh = 0; hh < H; hh++) ls[hh] = 0.f;
    for (int e = start + lane; e < end; e += 64){
      int sn = nbase + srcl[e];
      #pragma unroll
      for (int hh = 0; hh < H; hh++)
        ls[hh] += __expf(lrelu02(asrc[(size_t)sn*H + hh] + adh[hh]) - m[hh]);
    }
    #pragma unroll
    for (int hh = 0; hh < H; hh++) sinv[hh] = 1.f/(wred_sum(ls[hh]) + 1e-16f);
    for (int cs = start; cs < end; cs += 64){
      int cnt = min(64, end - cs);
      bool has = lane < cnt;
      int sn = nbase + (has ? srcl[cs + lane] : 0);
      float c0 = 0.f, c1 = 0.f;
      if (has){
        #pragma unroll
        for (int hh = 0; hh < H; hh++){
          float p = __expf(lrelu02(asrc[(size_t)sn*H + hh] + adh[hh]) - m[hh]) * sinv[hh];
          if (hh == 0) c0 = p; else c1 = p;
        }
        if (H == 1) c1 = c0;
      }
      for (int j = 0; j < cnt; j++)
        acc_edge(__shfl(sn, j, 64), __shfl(c0, j, 64), (H==2) ? __shfl(c1, j, 64) : __shfl(c0, j, 64));
    }
  }

  u16* outp = outp0 + (size_t)node*so;
  float fm[VEC], fr[VEC];
  #pragma unroll
  for (int i = 0; i < VEC; i++){
    int c = VEC*lane + i;
    float r = accm[i] + bias[c];
    if (LACT) r = lrelu01(r);
    fm[i] = r;
  }
  if (lane < REMV){
    #pragma unroll
    for (int i = 0; i < VEC; i++){
      int cr = MAINC + VEC*lane + i;
      float r = accr[i] + bias[cr];
      if (LACT) r = lrelu01(r);
      fr[i] = r;
    }
  }
  ushort2 st; st.x=f2u(fm[0]); st.y=f2u(fm[1]);
  *(ushort2*)(outp + 2*lane) = st;
  if (lane < REMV){
    ushort2 sr; sr.x=f2u(fr[0]); sr.y=f2u(fr[1]);
    *(ushort2*)(outp + MAINC + 2*lane) = sr;
  }

  if (ATTN){
    float s = 0.f, d = 0.f;
    #pragma unroll
    for (int i = 0; i < VEC; i++){
      int c = VEC*lane + i;
      s = fmaf(fm[i], vas[c], s);
      d = fmaf(fm[i], vad[c], d);
    }
    if (lane < REMV){
      #pragma unroll
      for (int i = 0; i < VEC; i++){
        int cr = MAINC + VEC*lane + i;
        s = fmaf(fr[i], vas[cr], s);
        d = fmaf(fr[i], vad[cr], d);
      }
    }
    s = wred_sum(s); d = wred_sum(d);
    if (lane == 0){ as_out[node] = s; ad_out[node] = d; }
  }
}

// ---------------- launch ----------------
extern "C" void kernel_launch(void* const* d_in, const int* in_sizes, int n_in,
                              void* d_out, int out_size, void* d_ws, size_t ws_size,
                              hipStream_t stream)
{
  (void)in_sizes; (void)n_in; (void)out_size;
  const float* x    = (const float*)d_in[0];
  const float* wl1  = (const float*)d_in[1];
  const float* gl1  = (const float*)d_in[3];
  const float* bel1 = (const float*)d_in[4];
  const float* wl2  = (const float*)d_in[5];
  const float* gl2  = (const float*)d_in[7];
  const float* bel2 = (const float*)d_in[8];
  const float* wp1  = (const float*)d_in[9];
  const float* gp1  = (const float*)d_in[11];
  const float* bep1 = (const float*)d_in[12];
  const float* wp2  = (const float*)d_in[13];
  const float* gp2  = (const float*)d_in[15];
  const float* bep2 = (const float*)d_in[16];
  const float* wg   = (const float*)d_in[17];
  const float* gg   = (const float*)d_in[19];
  const float* beg  = (const float*)d_in[20];
  const float* W1   = (const float*)d_in[21];
  const float* as1  = (const float*)d_in[22];
  const float* ad1  = (const float*)d_in[23];
  const float* bb1  = (const float*)d_in[24];
  const float* W2   = (const float*)d_in[25];
  const float* as2  = (const float*)d_in[26];
  const float* ad2  = (const float*)d_in[27];
  const float* bb2  = (const float*)d_in[28];
  const float* Wo   = (const float*)d_in[29];
  const float* bo   = (const float*)d_in[30];
  const float* Wo2  = (const float*)d_in[31];
  const float* bo2  = (const float*)d_in[32];
  const int*   ei   = (const int*)d_in[33];

  const size_t STATIC_BYTES = 1200000;
  int nc = 1;
  while (nc < 8 && STATIC_BYTES + (size_t)1536*(NODES/nc) > ws_size) nc <<= 1;
  const int CB = B_/nc, CN = CB*N0_;
  int cbShift = 0; while ((1 << cbShift) < CB) cbShift++;
  const int cbMask = CB - 1;

  char* wsb = (char*)d_ws; size_t off = 0;
  auto alloc = [&](size_t nbytes)->void*{
    void* p = wsb + off; off = (off + nbytes + 255) & ~(size_t)255; return p;
  };
  int*   zbase  = (int*)  alloc(20080*sizeof(int));
  float* gsum   = (float*)zbase;
  float* gsq    = gsum + 40;
  int*   counts = zbase + 80;
  int*   cursor = counts + 10000;
  float* sA     = (float*)alloc(40*sizeof(float));
  float* sB     = (float*)alloc(40*sizeof(float));
  int*   offs   = (int*)  alloc(10001*sizeof(int));
  int*   srcl   = (int*)  alloc((size_t)NE_*sizeof(int));
  u16*   W12T   = (u16*)  alloc((size_t)144*288*2);
  u16*   WoT    = (u16*)  alloc((size_t)144*320*2);
  float* va1s   = (float*)alloc(272*sizeof(float));
  float* va1d   = (float*)alloc(272*sizeof(float));
  float* va2s   = (float*)alloc(272*sizeof(float));
  float* va2d   = (float*)alloc(272*sizeof(float));
  float* v2ss   = (float*)alloc(272*sizeof(float));
  float* v2dd   = (float*)alloc(272*sizeof(float));
  float* ccv    = (float*)alloc(2*sizeof(float));
  float* b12    = (float*)alloc(136*sizeof(float));
  u16*   feat   = (u16*)  alloc((size_t)CN*160*2);
  u16*   aggF   = (u16*)  alloc((size_t)CN*288*2);
  u16*   h2     = (u16*)  alloc((size_t)CN*144*2);
  u16*   g2l    = (u16*)  alloc((size_t)CN*160*2);
  float* asrc1  = (float*)alloc((size_t)CN*2*sizeof(float));
  float* adst1  = (float*)alloc((size_t)CN*2*sizeof(float));
  float* asrc2  = (float*)alloc((size_t)CN*sizeof(float));
  float* adst2  = (float*)alloc((size_t)CN*sizeof(float));

  k_zero<<<79,256,0,stream>>>(zbase, 20080);

  k_bn_stats<<<313,256,0,stream>>>(x, wl1,wl2,wp1,wp2,wg, gsum, gsq);
  k_bn_fin  <<<1,64,0,stream>>>(gsum, gsq, sA, sB, gl1,gl2,gp1,gp2,gg, bel1,bel2,bep1,bep2,beg);

  k_count  <<<665,256,0,stream>>>(ei, counts);
  k_scan   <<<1,1024,0,stream>>>(counts, offs);
  k_scatter<<<665,256,0,stream>>>(ei, offs, cursor, srcl);

  k_wt <<<180,256,0,stream>>>(WoT, Wo, 144, 320, 136, 0, 1);
  k_w12<<<162,256,0,stream>>>(W1, W2, W12T);
  k_va <<<2,256,0,stream>>>(W1, as1, ad1, W2, as2, ad2, va1s, va1d, va2s, va2d);
  k_va2<<<2,256,0,stream>>>(W1, W2, bb1, va2s, va2d, v2ss, v2dd, ccv, b12);

  const int gx  = (CN + 255)/256;
  const int gx2 = (CN + 127)/128;
  const int aggB = 2500*CB;
  for (int c = 0; c < nc; c++){
    const int base = c*CN;

    k_feat<<<gx2,256,0,stream>>>(x, wl1,wl2,wp1,wp2,wg, sA, sB, va1s, va1d,
                                 feat, asrc1, adst1, base, CN);

    k_agg1<<<aggB,256,0,stream>>>(feat, asrc1, adst1, offs, srcl, aggF,
                                  v2ss, v2dd, ccv, asrc2, adst2, cbMask, cbShift);

    k_mfma<9,0,9,3><<<gx,256,0,stream>>>(aggF,288, (const u16*)0,0, W12T,288, h2,144, 0, b12, CN,
                                         (const float*)0,(const float*)0,(float*)0);

    k_agg<1,136,1,0><<<aggB,256,0,stream>>>(h2,144, asrc2, adst2, offs, srcl, bb2, g2l,160,
                                            (const float*)0,(const float*)0,(float*)0,(float*)0, cbMask, cbShift);

    k_mfma<5,5,9,2><<<gx,256,0,stream>>>(g2l,160, feat,160, WoT,320, (u16*)0,0, 0, bo, CN,
                                         Wo2, bo2, (float*)d_out + base);
  }
}

// Round 11
// 519.805 us; speedup vs baseline: 1.6878x; 1.0808x over previous
//
#include <hip/hip_runtime.h>
#include <hip/hip_bf16.h>
#include <math.h>

typedef unsigned short u16;
typedef unsigned int   u32;
typedef short v8s __attribute__((ext_vector_type(8)));
typedef float v4f __attribute__((ext_vector_type(4)));
#define DEV static __device__ __forceinline__

DEV float u2f(u16 u){ union{u32 i; float f;} v; v.i = ((u32)u)<<16; return v.f; }
DEV u16   f2u(float f){ union{float ff; u32 i;} v; v.ff = f; u32 r = v.i + 0x7fffu + ((v.i>>16)&1u); return (u16)(r>>16); }
DEV float lrelu02(float x){ return x > 0.f ? x : 0.2f*x; }
DEV float lrelu01(float x){ return x > 0.f ? x : 0.01f*x; }
DEV float fast_tanh(float x){
  float cx = fminf(fmaxf(x, -15.f), 15.f);
  float e = __expf(2.f*cx);
  return (e - 1.f) * __builtin_amdgcn_rcpf(e + 1.f);
}
DEV float wred_max(float v){
  #pragma unroll
  for (int o = 32; o > 0; o >>= 1) v = fmaxf(v, __shfl_xor(v, o, 64));
  return v;
}
DEV float wred_sum(float v){
  #pragma unroll
  for (int o = 32; o > 0; o >>= 1) v += __shfl_xor(v, o, 64);
  return v;
}

constexpr int B_   = 8;
constexpr int P_   = 32;
constexpr int N0_  = 10000;
constexpr int NODES = B_ * N0_;      // 80000
constexpr int E_   = 160000;
constexpr int NE_  = E_ + N0_;       // 170000

// ---------------- merged setup: zero | WoT | W12T | va1 | v2''/cc/b12 ----------------
__global__ void __launch_bounds__(256) k_setup(int* __restrict__ zbase,
    const float* __restrict__ Wo, u16* __restrict__ WoT,
    const float* __restrict__ W1, const float* __restrict__ W2, u16* __restrict__ W12T,
    const float* __restrict__ as1, const float* __restrict__ ad1,
    float* __restrict__ va1s, float* __restrict__ va1d,
    const float* __restrict__ as2, const float* __restrict__ ad2,
    const float* __restrict__ bb1,
    float* __restrict__ v2ss, float* __restrict__ v2dd,
    float* __restrict__ cc, float* __restrict__ b12)
{
  __shared__ float l2s[272], l2d[272];
  int blk = blockIdx.x, tid = threadIdx.x;
  if (blk < 79){ int i = blk*256 + tid; if (i < 20080) zbase[i] = 0; return; }
  blk -= 79;
  if (blk < 180){           // WoT[n][k] (144x320), head split
    int i = blk*256 + tid; if (i >= 144*320) return;
    int n = i/320, k = i - n*320; float v = 0.f;
    if (n < 136){
      if (k < 136) v = Wo[(size_t)k*136 + n];
      else if (k >= 160 && k < 296) v = Wo[(size_t)(k-24)*136 + n];
    }
    WoT[i] = f2u(v); return;
  }
  blk -= 180;
  if (blk < 162){           // W12T[n][kk] (144x288) = (W1@W2)^T per head-block
    int i = blk*256 + tid; if (i >= 144*288) return;
    int n = i/288, kk = i - n*288; float v = 0.f;
    if (n < 136 && kk < 272){
      int hh = kk/136, k = kk - hh*136;
      for (int c = 0; c < 136; c++)
        v = fmaf(W1[(size_t)k*272 + hh*136 + c], W2[(size_t)(hh*136+c)*136 + n], v);
    }
    W12T[i] = f2u(v); return;
  }
  blk -= 162;
  if (blk < 2){             // va1 = W1 a1 (272)
    int t = blk*256 + tid; if (t >= 272) return;
    int hh = t/136, k = t - hh*136; float s = 0.f, d = 0.f;
    for (int c = 0; c < 136; c++){
      float w = W1[(size_t)k*272 + hh*136 + c];
      s = fmaf(w, as1[hh*136+c], s);
      d = fmaf(w, ad1[hh*136+c], d);
    }
    va1s[t] = s; va1d[t] = d; return;
  }
  blk -= 2;
  {                         // v2'' = W1@(W2 a2); cc = bb1·(W2 a2); b12 = bb1@W2
    // stage va2 = W2 a2 in LDS (per block)
    for (int m = tid; m < 272; m += 256){
      float vs = 0.f, vd = 0.f;
      for (int n2 = 0; n2 < 136; n2++){
        float w2 = W2[(size_t)m*136 + n2];
        vs = fmaf(w2, as2[n2], vs);
        vd = fmaf(w2, ad2[n2], vd);
      }
      l2s[m] = vs; l2d[m] = vd;
    }
    __syncthreads();
    int t0 = blk*256 + tid;
    if (t0 < 272){
      int hh = t0/136, k = t0 - hh*136; float s = 0.f, d = 0.f;
      for (int c = 0; c < 136; c++){
        float w = W1[(size_t)k*272 + hh*136 + c];
        s = fmaf(w, l2s[hh*136+c], s);
        d = fmaf(w, l2d[hh*136+c], d);
      }
      v2ss[t0] = s; v2dd[t0] = d;
    }
    if (blk == 1){
      if (tid < 64){
        float s = 0.f, d = 0.f;
        for (int m = tid; m < 272; m += 64){
          s = fmaf(bb1[m], l2s[m], s);
          d = fmaf(bb1[m], l2d[m], d);
        }
        s = wred_sum(s); d = wred_sum(d);
        if (tid == 0){ cc[0] = s; cc[1] = d; }
      } else if (tid < 200){
        int n2 = tid - 64; float v = 0.f;
        for (int m = 0; m < 272; m++) v = fmaf(bb1[m], W2[(size_t)m*136 + n2], v);
        b12[n2] = v;
      }
    }
  }
}

// ---------------- backbone ----------------
DEV void load_convw(float* lw, const float* wl1, const float* wl2, const float* wp1,
                    const float* wp2, const float* wg, int tid, int nth){
  for (int i = tid; i < 384; i += nth){
    float v;
    if      (i < 24)  v = wl1[i];
    else if (i < 64)  v = wl2[i-24];
    else if (i < 88)  v = wp1[i-64];
    else if (i < 128) v = wp2[i-88];
    else              v = wg [i-128];
    lw[i] = v;
  }
}

template<int KS,int DIL,int T>
DEV void conv_stats(const float* xc, const float* wk, float& s, float& q){
  #pragma unroll
  for (int t = 0; t < T; t++){
    float v = 0.f;
    #pragma unroll
    for (int j = 0; j < KS; j++) v = fmaf(wk[j], xc[t + j*DIL], v);
    s += v; q = fmaf(v, v, q);
  }
}

// 2 waves per 64-node group: half0 = l1+l2 (ch 0..15), half1 = p1+p2+g (ch 16..39)
__global__ void __launch_bounds__(256) k_bn_stats(
    const float* __restrict__ x,
    const float* __restrict__ wl1, const float* __restrict__ wl2,
    const float* __restrict__ wp1, const float* __restrict__ wp2,
    const float* __restrict__ wg,
    float* __restrict__ gsum, float* __restrict__ gsq)
{
  __shared__ float lw[384];
  __shared__ float lacc[80];
  const int tid = threadIdx.x;
  load_convw(lw, wl1, wl2, wp1, wp2, wg, tid, 256);
  if (tid < 80) lacc[tid] = 0.f;
  __syncthreads();

  const int lane = tid & 63, wv = tid >> 6;
  const int nodeLocal = (wv >> 1)*64 + lane;
  const int half = wv & 1;
  const int gid = blockIdx.x*128 + nodeLocal;
  float xc[P_];
  if (gid < NODES){
    int b = gid / N0_, n = gid - b*N0_;
    const float* xp = x + (size_t)b*P_*N0_ + n;
    #pragma unroll
    for (int p = 0; p < P_; p++) xc[p] = xp[(size_t)p*N0_];
  } else {
    #pragma unroll
    for (int p = 0; p < P_; p++) xc[p] = 0.f;
  }

  auto red = [&](int ch, float s, float q){
    #pragma unroll
    for (int o = 32; o > 0; o >>= 1){ s += __shfl_down(s,o,64); q += __shfl_down(q,o,64); }
    if (lane == 0){ atomicAdd(&lacc[ch], s); atomicAdd(&lacc[40+ch], q); }
  };

  if (half == 0){
    #pragma unroll
    for (int k = 0; k < 8; k++){ float s=0,q=0; conv_stats<3,1,30>(xc, lw      + k*3 , s,q); red(k,     s,q); }
    #pragma unroll
    for (int k = 0; k < 8; k++){ float s=0,q=0; conv_stats<5,1,28>(xc, lw + 24 + k*5 , s,q); red(8+k,   s,q); }
  } else {
    #pragma unroll
    for (int k = 0; k < 8; k++){ float s=0,q=0; conv_stats<3,2,28>(xc, lw + 64 + k*3 , s,q); red(16+k,  s,q); }
    #pragma unroll
    for (int k = 0; k < 8; k++){ float s=0,q=0; conv_stats<5,2,24>(xc, lw + 88 + k*5 , s,q); red(24+k,  s,q); }
    #pragma unroll
    for (int k = 0; k < 8; k++){ float s=0,q=0; conv_stats<32,1,1>(xc, lw + 128+ k*32, s,q); red(32+k,  s,q); }
  }

  __syncthreads();
  if (tid < 40)      atomicAdd(&gsum[tid],    lacc[tid]);
  else if (tid < 80) atomicAdd(&gsq [tid-40], lacc[tid]);
}

__global__ void k_bn_fin(const float* __restrict__ gsum, const float* __restrict__ gsq,
                         float* __restrict__ sA, float* __restrict__ sB,
                         const float* g0, const float* g1, const float* g2, const float* g3, const float* g4,
                         const float* e0, const float* e1, const float* e2, const float* e3, const float* e4)
{
  int t = threadIdx.x;
  if (t >= 40) return;
  int bi = t >> 3, k = t & 7;
  const int Ts[5] = {30,28,28,24,1};
  float cnt  = (float)NODES * (float)Ts[bi];
  float mean = gsum[t] / cnt;
  float var  = gsq[t] / cnt - mean*mean;
  const float* gp = bi==0?g0: bi==1?g1: bi==2?g2: bi==3?g3: g4;
  const float* ep = bi==0?e0: bi==1?e1: bi==2?e2: bi==3?e3: e4;
  float a = gp[k] * rsqrtf(fmaxf(var, 0.f) + 1e-5f);
  sA[t] = a;
  sB[t] = ep[k] - a*mean;
}

template<int KS,int DIL,int T>
DEV void conv_pool4(const float* xc, const float* wk, float A, float Bc, float* o4){
  float y[T];
  #pragma unroll
  for (int t = 0; t < T; t++){
    float v = 0.f;
    #pragma unroll
    for (int j = 0; j < KS; j++) v = fmaf(wk[j], xc[t + j*DIL], v);
    y[t] = fmaf(A, v, Bc);
  }
  #pragma unroll
  for (int i = 0; i < 4; i++){
    const int lo = (i*T)/4, hi = ((i+1)*T + 3)/4;
    float m = y[lo];
    #pragma unroll
    for (int t = 0; t < T; t++){ if (t > lo && t < hi) m = fmaxf(m, y[t]); }
    o4[i] = m;
  }
}

// feat [m][160] bf16 (tanh) + featL [m][160] bf16 (lrelu01 of tanh) + fused layer-1 attention dots.
__global__ void __launch_bounds__(256) k_feat(
    const float* __restrict__ x,
    const float* __restrict__ wl1, const float* __restrict__ wl2,
    const float* __restrict__ wp1, const float* __restrict__ wp2,
    const float* __restrict__ wg,
    const float* __restrict__ sA, const float* __restrict__ sB,
    const float* __restrict__ va1s, const float* __restrict__ va1d,
    u16* __restrict__ feat, u16* __restrict__ featL,
    float* __restrict__ asrc1, float* __restrict__ adst1,
    int base, int m)
{
  __shared__ float lw[384];
  __shared__ float lA[40], lB[40];
  __shared__ float lvs[272], lvd[272];
  __shared__ float sdt[128][4];
  const int tid = threadIdx.x;
  load_convw(lw, wl1, wl2, wp1, wp2, wg, tid, 256);
  if (tid < 40){ lA[tid] = sA[tid]; lB[tid] = sB[tid]; }
  for (int i = tid; i < 272; i += 256){ lvs[i] = va1s[i]; lvd[i] = va1d[i]; }
  __syncthreads();

  const int lane = tid & 63, wv = tid >> 6;
  const int nodeLocal = (wv >> 1)*64 + lane;     // 0..127
  const int half = wv & 1;                       // wave-uniform
  const int nodeIdx = blockIdx.x*128 + nodeLocal;
  const bool act = nodeIdx < m;
  const int gcl = base + (act ? nodeIdx : (m-1));
  int b = gcl / N0_, n = gcl - b*N0_;
  float xc[P_];
  const float* xp = x + (size_t)b*P_*N0_ + n;
  #pragma unroll
  for (int p = 0; p < P_; p++) xc[p] = xp[(size_t)p*N0_];

  float dt[4] = {0.f,0.f,0.f,0.f};
  u32 pk[4], pkl[4];
  u16* orow  = feat  + (size_t)nodeIdx*160;
  u16* olrow = featL + (size_t)nodeIdx*160;
  auto emit = [&](int ch, float v){
    float t = fast_tanh(v);
    dt[0] = fmaf(t, lvs[ch],     dt[0]);
    dt[1] = fmaf(t, lvd[ch],     dt[1]);
    dt[2] = fmaf(t, lvs[136+ch], dt[2]);
    dt[3] = fmaf(t, lvd[136+ch], dt[3]);
    u16 h  = f2u(t);
    u16 hl = f2u(lrelu01(t));
    int s = ch & 7;
    if ((s & 1) == 0){ pk[s>>1] = h;                pkl[s>>1] = hl; }
    else             { pk[s>>1] |= ((u32)h) << 16;  pkl[s>>1] |= ((u32)hl) << 16; }
    if (s == 7 && act){
      *(uint4*)(orow  + (ch - 7)) = make_uint4(pk[0],pk[1],pk[2],pk[3]);
      *(uint4*)(olrow + (ch - 7)) = make_uint4(pkl[0],pkl[1],pkl[2],pkl[3]);
    }
  };

  float o4[4];
  if (half == 0){
    #pragma unroll
    for (int k = 0; k < 8; k++){
      conv_pool4<3,1,30>(xc, lw + k*3, lA[k], lB[k], o4);
      #pragma unroll
      for (int i = 0; i < 4; i++) emit(k*4+i, o4[i]);
    }
    #pragma unroll
    for (int k = 0; k < 8; k++){
      conv_pool4<5,1,28>(xc, lw + 24 + k*5, lA[8+k], lB[8+k], o4);
      #pragma unroll
      for (int i = 0; i < 4; i++) emit(32 + k*4+i, o4[i]);
    }
  } else {
    #pragma unroll
    for (int k = 0; k < 8; k++){
      conv_pool4<3,2,28>(xc, lw + 64 + k*3, lA[16+k], lB[16+k], o4);
      #pragma unroll
      for (int i = 0; i < 4; i++) emit(64 + k*4+i, o4[i]);
    }
    #pragma unroll
    for (int k = 0; k < 8; k++){
      conv_pool4<5,2,24>(xc, lw + 88 + k*5, lA[24+k], lB[24+k], o4);
      #pragma unroll
      for (int i = 0; i < 4; i++) emit(96 + k*4+i, o4[i]);
    }
    #pragma unroll
    for (int k = 0; k < 8; k++){
      float v = 0.f;
      #pragma unroll
      for (int j = 0; j < 32; j++) v = fmaf(lw[128 + k*32 + j], xc[j], v);
      emit(128 + k, fmaf(lA[32+k], v, lB[32+k]));
    }
  }

  if (half == 1){
    sdt[nodeLocal][0] = dt[0]; sdt[nodeLocal][1] = dt[1];
    sdt[nodeLocal][2] = dt[2]; sdt[nodeLocal][3] = dt[3];
  }
  __syncthreads();
  if (half == 0 && act){
    asrc1[(size_t)nodeIdx*2]   = dt[0] + sdt[nodeLocal][0];
    asrc1[(size_t)nodeIdx*2+1] = dt[2] + sdt[nodeLocal][2];
    adst1[(size_t)nodeIdx*2]   = dt[1] + sdt[nodeLocal][1];
    adst1[(size_t)nodeIdx*2+1] = dt[3] + sdt[nodeLocal][3];
  }
}

// ---------------- CSR ----------------
__global__ void k_count(const int* __restrict__ ei, int* __restrict__ counts){
  int e = blockIdx.x*blockDim.x + threadIdx.x;
  if (e >= NE_) return;
  int dst = (e < E_) ? ei[E_ + e] : (e - E_);
  atomicAdd(&counts[dst], 1);
}

__global__ void __launch_bounds__(1024) k_scan(const int* __restrict__ counts, int* __restrict__ offs){
  __shared__ int part[1024];
  int t = threadIdx.x;
  int loc[10]; int s = 0;
  #pragma unroll
  for (int i = 0; i < 10; i++){
    int idx = t*10 + i;
    int c = (idx < N0_) ? counts[idx] : 0;
    loc[i] = s; s += c;
  }
  part[t] = s;
  __syncthreads();
  for (int o = 1; o < 1024; o <<= 1){
    int v = (t >= o) ? part[t-o] : 0;
    __syncthreads();
    part[t] += v;
    __syncthreads();
  }
  int pre = (t == 0) ? 0 : part[t-1];
  #pragma unroll
  for (int i = 0; i < 10; i++){
    int idx = t*10 + i;
    if (idx < N0_) offs[idx] = pre + loc[i];
  }
  if (t == 0) offs[N0_] = part[1023];
}

__global__ void k_scatter(const int* __restrict__ ei, const int* __restrict__ offs,
                          int* __restrict__ cursor, int* __restrict__ srcl){
  int e = blockIdx.x*blockDim.x + threadIdx.x;
  if (e >= NE_) return;
  int src, dst;
  if (e < E_){ src = ei[e]; dst = ei[E_ + e]; } else { src = dst = e - E_; }
  int pos = atomicAdd(&cursor[dst], 1);
  srcl[offs[dst] + pos] = src;
}

// ---------------- MFMA GEMM: A[m][K] bf16 row-major, BT[n][K] bf16 ----------------
// EPI 0: plain; EPI 1: lrelu01(+bias); EPI 3: +bias only; EPI 2: fused head dot
// LR2: apply lrelu01 to A2 fragments on the fly (0 when A2 is pre-activated)
template<int KT1,int KT2,int NT,int EPI,int LR2>
__global__ void __launch_bounds__(256) k_mfma(
    const u16* __restrict__ A1, int sA1,
    const u16* __restrict__ A2, int sA2,
    const u16* __restrict__ BT, int sBT,
    u16* __restrict__ C, int sC, int nbase,
    const float* __restrict__ bias, int m,
    const float* __restrict__ w2v, const float* __restrict__ bo2p, float* __restrict__ fout)
{
  const int wv = threadIdx.x >> 6, lane = threadIdx.x & 63;
  const int quad = lane >> 4, l15 = lane & 15;
  const int mb = blockIdx.x*256 + wv*64;
  int ar[4];
  #pragma unroll
  for (int mt = 0; mt < 4; mt++) ar[mt] = min(mb + mt*16 + l15, m-1);

  v4f acc[4][NT];
  #pragma unroll
  for (int mt = 0; mt < 4; mt++)
    #pragma unroll
    for (int nt = 0; nt < NT; nt++)
      acc[mt][nt] = (v4f){0.f,0.f,0.f,0.f};

  for (int kt = 0; kt < KT1+KT2; kt++){
    const u16* ab; int sA, koff;
    if (KT2 == 0 || kt < KT1){ ab = A1; sA = sA1; koff = kt*32; }
    else { ab = A2; sA = sA2; koff = (kt-KT1)*32; }
    v8s a[4];
    #pragma unroll
    for (int mt = 0; mt < 4; mt++)
      a[mt] = *(const v8s*)(ab + (size_t)ar[mt]*sA + koff + quad*8);
    if (KT2 > 0 && LR2 && kt >= KT1){
      #pragma unroll
      for (int mt = 0; mt < 4; mt++)
        #pragma unroll
        for (int j = 0; j < 8; j++){
          float f = u2f((u16)a[mt][j]);
          f = f > 0.f ? f : 0.01f*f;
          a[mt][j] = (short)f2u(f);
        }
    }
    const int kb = kt*32 + quad*8;
    #pragma unroll
    for (int nt = 0; nt < NT; nt++){
      v8s b = *(const v8s*)(BT + (size_t)(nbase + nt*16 + l15)*sBT + kb);
      #pragma unroll
      for (int mt = 0; mt < 4; mt++)
        acc[mt][nt] = __builtin_amdgcn_mfma_f32_16x16x32_bf16(a[mt], b, acc[mt][nt], 0, 0, 0);
    }
  }

  if (EPI == 2){
    const float bo2v = bo2p[0];
    #pragma unroll
    for (int mt = 0; mt < 4; mt++){
      float part[4] = {0.f,0.f,0.f,0.f};
      #pragma unroll
      for (int nt = 0; nt < NT; nt++){
        const int col = nt*16 + l15;
        float wv2 = (col < 136) ? w2v[col] : 0.f;
        float bv  = bias[min(col,135)];
        #pragma unroll
        for (int i = 0; i < 4; i++){
          float xv = lrelu01(acc[mt][nt][i] + bv);
          part[i] = fmaf(xv, wv2, part[i]);
        }
      }
      #pragma unroll
      for (int i = 0; i < 4; i++){
        float v = part[i];
        v += __shfl_xor(v, 1, 64);
        v += __shfl_xor(v, 2, 64);
        v += __shfl_xor(v, 4, 64);
        v += __shfl_xor(v, 8, 64);
        int r = mb + mt*16 + quad*4 + i;
        if (l15 == 0 && r < m) fout[r] = v + bo2v;
      }
    }
    return;
  }

  #pragma unroll
  for (int mt = 0; mt < 4; mt++){
    const int r0 = mb + mt*16 + quad*4;
    #pragma unroll
    for (int nt = 0; nt < NT; nt++){
      const int col = nbase + nt*16 + l15;
      #pragma unroll
      for (int i = 0; i < 4; i++){
        int r = r0 + i;
        if (r < m){
          float xv = acc[mt][nt][i];
          if (EPI == 1){ xv += bias[min(col,135)]; xv = lrelu01(xv); }
          if (EPI == 3){ xv += bias[min(col,135)]; }
          C[(size_t)r*sC + col] = f2u(xv);
        }
      }
    }
  }
}

// ---------------- layer-1 GAT aggregation on feat (unroll-4) ----------------
__global__ void __launch_bounds__(256) k_agg1(const u16* __restrict__ feat,
    const float* __restrict__ asrc, const float* __restrict__ adst,
    const int* __restrict__ offs, const int* __restrict__ srcl,
    u16* __restrict__ aggF,
    const float* __restrict__ v2s, const float* __restrict__ v2d,
    const float* __restrict__ cc,
    float* __restrict__ as_out, float* __restrict__ ad_out,
    int cbMask, int cbShift)
{
  const int wv = threadIdx.x >> 6, lane = threadIdx.x & 63;
  const int id = blockIdx.x;
  const int bb = id & cbMask;
  const int dst = (id >> cbShift)*4 + wv;
  const int nbase = bb*N0_;
  const int node = nbase + dst;
  const int start = offs[dst], end = offs[dst+1];
  const int ne = end - start;

  const float ad0 = adst[(size_t)node*2], ad1v = adst[(size_t)node*2+1];

  float am0h0=0,am1h0=0,am0h1=0,am1h1=0;
  float ar0h0=0,ar1h0=0,ar0h1=0,ar1h1=0;

  auto acc_edge = [&](int sj, float c0, float c1){
    const u16* fp = feat + (size_t)sj*160;
    const ushort2 hv = *(const ushort2*)(fp + 2*lane);
    float f0 = u2f(hv.x), f1 = u2f(hv.y);
    am0h0 = fmaf(c0, f0, am0h0); am1h0 = fmaf(c0, f1, am1h0);
    am0h1 = fmaf(c1, f0, am0h1); am1h1 = fmaf(c1, f1, am1h1);
    if (lane < 4){
      const ushort2 hr = *(const ushort2*)(fp + 128 + 2*lane);
      float r0 = u2f(hr.x), r1 = u2f(hr.y);
      ar0h0 = fmaf(c0, r0, ar0h0); ar1h0 = fmaf(c0, r1, ar1h0);
      ar0h1 = fmaf(c1, r0, ar0h1); ar1h1 = fmaf(c1, r1, ar1h1);
    }
  };
  auto acc_edge4 = [&](int s0, int s1, int s2, int s3,
                       float a0, float a1, float a2, float a3,
                       float b0, float b1, float b2, float b3){
    const u16* p0 = feat + (size_t)s0*160;
    const u16* p1 = feat + (size_t)s1*160;
    const u16* p2 = feat + (size_t)s2*160;
    const u16* p3 = feat + (size_t)s3*160;
    const ushort2 v0 = *(const ushort2*)(p0 + 2*lane);
    const ushort2 v1 = *(const ushort2*)(p1 + 2*lane);
    const ushort2 v2 = *(const ushort2*)(p2 + 2*lane);
    const ushort2 v3 = *(const ushort2*)(p3 + 2*lane);
    ushort2 r0, r1, r2, r3;
    if (lane < 4){
      r0 = *(const ushort2*)(p0 + 128 + 2*lane);
      r1 = *(const ushort2*)(p1 + 128 + 2*lane);
      r2 = *(const ushort2*)(p2 + 128 + 2*lane);
      r3 = *(const ushort2*)(p3 + 128 + 2*lane);
    }
    float f;
    f = u2f(v0.x); am0h0 = fmaf(a0,f,am0h0); am0h1 = fmaf(b0,f,am0h1);
    f = u2f(v0.y); am1h0 = fmaf(a0,f,am1h0); am1h1 = fmaf(b0,f,am1h1);
    f = u2f(v1.x); am0h0 = fmaf(a1,f,am0h0); am0h1 = fmaf(b1,f,am0h1);
    f = u2f(v1.y); am1h0 = fmaf(a1,f,am1h0); am1h1 = fmaf(b1,f,am1h1);
    f = u2f(v2.x); am0h0 = fmaf(a2,f,am0h0); am0h1 = fmaf(b2,f,am0h1);
    f = u2f(v2.y); am1h0 = fmaf(a2,f,am1h0); am1h1 = fmaf(b2,f,am1h1);
    f = u2f(v3.x); am0h0 = fmaf(a3,f,am0h0); am0h1 = fmaf(b3,f,am0h1);
    f = u2f(v3.y); am1h0 = fmaf(a3,f,am1h0); am1h1 = fmaf(b3,f,am1h1);
    if (lane < 4){
      f = u2f(r0.x); ar0h0 = fmaf(a0,f,ar0h0); ar0h1 = fmaf(b0,f,ar0h1);
      f = u2f(r0.y); ar1h0 = fmaf(a0,f,ar1h0); ar1h1 = fmaf(b0,f,ar1h1);
      f = u2f(r1.x); ar0h0 = fmaf(a1,f,ar0h0); ar0h1 = fmaf(b1,f,ar0h1);
      f = u2f(r1.y); ar1h0 = fmaf(a1,f,ar1h0); ar1h1 = fmaf(b1,f,ar1h1);
      f = u2f(r2.x); ar0h0 = fmaf(a2,f,ar0h0); ar0h1 = fmaf(b2,f,ar0h1);
      f = u2f(r2.y); ar1h0 = fmaf(a2,f,ar1h0); ar1h1 = fmaf(b2,f,ar1h1);
      f = u2f(r3.x); ar0h0 = fmaf(a3,f,ar0h0); ar0h1 = fmaf(b3,f,ar0h1);
      f = u2f(r3.y); ar1h0 = fmaf(a3,f,ar1h0); ar1h1 = fmaf(b3,f,ar1h1);
    }
  };

  if (ne <= 64){
    const bool has = lane < ne;
    const int sn = nbase + (has ? srcl[start + lane] : 0);
    float al0 = has ? lrelu02(asrc[(size_t)sn*2]   + ad0)  : -1e30f;
    float al1 = has ? lrelu02(asrc[(size_t)sn*2+1] + ad1v) : -1e30f;
    float m0 = wred_max(al0);
    float p0 = has ? __expf(al0 - m0) : 0.f;
    float c0 = p0 * (1.f/(wred_sum(p0) + 1e-16f));
    float m1 = wred_max(al1);
    float p1 = has ? __expf(al1 - m1) : 0.f;
    float c1 = p1 * (1.f/(wred_sum(p1) + 1e-16f));
    int j = 0;
    for (; j + 3 < ne; j += 4){
      int   s0 = __shfl(sn, j, 64),   s1 = __shfl(sn, j+1, 64);
      int   s2 = __shfl(sn, j+2, 64), s3 = __shfl(sn, j+3, 64);
      float a0 = __shfl(c0, j, 64),   a1 = __shfl(c0, j+1, 64);
      float a2 = __shfl(c0, j+2, 64), a3 = __shfl(c0, j+3, 64);
      float b0 = __shfl(c1, j, 64),   b1 = __shfl(c1, j+1, 64);
      float b2 = __shfl(c1, j+2, 64), b3 = __shfl(c1, j+3, 64);
      acc_edge4(s0,s1,s2,s3, a0,a1,a2,a3, b0,b1,b2,b3);
    }
    for (; j < ne; j++)
      acc_edge(__shfl(sn, j, 64), __shfl(c0, j, 64), __shfl(c1, j, 64));
  } else {
    float lm0 = -1e30f, lm1 = -1e30f;
    for (int e = start + lane; e < end; e += 64){
      int sn = nbase + srcl[e];
      lm0 = fmaxf(lm0, lrelu02(asrc[(size_t)sn*2]   + ad0));
      lm1 = fmaxf(lm1, lrelu02(asrc[(size_t)sn*2+1] + ad1v));
    }
    float m0 = wred_max(lm0), m1 = wred_max(lm1);
    float ls0 = 0.f, ls1 = 0.f;
    for (int e = start + lane; e < end; e += 64){
      int sn = nbase + srcl[e];
      ls0 += __expf(lrelu02(asrc[(size_t)sn*2]   + ad0)  - m0);
      ls1 += __expf(lrelu02(asrc[(size_t)sn*2+1] + ad1v) - m1);
    }
    float si0 = 1.f/(wred_sum(ls0) + 1e-16f);
    float si1 = 1.f/(wred_sum(ls1) + 1e-16f);
    for (int cs2 = start; cs2 < end; cs2 += 64){
      int cnt = min(64, end - cs2);
      bool has = lane < cnt;
      int sn = nbase + (has ? srcl[cs2 + lane] : 0);
      float c0 = 0.f, c1 = 0.f;
      if (has){
        c0 = __expf(lrelu02(asrc[(size_t)sn*2]   + ad0)  - m0) * si0;
        c1 = __expf(lrelu02(asrc[(size_t)sn*2+1] + ad1v) - m1) * si1;
      }
      for (int j = 0; j < cnt; j++)
        acc_edge(__shfl(sn, j, 64), __shfl(c0, j, 64), __shfl(c1, j, 64));
    }
  }

  u16* outp = aggF + (size_t)node*288;
  {
    int c = 2*lane;
    ushort2 s0; s0.x = f2u(am0h0); s0.y = f2u(am1h0);
    *(ushort2*)(outp + c) = s0;
    ushort2 s1; s1.x = f2u(am0h1); s1.y = f2u(am1h1);
    *(ushort2*)(outp + 136 + c) = s1;
    if (lane < 4){
      int cr = 128 + 2*lane;
      ushort2 r0; r0.x = f2u(ar0h0); r0.y = f2u(ar1h0);
      *(ushort2*)(outp + cr) = r0;
      ushort2 r1; r1.x = f2u(ar0h1); r1.y = f2u(ar1h1);
      *(ushort2*)(outp + 136 + cr) = r1;
    }
  }
  {
    int c = 2*lane;
    float s = am0h0*v2s[c] + am1h0*v2s[c+1] + am0h1*v2s[136+c] + am1h1*v2s[136+c+1];
    float d = am0h0*v2d[c] + am1h0*v2d[c+1] + am0h1*v2d[136+c] + am1h1*v2d[136+c+1];
    if (lane < 4){
      int cr = 128 + 2*lane;
      s += ar0h0*v2s[cr] + ar1h0*v2s[cr+1] + ar0h1*v2s[136+cr] + ar1h1*v2s[136+cr+1];
      d += ar0h0*v2d[cr] + ar1h0*v2d[cr+1] + ar0h1*v2d[136+cr] + ar1h1*v2d[136+cr+1];
    }
    s = wred_sum(s); d = wred_sum(d);
    if (lane == 0){ as_out[node] = s + cc[0]; ad_out[node] = d + cc[1]; }
  }
}

// ---------------- layer-2 GAT aggregation (H=1, unroll-4) ----------------
template<int CT,int LACT>
__global__ void __launch_bounds__(256) k_agg(const u16* __restrict__ h, int sh,
    const float* __restrict__ asrc, const float* __restrict__ adst,
    const int* __restrict__ offs, const int* __restrict__ srcl,
    const float* __restrict__ bias, u16* __restrict__ outp0, int so,
    int cbMask, int cbShift)
{
  constexpr int MAINC = 128;
  constexpr int REMV  = (CT - MAINC)/2;

  const int wv = threadIdx.x >> 6, lane = threadIdx.x & 63;
  const int id = blockIdx.x;
  const int bb = id & cbMask;
  const int dst = (id >> cbShift)*4 + wv;
  const int nbase = bb*N0_;
  const int node = nbase + dst;
  const int start = offs[dst], end = offs[dst+1];
  const int ne = end - start;

  const float adh = adst[node];

  float acc0=0, acc1=0, accr0=0, accr1=0;

  auto acc_edge = [&](int sj, float c0){
    const u16* hp = h + (size_t)sj*sh;
    const ushort2 hv = *(const ushort2*)(hp + 2*lane);
    acc0 = fmaf(c0, u2f(hv.x), acc0);
    acc1 = fmaf(c0, u2f(hv.y), acc1);
    if (lane < REMV){
      const ushort2 hr = *(const ushort2*)(hp + MAINC + 2*lane);
      accr0 = fmaf(c0, u2f(hr.x), accr0);
      accr1 = fmaf(c0, u2f(hr.y), accr1);
    }
  };
  auto acc_edge4 = [&](int s0, int s1, int s2, int s3,
                       float a0, float a1, float a2, float a3){
    const u16* p0 = h + (size_t)s0*sh;
    const u16* p1 = h + (size_t)s1*sh;
    const u16* p2 = h + (size_t)s2*sh;
    const u16* p3 = h + (size_t)s3*sh;
    const ushort2 v0 = *(const ushort2*)(p0 + 2*lane);
    const ushort2 v1 = *(const ushort2*)(p1 + 2*lane);
    const ushort2 v2 = *(const ushort2*)(p2 + 2*lane);
    const ushort2 v3 = *(const ushort2*)(p3 + 2*lane);
    ushort2 r0, r1, r2, r3;
    if (lane < REMV){
      r0 = *(const ushort2*)(p0 + MAINC + 2*lane);
      r1 = *(const ushort2*)(p1 + MAINC + 2*lane);
      r2 = *(const ushort2*)(p2 + MAINC + 2*lane);
      r3 = *(const ushort2*)(p3 + MAINC + 2*lane);
    }
    acc0 = fmaf(a0, u2f(v0.x), acc0); acc1 = fmaf(a0, u2f(v0.y), acc1);
    acc0 = fmaf(a1, u2f(v1.x), acc0); acc1 = fmaf(a1, u2f(v1.y), acc1);
    acc0 = fmaf(a2, u2f(v2.x), acc0); acc1 = fmaf(a2, u2f(v2.y), acc1);
    acc0 = fmaf(a3, u2f(v3.x), acc0); acc1 = fmaf(a3, u2f(v3.y), acc1);
    if (lane < REMV){
      accr0 = fmaf(a0, u2f(r0.x), accr0); accr1 = fmaf(a0, u2f(r0.y), accr1);
      accr0 = fmaf(a1, u2f(r1.x), accr0); accr1 = fmaf(a1, u2f(r1.y), accr1);
      accr0 = fmaf(a2, u2f(r2.x), accr0); accr1 = fmaf(a2, u2f(r2.y), accr1);
      accr0 = fmaf(a3, u2f(r3.x), accr0); accr1 = fmaf(a3, u2f(r3.y), accr1);
    }
  };

  if (ne <= 64){
    const bool has = lane < ne;
    const int sn = nbase + (has ? srcl[start + lane] : 0);
    float al = has ? lrelu02(asrc[sn] + adh) : -1e30f;
    float m = wred_max(al);
    float p = has ? __expf(al - m) : 0.f;
    float c0 = p * (1.f/(wred_sum(p) + 1e-16f));
    int j = 0;
    for (; j + 3 < ne; j += 4){
      int   s0 = __shfl(sn, j, 64),   s1 = __shfl(sn, j+1, 64);
      int   s2 = __shfl(sn, j+2, 64), s3 = __shfl(sn, j+3, 64);
      float a0 = __shfl(c0, j, 64),   a1 = __shfl(c0, j+1, 64);
      float a2 = __shfl(c0, j+2, 64), a3 = __shfl(c0, j+3, 64);
      acc_edge4(s0,s1,s2,s3, a0,a1,a2,a3);
    }
    for (; j < ne; j++)
      acc_edge(__shfl(sn, j, 64), __shfl(c0, j, 64));
  } else {
    float lm = -1e30f;
    for (int e = start + lane; e < end; e += 64){
      int sn = nbase + srcl[e];
      lm = fmaxf(lm, lrelu02(asrc[sn] + adh));
    }
    float m = wred_max(lm);
    float ls = 0.f;
    for (int e = start + lane; e < end; e += 64){
      int sn = nbase + srcl[e];
      ls += __expf(lrelu02(asrc[sn] + adh) - m);
    }
    float si = 1.f/(wred_sum(ls) + 1e-16f);
    for (int cs = start; cs < end; cs += 64){
      int cnt = min(64, end - cs);
      bool has = lane < cnt;
      int sn = nbase + (has ? srcl[cs + lane] : 0);
      float c0 = has ? __expf(lrelu02(asrc[sn] + adh) - m) * si : 0.f;
      for (int j = 0; j < cnt; j++)
        acc_edge(__shfl(sn, j, 64), __shfl(c0, j, 64));
    }
  }

  u16* outp = outp0 + (size_t)node*so;
  {
    int c = 2*lane;
    float r0 = acc0 + bias[c], r1 = acc1 + bias[c+1];
    if (LACT){ r0 = lrelu01(r0); r1 = lrelu01(r1); }
    ushort2 st; st.x = f2u(r0); st.y = f2u(r1);
    *(ushort2*)(outp + c) = st;
    if (lane < REMV){
      int cr = MAINC + 2*lane;
      float q0 = accr0 + bias[cr], q1 = accr1 + bias[cr+1];
      if (LACT){ q0 = lrelu01(q0); q1 = lrelu01(q1); }
      ushort2 sr; sr.x = f2u(q0); sr.y = f2u(q1);
      *(ushort2*)(outp + cr) = sr;
    }
  }
}

// ---------------- launch ----------------
extern "C" void kernel_launch(void* const* d_in, const int* in_sizes, int n_in,
                              void* d_out, int out_size, void* d_ws, size_t ws_size,
                              hipStream_t stream)
{
  (void)in_sizes; (void)n_in; (void)out_size;
  const float* x    = (const float*)d_in[0];
  const float* wl1  = (const float*)d_in[1];
  const float* gl1  = (const float*)d_in[3];
  const float* bel1 = (const float*)d_in[4];
  const float* wl2  = (const float*)d_in[5];
  const float* gl2  = (const float*)d_in[7];
  const float* bel2 = (const float*)d_in[8];
  const float* wp1  = (const float*)d_in[9];
  const float* gp1  = (const float*)d_in[11];
  const float* bep1 = (const float*)d_in[12];
  const float* wp2  = (const float*)d_in[13];
  const float* gp2  = (const float*)d_in[15];
  const float* bep2 = (const float*)d_in[16];
  const float* wg   = (const float*)d_in[17];
  const float* gg   = (const float*)d_in[19];
  const float* beg  = (const float*)d_in[20];
  const float* W1   = (const float*)d_in[21];
  const float* as1  = (const float*)d_in[22];
  const float* ad1  = (const float*)d_in[23];
  const float* bb1  = (const float*)d_in[24];
  const float* W2   = (const float*)d_in[25];
  const float* as2  = (const float*)d_in[26];
  const float* ad2  = (const float*)d_in[27];
  const float* bb2  = (const float*)d_in[28];
  const float* Wo   = (const float*)d_in[29];
  const float* bo   = (const float*)d_in[30];
  const float* Wo2  = (const float*)d_in[31];
  const float* bo2  = (const float*)d_in[32];
  const int*   ei   = (const int*)d_in[33];

  const size_t STATIC_BYTES = 1200000;
  int nc = 1;
  while (nc < 8 && STATIC_BYTES + (size_t)1880*(NODES/nc) > ws_size) nc <<= 1;
  const int CB = B_/nc, CN = CB*N0_;
  int cbShift = 0; while ((1 << cbShift) < CB) cbShift++;
  const int cbMask = CB - 1;

  char* wsb = (char*)d_ws; size_t off = 0;
  auto alloc = [&](size_t nbytes)->void*{
    void* p = wsb + off; off = (off + nbytes + 255) & ~(size_t)255; return p;
  };
  int*   zbase  = (int*)  alloc(20080*sizeof(int));
  float* gsum   = (float*)zbase;
  float* gsq    = gsum + 40;
  int*   counts = zbase + 80;
  int*   cursor = counts + 10000;
  float* sA     = (float*)alloc(40*sizeof(float));
  float* sB     = (float*)alloc(40*sizeof(float));
  int*   offs   = (int*)  alloc(10001*sizeof(int));
  int*   srcl   = (int*)  alloc((size_t)NE_*sizeof(int));
  u16*   W12T   = (u16*)  alloc((size_t)144*288*2);
  u16*   WoT    = (u16*)  alloc((size_t)144*320*2);
  float* va1s   = (float*)alloc(272*sizeof(float));
  float* va1d   = (float*)alloc(272*sizeof(float));
  float* v2ss   = (float*)alloc(272*sizeof(float));
  float* v2dd   = (float*)alloc(272*sizeof(float));
  float* ccv    = (float*)alloc(2*sizeof(float));
  float* b12    = (float*)alloc(136*sizeof(float));
  u16*   feat   = (u16*)  alloc((size_t)CN*160*2);
  u16*   featL  = (u16*)  alloc((size_t)CN*160*2);
  u16*   aggF   = (u16*)  alloc((size_t)CN*288*2);
  u16*   h2     = (u16*)  alloc((size_t)CN*144*2);
  u16*   g2l    = (u16*)  alloc((size_t)CN*160*2);
  float* asrc1  = (float*)alloc((size_t)CN*2*sizeof(float));
  float* adst1  = (float*)alloc((size_t)CN*2*sizeof(float));
  float* asrc2  = (float*)alloc((size_t)CN*sizeof(float));
  float* adst2  = (float*)alloc((size_t)CN*sizeof(float));

  k_setup<<<425,256,0,stream>>>(zbase, Wo, WoT, W1, W2, W12T,
                                as1, ad1, va1s, va1d, as2, ad2, bb1,
                                v2ss, v2dd, ccv, b12);

  k_bn_stats<<<625,256,0,stream>>>(x, wl1,wl2,wp1,wp2,wg, gsum, gsq);
  k_bn_fin  <<<1,64,0,stream>>>(gsum, gsq, sA, sB, gl1,gl2,gp1,gp2,gg, bel1,bel2,bep1,bep2,beg);

  k_count  <<<665,256,0,stream>>>(ei, counts);
  k_scan   <<<1,1024,0,stream>>>(counts, offs);
  k_scatter<<<665,256,0,stream>>>(ei, offs, cursor, srcl);

  const int gx  = (CN + 255)/256;
  const int gx2 = (CN + 127)/128;
  const int aggB = 2500*CB;
  for (int c = 0; c < nc; c++){
    const int base = c*CN;

    k_feat<<<gx2,256,0,stream>>>(x, wl1,wl2,wp1,wp2,wg, sA, sB, va1s, va1d,
                                 feat, featL, asrc1, adst1, base, CN);

    k_agg1<<<aggB,256,0,stream>>>(feat, asrc1, adst1, offs, srcl, aggF,
                                  v2ss, v2dd, ccv, asrc2, adst2, cbMask, cbShift);

    k_mfma<9,0,9,3,0><<<gx,256,0,stream>>>(aggF,288, (const u16*)0,0, W12T,288, h2,144, 0, b12, CN,
                                           (const float*)0,(const float*)0,(float*)0);

    k_agg<136,1><<<aggB,256,0,stream>>>(h2,144, asrc2, adst2, offs, srcl, bb2, g2l,160,
                                        cbMask, cbShift);

    k_mfma<5,5,9,2,0><<<gx,256,0,stream>>>(g2l,160, featL,160, WoT,320, (u16*)0,0, 0, bo, CN,
                                           Wo2, bo2, (float*)d_out + base);
  }
}

// Round 12
// 517.392 us; speedup vs baseline: 1.6956x; 1.0047x over previous
//
#include <hip/hip_runtime.h>
#include <hip/hip_bf16.h>
#include <math.h>

typedef unsigned short u16;
typedef unsigned int   u32;
typedef short v8s __attribute__((ext_vector_type(8)));
typedef float v4f __attribute__((ext_vector_type(4)));
#define DEV static __device__ __forceinline__

DEV float u2f(u16 u){ union{u32 i; float f;} v; v.i = ((u32)u)<<16; return v.f; }
DEV u16   f2u(float f){ union{float ff; u32 i;} v; v.ff = f; u32 r = v.i + 0x7fffu + ((v.i>>16)&1u); return (u16)(r>>16); }
DEV float lrelu02(float x){ return x > 0.f ? x : 0.2f*x; }
DEV float lrelu01(float x){ return x > 0.f ? x : 0.01f*x; }
DEV float fast_tanh(float x){
  float cx = fminf(fmaxf(x, -15.f), 15.f);
  float e = __expf(2.f*cx);
  return (e - 1.f) * __builtin_amdgcn_rcpf(e + 1.f);
}
DEV float wred_max(float v){
  #pragma unroll
  for (int o = 32; o > 0; o >>= 1) v = fmaxf(v, __shfl_xor(v, o, 64));
  return v;
}
DEV float wred_sum(float v){
  #pragma unroll
  for (int o = 32; o > 0; o >>= 1) v += __shfl_xor(v, o, 64);
  return v;
}

constexpr int B_   = 8;
constexpr int P_   = 32;
constexpr int N0_  = 10000;
constexpr int NODES = B_ * N0_;      // 80000
constexpr int E_   = 160000;
constexpr int NE_  = E_ + N0_;       // 170000

// ---------------- merged setup ----------------
__global__ void __launch_bounds__(256) k_setup(int* __restrict__ zbase,
    const float* __restrict__ Wo, u16* __restrict__ WoT,
    const float* __restrict__ W1, const float* __restrict__ W2, u16* __restrict__ W12T,
    const float* __restrict__ as1, const float* __restrict__ ad1,
    float* __restrict__ va1s, float* __restrict__ va1d,
    const float* __restrict__ as2, const float* __restrict__ ad2,
    const float* __restrict__ bb1,
    float* __restrict__ v2ss, float* __restrict__ v2dd,
    float* __restrict__ cc, float* __restrict__ b12)
{
  __shared__ float l2s[272], l2d[272];
  int blk = blockIdx.x, tid = threadIdx.x;
  if (blk < 79){ int i = blk*256 + tid; if (i < 20080) zbase[i] = 0; return; }
  blk -= 79;
  if (blk < 180){           // WoT[n][k] (144x320), head split
    int i = blk*256 + tid; if (i >= 144*320) return;
    int n = i/320, k = i - n*320; float v = 0.f;
    if (n < 136){
      if (k < 136) v = Wo[(size_t)k*136 + n];
      else if (k >= 160 && k < 296) v = Wo[(size_t)(k-24)*136 + n];
    }
    WoT[i] = f2u(v); return;
  }
  blk -= 180;
  if (blk < 162){           // W12T[n][kk] (144x288) = (W1@W2)^T per head-block
    int i = blk*256 + tid; if (i >= 144*288) return;
    int n = i/288, kk = i - n*288; float v = 0.f;
    if (n < 136 && kk < 272){
      int hh = kk/136, k = kk - hh*136;
      for (int c = 0; c < 136; c++)
        v = fmaf(W1[(size_t)k*272 + hh*136 + c], W2[(size_t)(hh*136+c)*136 + n], v);
    }
    W12T[i] = f2u(v); return;
  }
  blk -= 162;
  if (blk < 2){             // va1 = W1 a1 (272)
    int t = blk*256 + tid; if (t >= 272) return;
    int hh = t/136, k = t - hh*136; float s = 0.f, d = 0.f;
    for (int c = 0; c < 136; c++){
      float w = W1[(size_t)k*272 + hh*136 + c];
      s = fmaf(w, as1[hh*136+c], s);
      d = fmaf(w, ad1[hh*136+c], d);
    }
    va1s[t] = s; va1d[t] = d; return;
  }
  blk -= 2;
  {                         // v2'' = W1@(W2 a2); cc = bb1·(W2 a2); b12 = bb1@W2
    for (int m = tid; m < 272; m += 256){
      float vs = 0.f, vd = 0.f;
      for (int n2 = 0; n2 < 136; n2++){
        float w2 = W2[(size_t)m*136 + n2];
        vs = fmaf(w2, as2[n2], vs);
        vd = fmaf(w2, ad2[n2], vd);
      }
      l2s[m] = vs; l2d[m] = vd;
    }
    __syncthreads();
    int t0 = blk*256 + tid;
    if (t0 < 272){
      int hh = t0/136, k = t0 - hh*136; float s = 0.f, d = 0.f;
      for (int c = 0; c < 136; c++){
        float w = W1[(size_t)k*272 + hh*136 + c];
        s = fmaf(w, l2s[hh*136+c], s);
        d = fmaf(w, l2d[hh*136+c], d);
      }
      v2ss[t0] = s; v2dd[t0] = d;
    }
    if (blk == 1){
      if (tid < 64){
        float s = 0.f, d = 0.f;
        for (int m = tid; m < 272; m += 64){
          s = fmaf(bb1[m], l2s[m], s);
          d = fmaf(bb1[m], l2d[m], d);
        }
        s = wred_sum(s); d = wred_sum(d);
        if (tid == 0){ cc[0] = s; cc[1] = d; }
      } else if (tid < 200){
        int n2 = tid - 64; float v = 0.f;
        for (int m = 0; m < 272; m++) v = fmaf(bb1[m], W2[(size_t)m*136 + n2], v);
        b12[n2] = v;
      }
    }
  }
}

// ---------------- backbone ----------------
DEV void load_convw(float* lw, const float* wl1, const float* wl2, const float* wp1,
                    const float* wp2, const float* wg, int tid, int nth){
  for (int i = tid; i < 384; i += nth){
    float v;
    if      (i < 24)  v = wl1[i];
    else if (i < 64)  v = wl2[i-24];
    else if (i < 88)  v = wp1[i-64];
    else if (i < 128) v = wp2[i-88];
    else              v = wg [i-128];
    lw[i] = v;
  }
}

template<int KS,int DIL,int T>
DEV void conv_stats(const float* xc, const float* wk, float& s, float& q){
  #pragma unroll
  for (int t = 0; t < T; t++){
    float v = 0.f;
    #pragma unroll
    for (int j = 0; j < KS; j++) v = fmaf(wk[j], xc[t + j*DIL], v);
    s += v; q = fmaf(v, v, q);
  }
}

__global__ void __launch_bounds__(256) k_bn_stats(
    const float* __restrict__ x,
    const float* __restrict__ wl1, const float* __restrict__ wl2,
    const float* __restrict__ wp1, const float* __restrict__ wp2,
    const float* __restrict__ wg,
    float* __restrict__ gsum, float* __restrict__ gsq)
{
  __shared__ float lw[384];
  __shared__ float lacc[80];
  const int tid = threadIdx.x;
  load_convw(lw, wl1, wl2, wp1, wp2, wg, tid, 256);
  if (tid < 80) lacc[tid] = 0.f;
  __syncthreads();

  const int lane = tid & 63, wv = tid >> 6;
  const int nodeLocal = (wv >> 1)*64 + lane;
  const int half = wv & 1;
  const int gid = blockIdx.x*128 + nodeLocal;
  float xc[P_];
  if (gid < NODES){
    int b = gid / N0_, n = gid - b*N0_;
    const float* xp = x + (size_t)b*P_*N0_ + n;
    #pragma unroll
    for (int p = 0; p < P_; p++) xc[p] = xp[(size_t)p*N0_];
  } else {
    #pragma unroll
    for (int p = 0; p < P_; p++) xc[p] = 0.f;
  }

  auto red = [&](int ch, float s, float q){
    #pragma unroll
    for (int o = 32; o > 0; o >>= 1){ s += __shfl_down(s,o,64); q += __shfl_down(q,o,64); }
    if (lane == 0){ atomicAdd(&lacc[ch], s); atomicAdd(&lacc[40+ch], q); }
  };

  if (half == 0){
    #pragma unroll
    for (int k = 0; k < 8; k++){ float s=0,q=0; conv_stats<3,1,30>(xc, lw      + k*3 , s,q); red(k,     s,q); }
    #pragma unroll
    for (int k = 0; k < 8; k++){ float s=0,q=0; conv_stats<5,1,28>(xc, lw + 24 + k*5 , s,q); red(8+k,   s,q); }
  } else {
    #pragma unroll
    for (int k = 0; k < 8; k++){ float s=0,q=0; conv_stats<3,2,28>(xc, lw + 64 + k*3 , s,q); red(16+k,  s,q); }
    #pragma unroll
    for (int k = 0; k < 8; k++){ float s=0,q=0; conv_stats<5,2,24>(xc, lw + 88 + k*5 , s,q); red(24+k,  s,q); }
    #pragma unroll
    for (int k = 0; k < 8; k++){ float s=0,q=0; conv_stats<32,1,1>(xc, lw + 128+ k*32, s,q); red(32+k,  s,q); }
  }

  __syncthreads();
  if (tid < 40)      atomicAdd(&gsum[tid],    lacc[tid]);
  else if (tid < 80) atomicAdd(&gsq [tid-40], lacc[tid]);
}

__global__ void k_bn_fin(const float* __restrict__ gsum, const float* __restrict__ gsq,
                         float* __restrict__ sA, float* __restrict__ sB,
                         const float* g0, const float* g1, const float* g2, const float* g3, const float* g4,
                         const float* e0, const float* e1, const float* e2, const float* e3, const float* e4)
{
  int t = threadIdx.x;
  if (t >= 40) return;
  int bi = t >> 3, k = t & 7;
  const int Ts[5] = {30,28,28,24,1};
  float cnt  = (float)NODES * (float)Ts[bi];
  float mean = gsum[t] / cnt;
  float var  = gsq[t] / cnt - mean*mean;
  const float* gp = bi==0?g0: bi==1?g1: bi==2?g2: bi==3?g3: g4;
  const float* ep = bi==0?e0: bi==1?e1: bi==2?e2: bi==3?e3: e4;
  float a = gp[k] * rsqrtf(fmaxf(var, 0.f) + 1e-5f);
  sA[t] = a;
  sB[t] = ep[k] - a*mean;
}

template<int KS,int DIL,int T>
DEV void conv_pool4(const float* xc, const float* wk, float A, float Bc, float* o4){
  float y[T];
  #pragma unroll
  for (int t = 0; t < T; t++){
    float v = 0.f;
    #pragma unroll
    for (int j = 0; j < KS; j++) v = fmaf(wk[j], xc[t + j*DIL], v);
    y[t] = fmaf(A, v, Bc);
  }
  #pragma unroll
  for (int i = 0; i < 4; i++){
    const int lo = (i*T)/4, hi = ((i+1)*T + 3)/4;
    float m = y[lo];
    #pragma unroll
    for (int t = 0; t < T; t++){ if (t > lo && t < hi) m = fmaxf(m, y[t]); }
    o4[i] = m;
  }
}

// feat [m][160] bf16 (tanh) + featL (lrelu01) + fused layer-1 attention dots (float4 LDS)
__global__ void __launch_bounds__(256) k_feat(
    const float* __restrict__ x,
    const float* __restrict__ wl1, const float* __restrict__ wl2,
    const float* __restrict__ wp1, const float* __restrict__ wp2,
    const float* __restrict__ wg,
    const float* __restrict__ sA, const float* __restrict__ sB,
    const float* __restrict__ va1s, const float* __restrict__ va1d,
    u16* __restrict__ feat, u16* __restrict__ featL,
    float* __restrict__ asrc1, float* __restrict__ adst1,
    int base, int m)
{
  __shared__ float lw[384];
  __shared__ float lA[40], lB[40];
  __shared__ float4 lv4[136];
  __shared__ float sdt[128][4];
  const int tid = threadIdx.x;
  load_convw(lw, wl1, wl2, wp1, wp2, wg, tid, 256);
  if (tid < 40){ lA[tid] = sA[tid]; lB[tid] = sB[tid]; }
  for (int i = tid; i < 136; i += 256)
    lv4[i] = make_float4(va1s[i], va1d[i], va1s[136+i], va1d[136+i]);
  __syncthreads();

  const int lane = tid & 63, wv = tid >> 6;
  const int nodeLocal = (wv >> 1)*64 + lane;     // 0..127
  const int half = wv & 1;                       // wave-uniform
  const int nodeIdx = blockIdx.x*128 + nodeLocal;
  const bool act = nodeIdx < m;
  const int gcl = base + (act ? nodeIdx : (m-1));
  int b = gcl / N0_, n = gcl - b*N0_;
  float xc[P_];
  const float* xp = x + (size_t)b*P_*N0_ + n;
  #pragma unroll
  for (int p = 0; p < P_; p++) xc[p] = xp[(size_t)p*N0_];

  float dt[4] = {0.f,0.f,0.f,0.f};
  u32 pk[4], pkl[4];
  u16* orow  = feat  + (size_t)nodeIdx*160;
  u16* olrow = featL + (size_t)nodeIdx*160;
  auto emit = [&](int ch, float v){
    float t = fast_tanh(v);
    float4 vv = lv4[ch];
    dt[0] = fmaf(t, vv.x, dt[0]);
    dt[1] = fmaf(t, vv.y, dt[1]);
    dt[2] = fmaf(t, vv.z, dt[2]);
    dt[3] = fmaf(t, vv.w, dt[3]);
    u16 h  = f2u(t);
    u16 hl = f2u(lrelu01(t));
    int s = ch & 7;
    if ((s & 1) == 0){ pk[s>>1] = h;                pkl[s>>1] = hl; }
    else             { pk[s>>1] |= ((u32)h) << 16;  pkl[s>>1] |= ((u32)hl) << 16; }
    if (s == 7 && act){
      *(uint4*)(orow  + (ch - 7)) = make_uint4(pk[0],pk[1],pk[2],pk[3]);
      *(uint4*)(olrow + (ch - 7)) = make_uint4(pkl[0],pkl[1],pkl[2],pkl[3]);
    }
  };

  float o4[4];
  if (half == 0){
    #pragma unroll
    for (int k = 0; k < 8; k++){
      conv_pool4<3,1,30>(xc, lw + k*3, lA[k], lB[k], o4);
      #pragma unroll
      for (int i = 0; i < 4; i++) emit(k*4+i, o4[i]);
    }
    #pragma unroll
    for (int k = 0; k < 8; k++){
      conv_pool4<5,1,28>(xc, lw + 24 + k*5, lA[8+k], lB[8+k], o4);
      #pragma unroll
      for (int i = 0; i < 4; i++) emit(32 + k*4+i, o4[i]);
    }
  } else {
    #pragma unroll
    for (int k = 0; k < 8; k++){
      conv_pool4<3,2,28>(xc, lw + 64 + k*3, lA[16+k], lB[16+k], o4);
      #pragma unroll
      for (int i = 0; i < 4; i++) emit(64 + k*4+i, o4[i]);
    }
    #pragma unroll
    for (int k = 0; k < 8; k++){
      conv_pool4<5,2,24>(xc, lw + 88 + k*5, lA[24+k], lB[24+k], o4);
      #pragma unroll
      for (int i = 0; i < 4; i++) emit(96 + k*4+i, o4[i]);
    }
    #pragma unroll
    for (int k = 0; k < 8; k++){
      float v = 0.f;
      #pragma unroll
      for (int j = 0; j < 32; j++) v = fmaf(lw[128 + k*32 + j], xc[j], v);
      emit(128 + k, fmaf(lA[32+k], v, lB[32+k]));
    }
  }

  if (half == 1){
    sdt[nodeLocal][0] = dt[0]; sdt[nodeLocal][1] = dt[1];
    sdt[nodeLocal][2] = dt[2]; sdt[nodeLocal][3] = dt[3];
  }
  __syncthreads();
  if (half == 0 && act){
    asrc1[(size_t)nodeIdx*2]   = dt[0] + sdt[nodeLocal][0];
    asrc1[(size_t)nodeIdx*2+1] = dt[2] + sdt[nodeLocal][2];
    adst1[(size_t)nodeIdx*2]   = dt[1] + sdt[nodeLocal][1];
    adst1[(size_t)nodeIdx*2+1] = dt[3] + sdt[nodeLocal][3];
  }
}

// ---------------- CSR ----------------
__global__ void k_count(const int* __restrict__ ei, int* __restrict__ counts){
  int e = blockIdx.x*blockDim.x + threadIdx.x;
  if (e >= NE_) return;
  int dst = (e < E_) ? ei[E_ + e] : (e - E_);
  atomicAdd(&counts[dst], 1);
}

__global__ void __launch_bounds__(1024) k_scan(const int* __restrict__ counts, int* __restrict__ offs){
  __shared__ int part[1024];
  int t = threadIdx.x;
  int loc[10]; int s = 0;
  #pragma unroll
  for (int i = 0; i < 10; i++){
    int idx = t*10 + i;
    int c = (idx < N0_) ? counts[idx] : 0;
    loc[i] = s; s += c;
  }
  part[t] = s;
  __syncthreads();
  for (int o = 1; o < 1024; o <<= 1){
    int v = (t >= o) ? part[t-o] : 0;
    __syncthreads();
    part[t] += v;
    __syncthreads();
  }
  int pre = (t == 0) ? 0 : part[t-1];
  #pragma unroll
  for (int i = 0; i < 10; i++){
    int idx = t*10 + i;
    if (idx < N0_) offs[idx] = pre + loc[i];
  }
  if (t == 0) offs[N0_] = part[1023];
}

__global__ void k_scatter(const int* __restrict__ ei, const int* __restrict__ offs,
                          int* __restrict__ cursor, int* __restrict__ srcl){
  int e = blockIdx.x*blockDim.x + threadIdx.x;
  if (e >= NE_) return;
  int src, dst;
  if (e < E_){ src = ei[e]; dst = ei[E_ + e]; } else { src = dst = e - E_; }
  int pos = atomicAdd(&cursor[dst], 1);
  srcl[offs[dst] + pos] = src;
}

// ---------------- MFMA GEMM ----------------
template<int KT1,int KT2,int NT,int EPI,int LR2>
__global__ void __launch_bounds__(256) k_mfma(
    const u16* __restrict__ A1, int sA1,
    const u16* __restrict__ A2, int sA2,
    const u16* __restrict__ BT, int sBT,
    u16* __restrict__ C, int sC, int nbase,
    const float* __restrict__ bias, int m,
    const float* __restrict__ w2v, const float* __restrict__ bo2p, float* __restrict__ fout)
{
  const int wv = threadIdx.x >> 6, lane = threadIdx.x & 63;
  const int quad = lane >> 4, l15 = lane & 15;
  const int mb = blockIdx.x*256 + wv*64;
  int ar[4];
  #pragma unroll
  for (int mt = 0; mt < 4; mt++) ar[mt] = min(mb + mt*16 + l15, m-1);

  v4f acc[4][NT];
  #pragma unroll
  for (int mt = 0; mt < 4; mt++)
    #pragma unroll
    for (int nt = 0; nt < NT; nt++)
      acc[mt][nt] = (v4f){0.f,0.f,0.f,0.f};

  for (int kt = 0; kt < KT1+KT2; kt++){
    const u16* ab; int sA, koff;
    if (KT2 == 0 || kt < KT1){ ab = A1; sA = sA1; koff = kt*32; }
    else { ab = A2; sA = sA2; koff = (kt-KT1)*32; }
    v8s a[4];
    #pragma unroll
    for (int mt = 0; mt < 4; mt++)
      a[mt] = *(const v8s*)(ab + (size_t)ar[mt]*sA + koff + quad*8);
    if (KT2 > 0 && LR2 && kt >= KT1){
      #pragma unroll
      for (int mt = 0; mt < 4; mt++)
        #pragma unroll
        for (int j = 0; j < 8; j++){
          float f = u2f((u16)a[mt][j]);
          f = f > 0.f ? f : 0.01f*f;
          a[mt][j] = (short)f2u(f);
        }
    }
    const int kb = kt*32 + quad*8;
    #pragma unroll
    for (int nt = 0; nt < NT; nt++){
      v8s b = *(const v8s*)(BT + (size_t)(nbase + nt*16 + l15)*sBT + kb);
      #pragma unroll
      for (int mt = 0; mt < 4; mt++)
        acc[mt][nt] = __builtin_amdgcn_mfma_f32_16x16x32_bf16(a[mt], b, acc[mt][nt], 0, 0, 0);
    }
  }

  if (EPI == 2){
    const float bo2v = bo2p[0];
    #pragma unroll
    for (int mt = 0; mt < 4; mt++){
      float part[4] = {0.f,0.f,0.f,0.f};
      #pragma unroll
      for (int nt = 0; nt < NT; nt++){
        const int col = nt*16 + l15;
        float wv2 = (col < 136) ? w2v[col] : 0.f;
        float bv  = bias[min(col,135)];
        #pragma unroll
        for (int i = 0; i < 4; i++){
          float xv = lrelu01(acc[mt][nt][i] + bv);
          part[i] = fmaf(xv, wv2, part[i]);
        }
      }
      #pragma unroll
      for (int i = 0; i < 4; i++){
        float v = part[i];
        v += __shfl_xor(v, 1, 64);
        v += __shfl_xor(v, 2, 64);
        v += __shfl_xor(v, 4, 64);
        v += __shfl_xor(v, 8, 64);
        int r = mb + mt*16 + quad*4 + i;
        if (l15 == 0 && r < m) fout[r] = v + bo2v;
      }
    }
    return;
  }

  #pragma unroll
  for (int mt = 0; mt < 4; mt++){
    const int r0 = mb + mt*16 + quad*4;
    #pragma unroll
    for (int nt = 0; nt < NT; nt++){
      const int col = nbase + nt*16 + l15;
      #pragma unroll
      for (int i = 0; i < 4; i++){
        int r = r0 + i;
        if (r < m){
          float xv = acc[mt][nt][i];
          if (EPI == 1){ xv += bias[min(col,135)]; xv = lrelu01(xv); }
          if (EPI == 3){ xv += bias[min(col,135)]; }
          C[(size_t)r*sC + col] = f2u(xv);
        }
      }
    }
  }
}

// ---------------- layer-1 GAT aggregation on feat: group-of-8 edges, distributed remainder ----------------
__global__ void __launch_bounds__(256) k_agg1(const u16* __restrict__ feat,
    const float* __restrict__ asrc, const float* __restrict__ adst,
    const int* __restrict__ offs, const int* __restrict__ srcl,
    u16* __restrict__ aggF,
    const float* __restrict__ v2s, const float* __restrict__ v2d,
    const float* __restrict__ cc,
    float* __restrict__ as_out, float* __restrict__ ad_out,
    int cbMask, int cbShift)
{
  const int wv = threadIdx.x >> 6, lane = threadIdx.x & 63;
  const int id = blockIdx.x;
  const int bb = id & cbMask;
  const int dst = (id >> cbShift)*4 + wv;
  const int nbase = bb*N0_;
  const int node = nbase + dst;
  const int start = offs[dst], end = offs[dst+1];
  const int ne = end - start;

  const float ad0 = adst[(size_t)node*2], ad1v = adst[(size_t)node*2+1];

  const char* featB = (const char*)feat;
  const int laneByte = 4*lane;                         // ushort2 for ch pair (2l,2l+1)
  const int remByte  = 256 + ((lane & 7) << 1);        // ch 128+(lane&7)

  float am0=0, am1=0, bm0=0, bm1=0;    // main accs: h0 pair, h1 pair
  float rh0=0, rh1=0;                  // distributed remainder accs

  // process one group of <=8 edges; offL/c0L/c1L are this lane's per-edge values for the chunk
  auto group8 = [&](int offL, float c0L, float c1L, int j, int cnt){
    u32 d[8]; float ca[8], cb[8];
    #pragma unroll
    for (int g = 0; g < 8; g++){
      bool v = g < cnt;
      int e = v ? j + g : j;
      int off = __shfl(offL, e, 64);
      ca[g] = v ? __shfl(c0L, e, 64) : 0.f;
      cb[g] = v ? __shfl(c1L, e, 64) : 0.f;
      d[g] = *(const u32*)(featB + off + laneByte);
    }
    #pragma unroll
    for (int g = 0; g < 8; g++){
      union{u32 i; float f;} lo, hi;
      lo.i = d[g] << 16; hi.i = d[g] & 0xffff0000u;
      am0 = fmaf(ca[g], lo.f, am0); am1 = fmaf(ca[g], hi.f, am1);
      bm0 = fmaf(cb[g], lo.f, bm0); bm1 = fmaf(cb[g], hi.f, bm1);
    }
    // remainder channels distributed: lane handles ch 128+(lane&7) of edge j+(lane>>3)
    int sl = lane >> 3;
    bool vr = sl < cnt;
    int er = vr ? j + sl : j;
    int offr = __shfl(offL, er, 64);
    float rc0 = vr ? __shfl(c0L, er, 64) : 0.f;
    float rc1 = vr ? __shfl(c1L, er, 64) : 0.f;
    float fv = u2f(*(const u16*)(featB + offr + remByte));
    rh0 = fmaf(rc0, fv, rh0);
    rh1 = fmaf(rc1, fv, rh1);
  };

  if (ne <= 64){
    const bool has = lane < ne;
    const int sn = nbase + (has ? srcl[start + lane] : 0);
    const int off64 = sn * 320;
    float al0 = has ? lrelu02(asrc[(size_t)sn*2]   + ad0)  : -1e30f;
    float al1 = has ? lrelu02(asrc[(size_t)sn*2+1] + ad1v) : -1e30f;
    float m0 = wred_max(al0);
    float p0 = has ? __expf(al0 - m0) : 0.f;
    float c0 = p0 * (1.f/(wred_sum(p0) + 1e-16f));
    float m1 = wred_max(al1);
    float p1 = has ? __expf(al1 - m1) : 0.f;
    float c1 = p1 * (1.f/(wred_sum(p1) + 1e-16f));
    int j = 0;
    for (; j + 8 <= ne; j += 8) group8(off64, c0, c1, j, 8);
    if (j < ne) group8(off64, c0, c1, j, ne - j);
  } else {
    float lm0 = -1e30f, lm1 = -1e30f;
    for (int e = start + lane; e < end; e += 64){
      int sn = nbase + srcl[e];
      lm0 = fmaxf(lm0, lrelu02(asrc[(size_t)sn*2]   + ad0));
      lm1 = fmaxf(lm1, lrelu02(asrc[(size_t)sn*2+1] + ad1v));
    }
    float m0 = wred_max(lm0), m1 = wred_max(lm1);
    float ls0 = 0.f, ls1 = 0.f;
    for (int e = start + lane; e < end; e += 64){
      int sn = nbase + srcl[e];
      ls0 += __expf(lrelu02(asrc[(size_t)sn*2]   + ad0)  - m0);
      ls1 += __expf(lrelu02(asrc[(size_t)sn*2+1] + ad1v) - m1);
    }
    float si0 = 1.f/(wred_sum(ls0) + 1e-16f);
    float si1 = 1.f/(wred_sum(ls1) + 1e-16f);
    for (int cs2 = start; cs2 < end; cs2 += 64){
      int cnt = min(64, end - cs2);
      bool has = lane < cnt;
      int sn = nbase + (has ? srcl[cs2 + lane] : 0);
      int off64 = sn * 320;
      float c0 = 0.f, c1 = 0.f;
      if (has){
        c0 = __expf(lrelu02(asrc[(size_t)sn*2]   + ad0)  - m0) * si0;
        c1 = __expf(lrelu02(asrc[(size_t)sn*2+1] + ad1v) - m1) * si1;
      }
      int j = 0;
      for (; j + 8 <= cnt; j += 8) group8(off64, c0, c1, j, 8);
      if (j < cnt) group8(off64, c0, c1, j, cnt - j);
    }
  }

  // reduce distributed remainder (8 lanes share each rem channel)
  #pragma unroll
  for (int o = 8; o < 64; o <<= 1){
    rh0 += __shfl_xor(rh0, o, 64);
    rh1 += __shfl_xor(rh1, o, 64);
  }

  u16* outp = aggF + (size_t)node*288;
  {
    int c = 2*lane;
    ushort2 s0; s0.x = f2u(am0); s0.y = f2u(am1);
    *(ushort2*)(outp + c) = s0;
    ushort2 s1; s1.x = f2u(bm0); s1.y = f2u(bm1);
    *(ushort2*)(outp + 136 + c) = s1;
    if (lane < 8){
      outp[128 + lane]       = f2u(rh0);
      outp[136 + 128 + lane] = f2u(rh1);
    }
  }
  {
    int c = 2*lane;
    float s = am0*v2s[c] + am1*v2s[c+1] + bm0*v2s[136+c] + bm1*v2s[136+c+1];
    float d = am0*v2d[c] + am1*v2d[c+1] + bm0*v2d[136+c] + bm1*v2d[136+c+1];
    if (lane < 8){
      s += rh0*v2s[128+lane] + rh1*v2s[136+128+lane];
      d += rh0*v2d[128+lane] + rh1*v2d[136+128+lane];
    }
    s = wred_sum(s); d = wred_sum(d);
    if (lane == 0){ as_out[node] = s + cc[0]; ad_out[node] = d + cc[1]; }
  }
}

// ---------------- layer-2 GAT aggregation (H=1): group-of-8, distributed remainder ----------------
__global__ void __launch_bounds__(256) k_agg2(const u16* __restrict__ h, int sh,
    const float* __restrict__ asrc, const float* __restrict__ adst,
    const int* __restrict__ offs, const int* __restrict__ srcl,
    const float* __restrict__ bias, u16* __restrict__ outp0, int so,
    int cbMask, int cbShift)
{
  const int wv = threadIdx.x >> 6, lane = threadIdx.x & 63;
  const int id = blockIdx.x;
  const int bb = id & cbMask;
  const int dst = (id >> cbShift)*4 + wv;
  const int nbase = bb*N0_;
  const int node = nbase + dst;
  const int start = offs[dst], end = offs[dst+1];
  const int ne = end - start;
  const int bstride = 2*sh;

  const float adh = adst[node];

  const char* hB = (const char*)h;
  const int laneByte = 4*lane;
  const int remByte  = 256 + ((lane & 7) << 1);

  float a0=0, a1=0, rh=0;

  auto group8 = [&](int offL, float c0L, int j, int cnt){
    u32 d[8]; float ca[8];
    #pragma unroll
    for (int g = 0; g < 8; g++){
      bool v = g < cnt;
      int e = v ? j + g : j;
      int off = __shfl(offL, e, 64);
      ca[g] = v ? __shfl(c0L, e, 64) : 0.f;
      d[g] = *(const u32*)(hB + off + laneByte);
    }
    #pragma unroll
    for (int g = 0; g < 8; g++){
      union{u32 i; float f;} lo, hi;
      lo.i = d[g] << 16; hi.i = d[g] & 0xffff0000u;
      a0 = fmaf(ca[g], lo.f, a0); a1 = fmaf(ca[g], hi.f, a1);
    }
    int sl = lane >> 3;
    bool vr = sl < cnt;
    int er = vr ? j + sl : j;
    int offr = __shfl(offL, er, 64);
    float rc = vr ? __shfl(c0L, er, 64) : 0.f;
    float fv = u2f(*(const u16*)(hB + offr + remByte));
    rh = fmaf(rc, fv, rh);
  };

  if (ne <= 64){
    const bool has = lane < ne;
    const int sn = nbase + (has ? srcl[start + lane] : 0);
    const int off64 = sn * bstride;
    float al = has ? lrelu02(asrc[sn] + adh) : -1e30f;
    float m = wred_max(al);
    float p = has ? __expf(al - m) : 0.f;
    float c0 = p * (1.f/(wred_sum(p) + 1e-16f));
    int j = 0;
    for (; j + 8 <= ne; j += 8) group8(off64, c0, j, 8);
    if (j < ne) group8(off64, c0, j, ne - j);
  } else {
    float lm = -1e30f;
    for (int e = start + lane; e < end; e += 64){
      int sn = nbase + srcl[e];
      lm = fmaxf(lm, lrelu02(asrc[sn] + adh));
    }
    float m = wred_max(lm);
    float ls = 0.f;
    for (int e = start + lane; e < end; e += 64){
      int sn = nbase + srcl[e];
      ls += __expf(lrelu02(asrc[sn] + adh) - m);
    }
    float si = 1.f/(wred_sum(ls) + 1e-16f);
    for (int cs = start; cs < end; cs += 64){
      int cnt = min(64, end - cs);
      bool has = lane < cnt;
      int sn = nbase + (has ? srcl[cs + lane] : 0);
      int off64 = sn * bstride;
      float c0 = has ? __expf(lrelu02(asrc[sn] + adh) - m) * si : 0.f;
      int j = 0;
      for (; j + 8 <= cnt; j += 8) group8(off64, c0, j, 8);
      if (j < cnt) group8(off64, c0, j, cnt - j);
    }
  }

  #pragma unroll
  for (int o = 8; o < 64; o <<= 1) rh += __shfl_xor(rh, o, 64);

  u16* outp = outp0 + (size_t)node*so;
  {
    int c = 2*lane;
    float r0 = lrelu01(a0 + bias[c]);
    float r1 = lrelu01(a1 + bias[c+1]);
    ushort2 st; st.x = f2u(r0); st.y = f2u(r1);
    *(ushort2*)(outp + c) = st;
    if (lane < 8){
      float rr = lrelu01(rh + bias[128 + lane]);
      outp[128 + lane] = f2u(rr);
    }
  }
}

// ---------------- launch ----------------
extern "C" void kernel_launch(void* const* d_in, const int* in_sizes, int n_in,
                              void* d_out, int out_size, void* d_ws, size_t ws_size,
                              hipStream_t stream)
{
  (void)in_sizes; (void)n_in; (void)out_size;
  const float* x    = (const float*)d_in[0];
  const float* wl1  = (const float*)d_in[1];
  const float* gl1  = (const float*)d_in[3];
  const float* bel1 = (const float*)d_in[4];
  const float* wl2  = (const float*)d_in[5];
  const float* gl2  = (const float*)d_in[7];
  const float* bel2 = (const float*)d_in[8];
  const float* wp1  = (const float*)d_in[9];
  const float* gp1  = (const float*)d_in[11];
  const float* bep1 = (const float*)d_in[12];
  const float* wp2  = (const float*)d_in[13];
  const float* gp2  = (const float*)d_in[15];
  const float* bep2 = (const float*)d_in[16];
  const float* wg   = (const float*)d_in[17];
  const float* gg   = (const float*)d_in[19];
  const float* beg  = (const float*)d_in[20];
  const float* W1   = (const float*)d_in[21];
  const float* as1  = (const float*)d_in[22];
  const float* ad1  = (const float*)d_in[23];
  const float* bb1  = (const float*)d_in[24];
  const float* W2   = (const float*)d_in[25];
  const float* as2  = (const float*)d_in[26];
  const float* ad2  = (const float*)d_in[27];
  const float* bb2  = (const float*)d_in[28];
  const float* Wo   = (const float*)d_in[29];
  const float* bo   = (const float*)d_in[30];
  const float* Wo2  = (const float*)d_in[31];
  const float* bo2  = (const float*)d_in[32];
  const int*   ei   = (const int*)d_in[33];

  const size_t STATIC_BYTES = 1200000;
  int nc = 1;
  while (nc < 8 && STATIC_BYTES + (size_t)1880*(NODES/nc) > ws_size) nc <<= 1;
  const int CB = B_/nc, CN = CB*N0_;
  int cbShift = 0; while ((1 << cbShift) < CB) cbShift++;
  const int cbMask = CB - 1;

  char* wsb = (char*)d_ws; size_t off = 0;
  auto alloc = [&](size_t nbytes)->void*{
    void* p = wsb + off; off = (off + nbytes + 255) & ~(size_t)255; return p;
  };
  int*   zbase  = (int*)  alloc(20080*sizeof(int));
  float* gsum   = (float*)zbase;
  float* gsq    = gsum + 40;
  int*   counts = zbase + 80;
  int*   cursor = counts + 10000;
  float* sA     = (float*)alloc(40*sizeof(float));
  float* sB     = (float*)alloc(40*sizeof(float));
  int*   offs   = (int*)  alloc(10001*sizeof(int));
  int*   srcl   = (int*)  alloc((size_t)NE_*sizeof(int));
  u16*   W12T   = (u16*)  alloc((size_t)144*288*2);
  u16*   WoT    = (u16*)  alloc((size_t)144*320*2);
  float* va1s   = (float*)alloc(272*sizeof(float));
  float* va1d   = (float*)alloc(272*sizeof(float));
  float* v2ss   = (float*)alloc(272*sizeof(float));
  float* v2dd   = (float*)alloc(272*sizeof(float));
  float* ccv    = (float*)alloc(2*sizeof(float));
  float* b12    = (float*)alloc(136*sizeof(float));
  u16*   feat   = (u16*)  alloc((size_t)CN*160*2);
  u16*   featL  = (u16*)  alloc((size_t)CN*160*2);
  u16*   aggF   = (u16*)  alloc((size_t)CN*288*2);
  u16*   h2     = (u16*)  alloc((size_t)CN*144*2);
  u16*   g2l    = (u16*)  alloc((size_t)CN*160*2);
  float* asrc1  = (float*)alloc((size_t)CN*2*sizeof(float));
  float* adst1  = (float*)alloc((size_t)CN*2*sizeof(float));
  float* asrc2  = (float*)alloc((size_t)CN*sizeof(float));
  float* adst2  = (float*)alloc((size_t)CN*sizeof(float));

  k_setup<<<425,256,0,stream>>>(zbase, Wo, WoT, W1, W2, W12T,
                                as1, ad1, va1s, va1d, as2, ad2, bb1,
                                v2ss, v2dd, ccv, b12);

  k_bn_stats<<<625,256,0,stream>>>(x, wl1,wl2,wp1,wp2,wg, gsum, gsq);
  k_bn_fin  <<<1,64,0,stream>>>(gsum, gsq, sA, sB, gl1,gl2,gp1,gp2,gg, bel1,bel2,bep1,bep2,beg);

  k_count  <<<665,256,0,stream>>>(ei, counts);
  k_scan   <<<1,1024,0,stream>>>(counts, offs);
  k_scatter<<<665,256,0,stream>>>(ei, offs, cursor, srcl);

  const int gx  = (CN + 255)/256;
  const int gx2 = (CN + 127)/128;
  const int aggB = 2500*CB;
  for (int c = 0; c < nc; c++){
    const int base = c*CN;

    k_feat<<<gx2,256,0,stream>>>(x, wl1,wl2,wp1,wp2,wg, sA, sB, va1s, va1d,
                                 feat, featL, asrc1, adst1, base, CN);

    k_agg1<<<aggB,256,0,stream>>>(feat, asrc1, adst1, offs, srcl, aggF,
                                  v2ss, v2dd, ccv, asrc2, adst2, cbMask, cbShift);

    k_mfma<9,0,9,3,0><<<gx,256,0,stream>>>(aggF,288, (const u16*)0,0, W12T,288, h2,144, 0, b12, CN,
                                           (const float*)0,(const float*)0,(float*)0);

    k_agg2<<<aggB,256,0,stream>>>(h2,144, asrc2, adst2, offs, srcl, bb2, g2l,160,
                                  cbMask, cbShift);

    k_mfma<5,5,9,2,0><<<gx,256,0,stream>>>(g2l,160, featL,160, WoT,320, (u16*)0,0, 0, bo, CN,
                                           Wo2, bo2, (float*)d_out + base);
  }
}

// Round 13
// 506.779 us; speedup vs baseline: 1.7311x; 1.0209x over previous
//
#include <hip/hip_runtime.h>
#include <hip/hip_bf16.h>
#include <math.h>

typedef unsigned short u16;
typedef unsigned int   u32;
typedef short v8s __attribute__((ext_vector_type(8)));
typedef float v4f __attribute__((ext_vector_type(4)));
#define DEV static __device__ __forceinline__

DEV float u2f(u16 u){ union{u32 i; float f;} v; v.i = ((u32)u)<<16; return v.f; }
DEV u16   f2u(float f){ union{float ff; u32 i;} v; v.ff = f; u32 r = v.i + 0x7fffu + ((v.i>>16)&1u); return (u16)(r>>16); }
DEV float lrelu02(float x){ return x > 0.f ? x : 0.2f*x; }
DEV float lrelu01(float x){ return x > 0.f ? x : 0.01f*x; }
DEV float fast_tanh(float x){
  float cx = fminf(fmaxf(x, -15.f), 15.f);
  float e = __expf(2.f*cx);
  return (e - 1.f) * __builtin_amdgcn_rcpf(e + 1.f);
}
DEV float wred_max(float v){
  #pragma unroll
  for (int o = 32; o > 0; o >>= 1) v = fmaxf(v, __shfl_xor(v, o, 64));
  return v;
}
DEV float wred_sum(float v){
  #pragma unroll
  for (int o = 32; o > 0; o >>= 1) v += __shfl_xor(v, o, 64);
  return v;
}

constexpr int B_   = 8;
constexpr int P_   = 32;
constexpr int N0_  = 10000;
constexpr int NODES = B_ * N0_;      // 80000
constexpr int E_   = 160000;
constexpr int NE_  = E_ + N0_;       // 170000

// ---------------- merged setup ----------------
__global__ void __launch_bounds__(256) k_setup(int* __restrict__ zbase,
    const float* __restrict__ Wo, u16* __restrict__ WoT,
    const float* __restrict__ W1, const float* __restrict__ W2, u16* __restrict__ W12T,
    const float* __restrict__ as1, const float* __restrict__ ad1,
    float* __restrict__ va1s, float* __restrict__ va1d,
    const float* __restrict__ as2, const float* __restrict__ ad2,
    const float* __restrict__ bb1,
    float* __restrict__ v2ss, float* __restrict__ v2dd,
    float* __restrict__ cc, float* __restrict__ b12)
{
  __shared__ float l2s[272], l2d[272];
  int blk = blockIdx.x, tid = threadIdx.x;
  if (blk < 79){ int i = blk*256 + tid; if (i < 20080) zbase[i] = 0; return; }
  blk -= 79;
  if (blk < 180){           // WoT[n][k] (144x320), head split
    int i = blk*256 + tid; if (i >= 144*320) return;
    int n = i/320, k = i - n*320; float v = 0.f;
    if (n < 136){
      if (k < 136) v = Wo[(size_t)k*136 + n];
      else if (k >= 160 && k < 296) v = Wo[(size_t)(k-24)*136 + n];
    }
    WoT[i] = f2u(v); return;
  }
  blk -= 180;
  if (blk < 162){           // W12T[n][kk] (144x288) = (W1@W2)^T per head-block
    int i = blk*256 + tid; if (i >= 144*288) return;
    int n = i/288, kk = i - n*288; float v = 0.f;
    if (n < 136 && kk < 272){
      int hh = kk/136, k = kk - hh*136;
      for (int c = 0; c < 136; c++)
        v = fmaf(W1[(size_t)k*272 + hh*136 + c], W2[(size_t)(hh*136+c)*136 + n], v);
    }
    W12T[i] = f2u(v); return;
  }
  blk -= 162;
  if (blk < 2){             // va1 = W1 a1 (272)
    int t = blk*256 + tid; if (t >= 272) return;
    int hh = t/136, k = t - hh*136; float s = 0.f, d = 0.f;
    for (int c = 0; c < 136; c++){
      float w = W1[(size_t)k*272 + hh*136 + c];
      s = fmaf(w, as1[hh*136+c], s);
      d = fmaf(w, ad1[hh*136+c], d);
    }
    va1s[t] = s; va1d[t] = d; return;
  }
  blk -= 2;
  {                         // v2'' = W1@(W2 a2); cc = bb1·(W2 a2); b12 = bb1@W2
    for (int m = tid; m < 272; m += 256){
      float vs = 0.f, vd = 0.f;
      for (int n2 = 0; n2 < 136; n2++){
        float w2 = W2[(size_t)m*136 + n2];
        vs = fmaf(w2, as2[n2], vs);
        vd = fmaf(w2, ad2[n2], vd);
      }
      l2s[m] = vs; l2d[m] = vd;
    }
    __syncthreads();
    int t0 = blk*256 + tid;
    if (t0 < 272){
      int hh = t0/136, k = t0 - hh*136; float s = 0.f, d = 0.f;
      for (int c = 0; c < 136; c++){
        float w = W1[(size_t)k*272 + hh*136 + c];
        s = fmaf(w, l2s[hh*136+c], s);
        d = fmaf(w, l2d[hh*136+c], d);
      }
      v2ss[t0] = s; v2dd[t0] = d;
    }
    if (blk == 1){
      if (tid < 64){
        float s = 0.f, d = 0.f;
        for (int m = tid; m < 272; m += 64){
          s = fmaf(bb1[m], l2s[m], s);
          d = fmaf(bb1[m], l2d[m], d);
        }
        s = wred_sum(s); d = wred_sum(d);
        if (tid == 0){ cc[0] = s; cc[1] = d; }
      } else if (tid < 200){
        int n2 = tid - 64; float v = 0.f;
        for (int m = 0; m < 272; m++) v = fmaf(bb1[m], W2[(size_t)m*136 + n2], v);
        b12[n2] = v;
      }
    }
  }
}

// ---------------- backbone ----------------
DEV void load_convw(float* lw, const float* wl1, const float* wl2, const float* wp1,
                    const float* wp2, const float* wg, int tid, int nth){
  for (int i = tid; i < 384; i += nth){
    float v;
    if      (i < 24)  v = wl1[i];
    else if (i < 64)  v = wl2[i-24];
    else if (i < 88)  v = wp1[i-64];
    else if (i < 128) v = wp2[i-88];
    else              v = wg [i-128];
    lw[i] = v;
  }
}

template<int KS,int DIL,int T>
DEV void conv_stats(const float* xc, const float* wk, float& s, float& q){
  #pragma unroll
  for (int t = 0; t < T; t++){
    float v = 0.f;
    #pragma unroll
    for (int j = 0; j < KS; j++) v = fmaf(wk[j], xc[t + j*DIL], v);
    s += v; q = fmaf(v, v, q);
  }
}

__global__ void __launch_bounds__(256) k_bn_stats(
    const float* __restrict__ x,
    const float* __restrict__ wl1, const float* __restrict__ wl2,
    const float* __restrict__ wp1, const float* __restrict__ wp2,
    const float* __restrict__ wg,
    float* __restrict__ gsum, float* __restrict__ gsq)
{
  __shared__ float lw[384];
  __shared__ float lacc[80];
  const int tid = threadIdx.x;
  load_convw(lw, wl1, wl2, wp1, wp2, wg, tid, 256);
  if (tid < 80) lacc[tid] = 0.f;
  __syncthreads();

  const int lane = tid & 63, wv = tid >> 6;
  const int nodeLocal = (wv >> 1)*64 + lane;
  const int half = wv & 1;
  const int gid = blockIdx.x*128 + nodeLocal;
  float xc[P_];
  if (gid < NODES){
    int b = gid / N0_, n = gid - b*N0_;
    const float* xp = x + (size_t)b*P_*N0_ + n;
    #pragma unroll
    for (int p = 0; p < P_; p++) xc[p] = xp[(size_t)p*N0_];
  } else {
    #pragma unroll
    for (int p = 0; p < P_; p++) xc[p] = 0.f;
  }

  auto red = [&](int ch, float s, float q){
    #pragma unroll
    for (int o = 32; o > 0; o >>= 1){ s += __shfl_down(s,o,64); q += __shfl_down(q,o,64); }
    if (lane == 0){ atomicAdd(&lacc[ch], s); atomicAdd(&lacc[40+ch], q); }
  };

  if (half == 0){
    #pragma unroll
    for (int k = 0; k < 8; k++){ float s=0,q=0; conv_stats<3,1,30>(xc, lw      + k*3 , s,q); red(k,     s,q); }
    #pragma unroll
    for (int k = 0; k < 8; k++){ float s=0,q=0; conv_stats<5,1,28>(xc, lw + 24 + k*5 , s,q); red(8+k,   s,q); }
  } else {
    #pragma unroll
    for (int k = 0; k < 8; k++){ float s=0,q=0; conv_stats<3,2,28>(xc, lw + 64 + k*3 , s,q); red(16+k,  s,q); }
    #pragma unroll
    for (int k = 0; k < 8; k++){ float s=0,q=0; conv_stats<5,2,24>(xc, lw + 88 + k*5 , s,q); red(24+k,  s,q); }
    #pragma unroll
    for (int k = 0; k < 8; k++){ float s=0,q=0; conv_stats<32,1,1>(xc, lw + 128+ k*32, s,q); red(32+k,  s,q); }
  }

  __syncthreads();
  if (tid < 40)      atomicAdd(&gsum[tid],    lacc[tid]);
  else if (tid < 80) atomicAdd(&gsq [tid-40], lacc[tid]);
}

__global__ void k_bn_fin(const float* __restrict__ gsum, const float* __restrict__ gsq,
                         float* __restrict__ sA, float* __restrict__ sB,
                         const float* g0, const float* g1, const float* g2, const float* g3, const float* g4,
                         const float* e0, const float* e1, const float* e2, const float* e3, const float* e4)
{
  int t = threadIdx.x;
  if (t >= 40) return;
  int bi = t >> 3, k = t & 7;
  const int Ts[5] = {30,28,28,24,1};
  float cnt  = (float)NODES * (float)Ts[bi];
  float mean = gsum[t] / cnt;
  float var  = gsq[t] / cnt - mean*mean;
  const float* gp = bi==0?g0: bi==1?g1: bi==2?g2: bi==3?g3: g4;
  const float* ep = bi==0?e0: bi==1?e1: bi==2?e2: bi==3?e3: e4;
  float a = gp[k] * rsqrtf(fmaxf(var, 0.f) + 1e-5f);
  sA[t] = a;
  sB[t] = ep[k] - a*mean;
}

template<int KS,int DIL,int T>
DEV void conv_pool4(const float* xc, const float* wk, float A, float Bc, float* o4){
  float y[T];
  #pragma unroll
  for (int t = 0; t < T; t++){
    float v = 0.f;
    #pragma unroll
    for (int j = 0; j < KS; j++) v = fmaf(wk[j], xc[t + j*DIL], v);
    y[t] = fmaf(A, v, Bc);
  }
  #pragma unroll
  for (int i = 0; i < 4; i++){
    const int lo = (i*T)/4, hi = ((i+1)*T + 3)/4;
    float m = y[lo];
    #pragma unroll
    for (int t = 0; t < T; t++){ if (t > lo && t < hi) m = fmaxf(m, y[t]); }
    o4[i] = m;
  }
}

// feat [m][160] bf16 (tanh) + featL (lrelu01) + fused layer-1 attention dots (float4 LDS)
__global__ void __launch_bounds__(256) k_feat(
    const float* __restrict__ x,
    const float* __restrict__ wl1, const float* __restrict__ wl2,
    const float* __restrict__ wp1, const float* __restrict__ wp2,
    const float* __restrict__ wg,
    const float* __restrict__ sA, const float* __restrict__ sB,
    const float* __restrict__ va1s, const float* __restrict__ va1d,
    u16* __restrict__ feat, u16* __restrict__ featL,
    float* __restrict__ asrc1, float* __restrict__ adst1,
    int base, int m)
{
  __shared__ float lw[384];
  __shared__ float lA[40], lB[40];
  __shared__ float4 lv4[136];
  __shared__ float sdt[128][4];
  const int tid = threadIdx.x;
  load_convw(lw, wl1, wl2, wp1, wp2, wg, tid, 256);
  if (tid < 40){ lA[tid] = sA[tid]; lB[tid] = sB[tid]; }
  for (int i = tid; i < 136; i += 256)
    lv4[i] = make_float4(va1s[i], va1d[i], va1s[136+i], va1d[136+i]);
  __syncthreads();

  const int lane = tid & 63, wv = tid >> 6;
  const int nodeLocal = (wv >> 1)*64 + lane;     // 0..127
  const int half = wv & 1;                       // wave-uniform
  const int nodeIdx = blockIdx.x*128 + nodeLocal;
  const bool act = nodeIdx < m;
  const int gcl = base + (act ? nodeIdx : (m-1));
  int b = gcl / N0_, n = gcl - b*N0_;
  float xc[P_];
  const float* xp = x + (size_t)b*P_*N0_ + n;
  #pragma unroll
  for (int p = 0; p < P_; p++) xc[p] = xp[(size_t)p*N0_];

  float dt[4] = {0.f,0.f,0.f,0.f};
  u32 pk[4], pkl[4];
  u16* orow  = feat  + (size_t)nodeIdx*160;
  u16* olrow = featL + (size_t)nodeIdx*160;
  auto emit = [&](int ch, float v){
    float t = fast_tanh(v);
    float4 vv = lv4[ch];
    dt[0] = fmaf(t, vv.x, dt[0]);
    dt[1] = fmaf(t, vv.y, dt[1]);
    dt[2] = fmaf(t, vv.z, dt[2]);
    dt[3] = fmaf(t, vv.w, dt[3]);
    u16 h  = f2u(t);
    u16 hl = f2u(lrelu01(t));
    int s = ch & 7;
    if ((s & 1) == 0){ pk[s>>1] = h;                pkl[s>>1] = hl; }
    else             { pk[s>>1] |= ((u32)h) << 16;  pkl[s>>1] |= ((u32)hl) << 16; }
    if (s == 7 && act){
      *(uint4*)(orow  + (ch - 7)) = make_uint4(pk[0],pk[1],pk[2],pk[3]);
      *(uint4*)(olrow + (ch - 7)) = make_uint4(pkl[0],pkl[1],pkl[2],pkl[3]);
    }
  };

  float o4[4];
  if (half == 0){
    #pragma unroll
    for (int k = 0; k < 8; k++){
      conv_pool4<3,1,30>(xc, lw + k*3, lA[k], lB[k], o4);
      #pragma unroll
      for (int i = 0; i < 4; i++) emit(k*4+i, o4[i]);
    }
    #pragma unroll
    for (int k = 0; k < 8; k++){
      conv_pool4<5,1,28>(xc, lw + 24 + k*5, lA[8+k], lB[8+k], o4);
      #pragma unroll
      for (int i = 0; i < 4; i++) emit(32 + k*4+i, o4[i]);
    }
  } else {
    #pragma unroll
    for (int k = 0; k < 8; k++){
      conv_pool4<3,2,28>(xc, lw + 64 + k*3, lA[16+k], lB[16+k], o4);
      #pragma unroll
      for (int i = 0; i < 4; i++) emit(64 + k*4+i, o4[i]);
    }
    #pragma unroll
    for (int k = 0; k < 8; k++){
      conv_pool4<5,2,24>(xc, lw + 88 + k*5, lA[24+k], lB[24+k], o4);
      #pragma unroll
      for (int i = 0; i < 4; i++) emit(96 + k*4+i, o4[i]);
    }
    #pragma unroll
    for (int k = 0; k < 8; k++){
      float v = 0.f;
      #pragma unroll
      for (int j = 0; j < 32; j++) v = fmaf(lw[128 + k*32 + j], xc[j], v);
      emit(128 + k, fmaf(lA[32+k], v, lB[32+k]));
    }
  }

  if (half == 1){
    sdt[nodeLocal][0] = dt[0]; sdt[nodeLocal][1] = dt[1];
    sdt[nodeLocal][2] = dt[2]; sdt[nodeLocal][3] = dt[3];
  }
  __syncthreads();
  if (half == 0 && act){
    asrc1[(size_t)nodeIdx*2]   = dt[0] + sdt[nodeLocal][0];
    asrc1[(size_t)nodeIdx*2+1] = dt[2] + sdt[nodeLocal][2];
    adst1[(size_t)nodeIdx*2]   = dt[1] + sdt[nodeLocal][1];
    adst1[(size_t)nodeIdx*2+1] = dt[3] + sdt[nodeLocal][3];
  }
}

// ---------------- CSR ----------------
__global__ void k_count(const int* __restrict__ ei, int* __restrict__ counts){
  int e = blockIdx.x*blockDim.x + threadIdx.x;
  if (e >= NE_) return;
  int dst = (e < E_) ? ei[E_ + e] : (e - E_);
  atomicAdd(&counts[dst], 1);
}

__global__ void __launch_bounds__(1024) k_scan(const int* __restrict__ counts, int* __restrict__ offs){
  __shared__ int part[1024];
  int t = threadIdx.x;
  int loc[10]; int s = 0;
  #pragma unroll
  for (int i = 0; i < 10; i++){
    int idx = t*10 + i;
    int c = (idx < N0_) ? counts[idx] : 0;
    loc[i] = s; s += c;
  }
  part[t] = s;
  __syncthreads();
  for (int o = 1; o < 1024; o <<= 1){
    int v = (t >= o) ? part[t-o] : 0;
    __syncthreads();
    part[t] += v;
    __syncthreads();
  }
  int pre = (t == 0) ? 0 : part[t-1];
  #pragma unroll
  for (int i = 0; i < 10; i++){
    int idx = t*10 + i;
    if (idx < N0_) offs[idx] = pre + loc[i];
  }
  if (t == 0) offs[N0_] = part[1023];
}

__global__ void k_scatter(const int* __restrict__ ei, const int* __restrict__ offs,
                          int* __restrict__ cursor, int* __restrict__ srcl){
  int e = blockIdx.x*blockDim.x + threadIdx.x;
  if (e >= NE_) return;
  int src, dst;
  if (e < E_){ src = ei[e]; dst = ei[E_ + e]; } else { src = dst = e - E_; }
  int pos = atomicAdd(&cursor[dst], 1);
  srcl[offs[dst] + pos] = src;
}

// ---------------- MFMA GEMM ----------------
template<int KT1,int KT2,int NT,int EPI,int LR2>
__global__ void __launch_bounds__(256) k_mfma(
    const u16* __restrict__ A1, int sA1,
    const u16* __restrict__ A2, int sA2,
    const u16* __restrict__ BT, int sBT,
    u16* __restrict__ C, int sC, int nbase,
    const float* __restrict__ bias, int m,
    const float* __restrict__ w2v, const float* __restrict__ bo2p, float* __restrict__ fout)
{
  const int wv = threadIdx.x >> 6, lane = threadIdx.x & 63;
  const int quad = lane >> 4, l15 = lane & 15;
  const int mb = blockIdx.x*256 + wv*64;
  int ar[4];
  #pragma unroll
  for (int mt = 0; mt < 4; mt++) ar[mt] = min(mb + mt*16 + l15, m-1);

  v4f acc[4][NT];
  #pragma unroll
  for (int mt = 0; mt < 4; mt++)
    #pragma unroll
    for (int nt = 0; nt < NT; nt++)
      acc[mt][nt] = (v4f){0.f,0.f,0.f,0.f};

  for (int kt = 0; kt < KT1+KT2; kt++){
    const u16* ab; int sA, koff;
    if (KT2 == 0 || kt < KT1){ ab = A1; sA = sA1; koff = kt*32; }
    else { ab = A2; sA = sA2; koff = (kt-KT1)*32; }
    v8s a[4];
    #pragma unroll
    for (int mt = 0; mt < 4; mt++)
      a[mt] = *(const v8s*)(ab + (size_t)ar[mt]*sA + koff + quad*8);
    if (KT2 > 0 && LR2 && kt >= KT1){
      #pragma unroll
      for (int mt = 0; mt < 4; mt++)
        #pragma unroll
        for (int j = 0; j < 8; j++){
          float f = u2f((u16)a[mt][j]);
          f = f > 0.f ? f : 0.01f*f;
          a[mt][j] = (short)f2u(f);
        }
    }
    const int kb = kt*32 + quad*8;
    #pragma unroll
    for (int nt = 0; nt < NT; nt++){
      v8s b = *(const v8s*)(BT + (size_t)(nbase + nt*16 + l15)*sBT + kb);
      #pragma unroll
      for (int mt = 0; mt < 4; mt++)
        acc[mt][nt] = __builtin_amdgcn_mfma_f32_16x16x32_bf16(a[mt], b, acc[mt][nt], 0, 0, 0);
    }
  }

  if (EPI == 2){
    const float bo2v = bo2p[0];
    #pragma unroll
    for (int mt = 0; mt < 4; mt++){
      float part[4] = {0.f,0.f,0.f,0.f};
      #pragma unroll
      for (int nt = 0; nt < NT; nt++){
        const int col = nt*16 + l15;
        float wv2 = (col < 136) ? w2v[col] : 0.f;
        float bv  = bias[min(col,135)];
        #pragma unroll
        for (int i = 0; i < 4; i++){
          float xv = lrelu01(acc[mt][nt][i] + bv);
          part[i] = fmaf(xv, wv2, part[i]);
        }
      }
      #pragma unroll
      for (int i = 0; i < 4; i++){
        float v = part[i];
        v += __shfl_xor(v, 1, 64);
        v += __shfl_xor(v, 2, 64);
        v += __shfl_xor(v, 4, 64);
        v += __shfl_xor(v, 8, 64);
        int r = mb + mt*16 + quad*4 + i;
        if (l15 == 0 && r < m) fout[r] = v + bo2v;
      }
    }
    return;
  }

  #pragma unroll
  for (int mt = 0; mt < 4; mt++){
    const int r0 = mb + mt*16 + quad*4;
    #pragma unroll
    for (int nt = 0; nt < NT; nt++){
      const int col = nbase + nt*16 + l15;
      #pragma unroll
      for (int i = 0; i < 4; i++){
        int r = r0 + i;
        if (r < m){
          float xv = acc[mt][nt][i];
          if (EPI == 1){ xv += bias[min(col,135)]; xv = lrelu01(xv); }
          if (EPI == 3){ xv += bias[min(col,135)]; }
          C[(size_t)r*sC + col] = f2u(xv);
        }
      }
    }
  }
}

// ---------------- layer-1 GAT aggregation on feat (unroll-4, byte-offset shfl) ----------------
__global__ void __launch_bounds__(256) k_agg1(const u16* __restrict__ feat,
    const float* __restrict__ asrc, const float* __restrict__ adst,
    const int* __restrict__ offs, const int* __restrict__ srcl,
    u16* __restrict__ aggF,
    const float* __restrict__ v2s, const float* __restrict__ v2d,
    const float* __restrict__ cc,
    float* __restrict__ as_out, float* __restrict__ ad_out,
    int cbMask, int cbShift)
{
  const int wv = threadIdx.x >> 6, lane = threadIdx.x & 63;
  const int id = blockIdx.x;
  const int bb = id & cbMask;
  const int dst = (id >> cbShift)*4 + wv;
  const int nbase = bb*N0_;
  const int node = nbase + dst;
  const int start = offs[dst], end = offs[dst+1];
  const int ne = end - start;

  const float ad0 = adst[(size_t)node*2], ad1v = adst[(size_t)node*2+1];

  const char* featB = (const char*)feat;

  float am0h0=0,am1h0=0,am0h1=0,am1h1=0;
  float ar0h0=0,ar1h0=0,ar0h1=0,ar1h1=0;

  auto acc_edge = [&](int off, float c0, float c1){
    const u16* fp = (const u16*)(featB + off);
    const ushort2 hv = *(const ushort2*)(fp + 2*lane);
    float f0 = u2f(hv.x), f1 = u2f(hv.y);
    am0h0 = fmaf(c0, f0, am0h0); am1h0 = fmaf(c0, f1, am1h0);
    am0h1 = fmaf(c1, f0, am0h1); am1h1 = fmaf(c1, f1, am1h1);
    if (lane < 4){
      const ushort2 hr = *(const ushort2*)(fp + 128 + 2*lane);
      float r0 = u2f(hr.x), r1 = u2f(hr.y);
      ar0h0 = fmaf(c0, r0, ar0h0); ar1h0 = fmaf(c0, r1, ar1h0);
      ar0h1 = fmaf(c1, r0, ar0h1); ar1h1 = fmaf(c1, r1, ar1h1);
    }
  };
  auto acc_edge4 = [&](int o0, int o1, int o2, int o3,
                       float a0, float a1, float a2, float a3,
                       float b0, float b1, float b2, float b3){
    const u16* p0 = (const u16*)(featB + o0);
    const u16* p1 = (const u16*)(featB + o1);
    const u16* p2 = (const u16*)(featB + o2);
    const u16* p3 = (const u16*)(featB + o3);
    const ushort2 v0 = *(const ushort2*)(p0 + 2*lane);
    const ushort2 v1 = *(const ushort2*)(p1 + 2*lane);
    const ushort2 v2 = *(const ushort2*)(p2 + 2*lane);
    const ushort2 v3 = *(const ushort2*)(p3 + 2*lane);
    ushort2 r0, r1, r2, r3;
    if (lane < 4){
      r0 = *(const ushort2*)(p0 + 128 + 2*lane);
      r1 = *(const ushort2*)(p1 + 128 + 2*lane);
      r2 = *(const ushort2*)(p2 + 128 + 2*lane);
      r3 = *(const ushort2*)(p3 + 128 + 2*lane);
    }
    float f;
    f = u2f(v0.x); am0h0 = fmaf(a0,f,am0h0); am0h1 = fmaf(b0,f,am0h1);
    f = u2f(v0.y); am1h0 = fmaf(a0,f,am1h0); am1h1 = fmaf(b0,f,am1h1);
    f = u2f(v1.x); am0h0 = fmaf(a1,f,am0h0); am0h1 = fmaf(b1,f,am0h1);
    f = u2f(v1.y); am1h0 = fmaf(a1,f,am1h0); am1h1 = fmaf(b1,f,am1h1);
    f = u2f(v2.x); am0h0 = fmaf(a2,f,am0h0); am0h1 = fmaf(b2,f,am0h1);
    f = u2f(v2.y); am1h0 = fmaf(a2,f,am1h0); am1h1 = fmaf(b2,f,am1h1);
    f = u2f(v3.x); am0h0 = fmaf(a3,f,am0h0); am0h1 = fmaf(b3,f,am0h1);
    f = u2f(v3.y); am1h0 = fmaf(a3,f,am1h0); am1h1 = fmaf(b3,f,am1h1);
    if (lane < 4){
      f = u2f(r0.x); ar0h0 = fmaf(a0,f,ar0h0); ar0h1 = fmaf(b0,f,ar0h1);
      f = u2f(r0.y); ar1h0 = fmaf(a0,f,ar1h0); ar1h1 = fmaf(b0,f,ar1h1);
      f = u2f(r1.x); ar0h0 = fmaf(a1,f,ar0h0); ar0h1 = fmaf(b1,f,ar0h1);
      f = u2f(r1.y); ar1h0 = fmaf(a1,f,ar1h0); ar1h1 = fmaf(b1,f,ar1h1);
      f = u2f(r2.x); ar0h0 = fmaf(a2,f,ar0h0); ar0h1 = fmaf(b2,f,ar0h1);
      f = u2f(r2.y); ar1h0 = fmaf(a2,f,ar1h0); ar1h1 = fmaf(b2,f,ar1h1);
      f = u2f(r3.x); ar0h0 = fmaf(a3,f,ar0h0); ar0h1 = fmaf(b3,f,ar0h1);
      f = u2f(r3.y); ar1h0 = fmaf(a3,f,ar1h0); ar1h1 = fmaf(b3,f,ar1h1);
    }
  };

  if (ne <= 64){
    const bool has = lane < ne;
    const int sn = nbase + (has ? srcl[start + lane] : 0);
    const int offL = sn * 320;
    float al0 = has ? lrelu02(asrc[(size_t)sn*2]   + ad0)  : -1e30f;
    float al1 = has ? lrelu02(asrc[(size_t)sn*2+1] + ad1v) : -1e30f;
    float m0 = wred_max(al0);
    float p0 = has ? __expf(al0 - m0) : 0.f;
    float c0 = p0 * (1.f/(wred_sum(p0) + 1e-16f));
    float m1 = wred_max(al1);
    float p1 = has ? __expf(al1 - m1) : 0.f;
    float c1 = p1 * (1.f/(wred_sum(p1) + 1e-16f));
    int j = 0;
    for (; j + 3 < ne; j += 4){
      int   o0 = __shfl(offL, j, 64),  o1 = __shfl(offL, j+1, 64);
      int   o2 = __shfl(offL, j+2, 64),o3 = __shfl(offL, j+3, 64);
      float a0 = __shfl(c0, j, 64),   a1 = __shfl(c0, j+1, 64);
      float a2 = __shfl(c0, j+2, 64), a3 = __shfl(c0, j+3, 64);
      float b0 = __shfl(c1, j, 64),   b1 = __shfl(c1, j+1, 64);
      float b2 = __shfl(c1, j+2, 64), b3 = __shfl(c1, j+3, 64);
      acc_edge4(o0,o1,o2,o3, a0,a1,a2,a3, b0,b1,b2,b3);
    }
    for (; j < ne; j++)
      acc_edge(__shfl(offL, j, 64), __shfl(c0, j, 64), __shfl(c1, j, 64));
  } else {
    float lm0 = -1e30f, lm1 = -1e30f;
    for (int e = start + lane; e < end; e += 64){
      int sn = nbase + srcl[e];
      lm0 = fmaxf(lm0, lrelu02(asrc[(size_t)sn*2]   + ad0));
      lm1 = fmaxf(lm1, lrelu02(asrc[(size_t)sn*2+1] + ad1v));
    }
    float m0 = wred_max(lm0), m1 = wred_max(lm1);
    float ls0 = 0.f, ls1 = 0.f;
    for (int e = start + lane; e < end; e += 64){
      int sn = nbase + srcl[e];
      ls0 += __expf(lrelu02(asrc[(size_t)sn*2]   + ad0)  - m0);
      ls1 += __expf(lrelu02(asrc[(size_t)sn*2+1] + ad1v) - m1);
    }
    float si0 = 1.f/(wred_sum(ls0) + 1e-16f);
    float si1 = 1.f/(wred_sum(ls1) + 1e-16f);
    for (int cs2 = start; cs2 < end; cs2 += 64){
      int cnt = min(64, end - cs2);
      bool has = lane < cnt;
      int sn = nbase + (has ? srcl[cs2 + lane] : 0);
      int offL = sn * 320;
      float c0 = 0.f, c1 = 0.f;
      if (has){
        c0 = __expf(lrelu02(asrc[(size_t)sn*2]   + ad0)  - m0) * si0;
        c1 = __expf(lrelu02(asrc[(size_t)sn*2+1] + ad1v) - m1) * si1;
      }
      for (int j = 0; j < cnt; j++)
        acc_edge(__shfl(offL, j, 64), __shfl(c0, j, 64), __shfl(c1, j, 64));
    }
  }

  u16* outp = aggF + (size_t)node*288;
  {
    int c = 2*lane;
    ushort2 s0; s0.x = f2u(am0h0); s0.y = f2u(am1h0);
    *(ushort2*)(outp + c) = s0;
    ushort2 s1; s1.x = f2u(am0h1); s1.y = f2u(am1h1);
    *(ushort2*)(outp + 136 + c) = s1;
    if (lane < 4){
      int cr = 128 + 2*lane;
      ushort2 r0; r0.x = f2u(ar0h0); r0.y = f2u(ar1h0);
      *(ushort2*)(outp + cr) = r0;
      ushort2 r1; r1.x = f2u(ar0h1); r1.y = f2u(ar1h1);
      *(ushort2*)(outp + 136 + cr) = r1;
    }
  }
  {
    int c = 2*lane;
    float s = am0h0*v2s[c] + am1h0*v2s[c+1] + am0h1*v2s[136+c] + am1h1*v2s[136+c+1];
    float d = am0h0*v2d[c] + am1h0*v2d[c+1] + am0h1*v2d[136+c] + am1h1*v2d[136+c+1];
    if (lane < 4){
      int cr = 128 + 2*lane;
      s += ar0h0*v2s[cr] + ar1h0*v2s[cr+1] + ar0h1*v2s[136+cr] + ar1h1*v2s[136+cr+1];
      d += ar0h0*v2d[cr] + ar1h0*v2d[cr+1] + ar0h1*v2d[136+cr] + ar1h1*v2d[136+cr+1];
    }
    s = wred_sum(s); d = wred_sum(d);
    if (lane == 0){ as_out[node] = s + cc[0]; ad_out[node] = d + cc[1]; }
  }
}

// ---------------- layer-2 GAT aggregation (H=1, unroll-4, byte-offset shfl) ----------------
__global__ void __launch_bounds__(256) k_agg2(const u16* __restrict__ h, int sh,
    const float* __restrict__ asrc, const float* __restrict__ adst,
    const int* __restrict__ offs, const int* __restrict__ srcl,
    const float* __restrict__ bias, u16* __restrict__ outp0, int so,
    int cbMask, int cbShift)
{
  constexpr int MAINC = 128;
  constexpr int REMV  = 4;

  const int wv = threadIdx.x >> 6, lane = threadIdx.x & 63;
  const int id = blockIdx.x;
  const int bb = id & cbMask;
  const int dst = (id >> cbShift)*4 + wv;
  const int nbase = bb*N0_;
  const int node = nbase + dst;
  const int start = offs[dst], end = offs[dst+1];
  const int ne = end - start;
  const int bstride = 2*sh;

  const float adh = adst[node];
  const char* hB = (const char*)h;

  float acc0=0, acc1=0, accr0=0, accr1=0;

  auto acc_edge = [&](int off, float c0){
    const u16* hp = (const u16*)(hB + off);
    const ushort2 hv = *(const ushort2*)(hp + 2*lane);
    acc0 = fmaf(c0, u2f(hv.x), acc0);
    acc1 = fmaf(c0, u2f(hv.y), acc1);
    if (lane < REMV){
      const ushort2 hr = *(const ushort2*)(hp + MAINC + 2*lane);
      accr0 = fmaf(c0, u2f(hr.x), accr0);
      accr1 = fmaf(c0, u2f(hr.y), accr1);
    }
  };
  auto acc_edge4 = [&](int o0, int o1, int o2, int o3,
                       float a0, float a1, float a2, float a3){
    const u16* p0 = (const u16*)(hB + o0);
    const u16* p1 = (const u16*)(hB + o1);
    const u16* p2 = (const u16*)(hB + o2);
    const u16* p3 = (const u16*)(hB + o3);
    const ushort2 v0 = *(const ushort2*)(p0 + 2*lane);
    const ushort2 v1 = *(const ushort2*)(p1 + 2*lane);
    const ushort2 v2 = *(const ushort2*)(p2 + 2*lane);
    const ushort2 v3 = *(const ushort2*)(p3 + 2*lane);
    ushort2 r0, r1, r2, r3;
    if (lane < REMV){
      r0 = *(const ushort2*)(p0 + MAINC + 2*lane);
      r1 = *(const ushort2*)(p1 + MAINC + 2*lane);
      r2 = *(const ushort2*)(p2 + MAINC + 2*lane);
      r3 = *(const ushort2*)(p3 + MAINC + 2*lane);
    }
    acc0 = fmaf(a0, u2f(v0.x), acc0); acc1 = fmaf(a0, u2f(v0.y), acc1);
    acc0 = fmaf(a1, u2f(v1.x), acc0); acc1 = fmaf(a1, u2f(v1.y), acc1);
    acc0 = fmaf(a2, u2f(v2.x), acc0); acc1 = fmaf(a2, u2f(v2.y), acc1);
    acc0 = fmaf(a3, u2f(v3.x), acc0); acc1 = fmaf(a3, u2f(v3.y), acc1);
    if (lane < REMV){
      accr0 = fmaf(a0, u2f(r0.x), accr0); accr1 = fmaf(a0, u2f(r0.y), accr1);
      accr0 = fmaf(a1, u2f(r1.x), accr0); accr1 = fmaf(a1, u2f(r1.y), accr1);
      accr0 = fmaf(a2, u2f(r2.x), accr0); accr1 = fmaf(a2, u2f(r2.y), accr1);
      accr0 = fmaf(a3, u2f(r3.x), accr0); accr1 = fmaf(a3, u2f(r3.y), accr1);
    }
  };

  if (ne <= 64){
    const bool has = lane < ne;
    const int sn = nbase + (has ? srcl[start + lane] : 0);
    const int offL = sn * bstride;
    float al = has ? lrelu02(asrc[sn] + adh) : -1e30f;
    float m = wred_max(al);
    float p = has ? __expf(al - m) : 0.f;
    float c0 = p * (1.f/(wred_sum(p) + 1e-16f));
    int j = 0;
    for (; j + 3 < ne; j += 4){
      int   o0 = __shfl(offL, j, 64),   o1 = __shfl(offL, j+1, 64);
      int   o2 = __shfl(offL, j+2, 64), o3 = __shfl(offL, j+3, 64);
      float a0 = __shfl(c0, j, 64),   a1 = __shfl(c0, j+1, 64);
      float a2 = __shfl(c0, j+2, 64), a3 = __shfl(c0, j+3, 64);
      acc_edge4(o0,o1,o2,o3, a0,a1,a2,a3);
    }
    for (; j < ne; j++)
      acc_edge(__shfl(offL, j, 64), __shfl(c0, j, 64));
  } else {
    float lm = -1e30f;
    for (int e = start + lane; e < end; e += 64){
      int sn = nbase + srcl[e];
      lm = fmaxf(lm, lrelu02(asrc[sn] + adh));
    }
    float m = wred_max(lm);
    float ls = 0.f;
    for (int e = start + lane; e < end; e += 64){
      int sn = nbase + srcl[e];
      ls += __expf(lrelu02(asrc[sn] + adh) - m);
    }
    float si = 1.f/(wred_sum(ls) + 1e-16f);
    for (int cs = start; cs < end; cs += 64){
      int cnt = min(64, end - cs);
      bool has = lane < cnt;
      int sn = nbase + (has ? srcl[cs + lane] : 0);
      int offL = sn * bstride;
      float c0 = has ? __expf(lrelu02(asrc[sn] + adh) - m) * si : 0.f;
      for (int j = 0; j < cnt; j++)
        acc_edge(__shfl(offL, j, 64), __shfl(c0, j, 64));
    }
  }

  u16* outp = outp0 + (size_t)node*so;
  {
    int c = 2*lane;
    float r0 = lrelu01(acc0 + bias[c]);
    float r1 = lrelu01(acc1 + bias[c+1]);
    ushort2 st; st.x = f2u(r0); st.y = f2u(r1);
    *(ushort2*)(outp + c) = st;
    if (lane < REMV){
      int cr = MAINC + 2*lane;
      float q0 = lrelu01(accr0 + bias[cr]);
      float q1 = lrelu01(accr1 + bias[cr+1]);
      ushort2 sr; sr.x = f2u(q0); sr.y = f2u(q1);
      *(ushort2*)(outp + cr) = sr;
    }
  }
}

// ---------------- launch ----------------
extern "C" void kernel_launch(void* const* d_in, const int* in_sizes, int n_in,
                              void* d_out, int out_size, void* d_ws, size_t ws_size,
                              hipStream_t stream)
{
  (void)in_sizes; (void)n_in; (void)out_size;
  const float* x    = (const float*)d_in[0];
  const float* wl1  = (const float*)d_in[1];
  const float* gl1  = (const float*)d_in[3];
  const float* bel1 = (const float*)d_in[4];
  const float* wl2  = (const float*)d_in[5];
  const float* gl2  = (const float*)d_in[7];
  const float* bel2 = (const float*)d_in[8];
  const float* wp1  = (const float*)d_in[9];
  const float* gp1  = (const float*)d_in[11];
  const float* bep1 = (const float*)d_in[12];
  const float* wp2  = (const float*)d_in[13];
  const float* gp2  = (const float*)d_in[15];
  const float* bep2 = (const float*)d_in[16];
  const float* wg   = (const float*)d_in[17];
  const float* gg   = (const float*)d_in[19];
  const float* beg  = (const float*)d_in[20];
  const float* W1   = (const float*)d_in[21];
  const float* as1  = (const float*)d_in[22];
  const float* ad1  = (const float*)d_in[23];
  const float* bb1  = (const float*)d_in[24];
  const float* W2   = (const float*)d_in[25];
  const float* as2  = (const float*)d_in[26];
  const float* ad2  = (const float*)d_in[27];
  const float* bb2  = (const float*)d_in[28];
  const float* Wo   = (const float*)d_in[29];
  const float* bo   = (const float*)d_in[30];
  const float* Wo2  = (const float*)d_in[31];
  const float* bo2  = (const float*)d_in[32];
  const int*   ei   = (const int*)d_in[33];

  const size_t STATIC_BYTES = 1200000;
  int nc = 1;
  while (nc < 8 && STATIC_BYTES + (size_t)1880*(NODES/nc) > ws_size) nc <<= 1;
  const int CB = B_/nc, CN = CB*N0_;
  int cbShift = 0; while ((1 << cbShift) < CB) cbShift++;
  const int cbMask = CB - 1;

  char* wsb = (char*)d_ws; size_t off = 0;
  auto alloc = [&](size_t nbytes)->void*{
    void* p = wsb + off; off = (off + nbytes + 255) & ~(size_t)255; return p;
  };
  int*   zbase  = (int*)  alloc(20080*sizeof(int));
  float* gsum   = (float*)zbase;
  float* gsq    = gsum + 40;
  int*   counts = zbase + 80;
  int*   cursor = counts + 10000;
  float* sA     = (float*)alloc(40*sizeof(float));
  float* sB     = (float*)alloc(40*sizeof(float));
  int*   offs   = (int*)  alloc(10001*sizeof(int));
  int*   srcl   = (int*)  alloc((size_t)NE_*sizeof(int));
  u16*   W12T   = (u16*)  alloc((size_t)144*288*2);
  u16*   WoT    = (u16*)  alloc((size_t)144*320*2);
  float* va1s   = (float*)alloc(272*sizeof(float));
  float* va1d   = (float*)alloc(272*sizeof(float));
  float* v2ss   = (float*)alloc(272*sizeof(float));
  float* v2dd   = (float*)alloc(272*sizeof(float));
  float* ccv    = (float*)alloc(2*sizeof(float));
  float* b12    = (float*)alloc(136*sizeof(float));
  u16*   feat   = (u16*)  alloc((size_t)CN*160*2);
  u16*   featL  = (u16*)  alloc((size_t)CN*160*2);
  u16*   aggF   = (u16*)  alloc((size_t)CN*288*2);
  u16*   h2     = (u16*)  alloc((size_t)CN*144*2);
  u16*   g2l    = (u16*)  alloc((size_t)CN*160*2);
  float* asrc1  = (float*)alloc((size_t)CN*2*sizeof(float));
  float* adst1  = (float*)alloc((size_t)CN*2*sizeof(float));
  float* asrc2  = (float*)alloc((size_t)CN*sizeof(float));
  float* adst2  = (float*)alloc((size_t)CN*sizeof(float));

  k_setup<<<425,256,0,stream>>>(zbase, Wo, WoT, W1, W2, W12T,
                                as1, ad1, va1s, va1d, as2, ad2, bb1,
                                v2ss, v2dd, ccv, b12);

  k_bn_stats<<<625,256,0,stream>>>(x, wl1,wl2,wp1,wp2,wg, gsum, gsq);
  k_bn_fin  <<<1,64,0,stream>>>(gsum, gsq, sA, sB, gl1,gl2,gp1,gp2,gg, bel1,bel2,bep1,bep2,beg);

  k_count  <<<665,256,0,stream>>>(ei, counts);
  k_scan   <<<1,1024,0,stream>>>(counts, offs);
  k_scatter<<<665,256,0,stream>>>(ei, offs, cursor, srcl);

  const int gx  = (CN + 255)/256;
  const int gx2 = (CN + 127)/128;
  const int aggB = 2500*CB;
  for (int c = 0; c < nc; c++){
    const int base = c*CN;

    k_feat<<<gx2,256,0,stream>>>(x, wl1,wl2,wp1,wp2,wg, sA, sB, va1s, va1d,
                                 feat, featL, asrc1, adst1, base, CN);

    k_agg1<<<aggB,256,0,stream>>>(feat, asrc1, adst1, offs, srcl, aggF,
                                  v2ss, v2dd, ccv, asrc2, adst2, cbMask, cbShift);

    k_mfma<9,0,9,3,0><<<gx,256,0,stream>>>(aggF,288, (const u16*)0,0, W12T,288, h2,144, 0, b12, CN,
                                           (const float*)0,(const float*)0,(float*)0);

    k_agg2<<<aggB,256,0,stream>>>(h2,144, asrc2, adst2, offs, srcl, bb2, g2l,160,
                                  cbMask, cbShift);

    k_mfma<5,5,9,2,0><<<gx,256,0,stream>>>(g2l,160, featL,160, WoT,320, (u16*)0,0, 0, bo, CN,
                                           Wo2, bo2, (float*)d_out + base);
  }
}

// Round 14
// 486.339 us; speedup vs baseline: 1.8039x; 1.0420x over previous
//
#include <hip/hip_runtime.h>
#include <hip/hip_bf16.h>
#include <math.h>

typedef unsigned short u16;
typedef unsigned int   u32;
typedef short v8s __attribute__((ext_vector_type(8)));
typedef float v4f __attribute__((ext_vector_type(4)));
#define DEV static __device__ __forceinline__

DEV float u2f(u16 u){ union{u32 i; float f;} v; v.i = ((u32)u)<<16; return v.f; }
DEV u16   f2u(float f){ union{float ff; u32 i;} v; v.ff = f; u32 r = v.i + 0x7fffu + ((v.i>>16)&1u); return (u16)(r>>16); }
DEV float lrelu02(float x){ return x > 0.f ? x : 0.2f*x; }
DEV float lrelu01(float x){ return x > 0.f ? x : 0.01f*x; }
DEV float fast_tanh(float x){
  float cx = fminf(fmaxf(x, -15.f), 15.f);
  float e = __expf(2.f*cx);
  return (e - 1.f) * __builtin_amdgcn_rcpf(e + 1.f);
}
DEV float wred_sum(float v){
  #pragma unroll
  for (int o = 32; o > 0; o >>= 1) v += __shfl_xor(v, o, 64);
  return v;
}
DEV float wred_max32(float v){
  #pragma unroll
  for (int o = 16; o > 0; o >>= 1) v = fmaxf(v, __shfl_xor(v, o, 64));
  return v;
}
DEV float wred_sum32(float v){
  #pragma unroll
  for (int o = 16; o > 0; o >>= 1) v += __shfl_xor(v, o, 64);
  return v;
}

constexpr int B_   = 8;
constexpr int P_   = 32;
constexpr int N0_  = 10000;
constexpr int NODES = B_ * N0_;      // 80000
constexpr int E_   = 160000;
constexpr int NE_  = E_ + N0_;       // 170000

// ---------------- merged setup ----------------
__global__ void __launch_bounds__(256) k_setup(int* __restrict__ zbase,
    const float* __restrict__ Wo, u16* __restrict__ WoT,
    const float* __restrict__ W1, const float* __restrict__ W2, u16* __restrict__ W12T,
    const float* __restrict__ as1, const float* __restrict__ ad1,
    float* __restrict__ va1s, float* __restrict__ va1d,
    const float* __restrict__ as2, const float* __restrict__ ad2,
    const float* __restrict__ bb1,
    float* __restrict__ v2ss, float* __restrict__ v2dd,
    float* __restrict__ cc, float* __restrict__ b12)
{
  __shared__ float l2s[272], l2d[272];
  int blk = blockIdx.x, tid = threadIdx.x;
  if (blk < 79){ int i = blk*256 + tid; if (i < 20080) zbase[i] = 0; return; }
  blk -= 79;
  if (blk < 180){           // WoT[n][k] (144x320), head split
    int i = blk*256 + tid; if (i >= 144*320) return;
    int n = i/320, k = i - n*320; float v = 0.f;
    if (n < 136){
      if (k < 136) v = Wo[(size_t)k*136 + n];
      else if (k >= 160 && k < 296) v = Wo[(size_t)(k-24)*136 + n];
    }
    WoT[i] = f2u(v); return;
  }
  blk -= 180;
  if (blk < 162){           // W12T[n][kk] (144x288) = (W1@W2)^T per head-block
    int i = blk*256 + tid; if (i >= 144*288) return;
    int n = i/288, kk = i - n*288; float v = 0.f;
    if (n < 136 && kk < 272){
      int hh = kk/136, k = kk - hh*136;
      for (int c = 0; c < 136; c++)
        v = fmaf(W1[(size_t)k*272 + hh*136 + c], W2[(size_t)(hh*136+c)*136 + n], v);
    }
    W12T[i] = f2u(v); return;
  }
  blk -= 162;
  if (blk < 2){             // va1 = W1 a1 (272)
    int t = blk*256 + tid; if (t >= 272) return;
    int hh = t/136, k = t - hh*136; float s = 0.f, d = 0.f;
    for (int c = 0; c < 136; c++){
      float w = W1[(size_t)k*272 + hh*136 + c];
      s = fmaf(w, as1[hh*136+c], s);
      d = fmaf(w, ad1[hh*136+c], d);
    }
    va1s[t] = s; va1d[t] = d; return;
  }
  blk -= 2;
  {                         // v2'' = W1@(W2 a2); cc = bb1·(W2 a2); b12 = bb1@W2
    for (int m = tid; m < 272; m += 256){
      float vs = 0.f, vd = 0.f;
      for (int n2 = 0; n2 < 136; n2++){
        float w2 = W2[(size_t)m*136 + n2];
        vs = fmaf(w2, as2[n2], vs);
        vd = fmaf(w2, ad2[n2], vd);
      }
      l2s[m] = vs; l2d[m] = vd;
    }
    __syncthreads();
    int t0 = blk*256 + tid;
    if (t0 < 272){
      int hh = t0/136, k = t0 - hh*136; float s = 0.f, d = 0.f;
      for (int c = 0; c < 136; c++){
        float w = W1[(size_t)k*272 + hh*136 + c];
        s = fmaf(w, l2s[hh*136+c], s);
        d = fmaf(w, l2d[hh*136+c], d);
      }
      v2ss[t0] = s; v2dd[t0] = d;
    }
    if (blk == 1){
      if (tid < 64){
        float s = 0.f, d = 0.f;
        for (int m = tid; m < 272; m += 64){
          s = fmaf(bb1[m], l2s[m], s);
          d = fmaf(bb1[m], l2d[m], d);
        }
        s = wred_sum(s); d = wred_sum(d);
        if (tid == 0){ cc[0] = s; cc[1] = d; }
      } else if (tid < 200){
        int n2 = tid - 64; float v = 0.f;
        for (int m = 0; m < 272; m++) v = fmaf(bb1[m], W2[(size_t)m*136 + n2], v);
        b12[n2] = v;
      }
    }
  }
}

// ---------------- backbone ----------------
DEV void load_convw(float* lw, const float* wl1, const float* wl2, const float* wp1,
                    const float* wp2, const float* wg, int tid, int nth){
  for (int i = tid; i < 384; i += nth){
    float v;
    if      (i < 24)  v = wl1[i];
    else if (i < 64)  v = wl2[i-24];
    else if (i < 88)  v = wp1[i-64];
    else if (i < 128) v = wp2[i-88];
    else              v = wg [i-128];
    lw[i] = v;
  }
}

template<int KS,int DIL,int T>
DEV void conv_stats(const float* xc, const float* wk, float& s, float& q){
  #pragma unroll
  for (int t = 0; t < T; t++){
    float v = 0.f;
    #pragma unroll
    for (int j = 0; j < KS; j++) v = fmaf(wk[j], xc[t + j*DIL], v);
    s += v; q = fmaf(v, v, q);
  }
}

__global__ void __launch_bounds__(256) k_bn_stats(
    const float* __restrict__ x,
    const float* __restrict__ wl1, const float* __restrict__ wl2,
    const float* __restrict__ wp1, const float* __restrict__ wp2,
    const float* __restrict__ wg,
    float* __restrict__ gsum, float* __restrict__ gsq)
{
  __shared__ float lw[384];
  __shared__ float lacc[80];
  const int tid = threadIdx.x;
  load_convw(lw, wl1, wl2, wp1, wp2, wg, tid, 256);
  if (tid < 80) lacc[tid] = 0.f;
  __syncthreads();

  const int lane = tid & 63, wv = tid >> 6;
  const int nodeLocal = (wv >> 1)*64 + lane;
  const int half = wv & 1;
  const int gid = blockIdx.x*128 + nodeLocal;
  float xc[P_];
  if (gid < NODES){
    int b = gid / N0_, n = gid - b*N0_;
    const float* xp = x + (size_t)b*P_*N0_ + n;
    #pragma unroll
    for (int p = 0; p < P_; p++) xc[p] = xp[(size_t)p*N0_];
  } else {
    #pragma unroll
    for (int p = 0; p < P_; p++) xc[p] = 0.f;
  }

  auto red = [&](int ch, float s, float q){
    #pragma unroll
    for (int o = 32; o > 0; o >>= 1){ s += __shfl_down(s,o,64); q += __shfl_down(q,o,64); }
    if (lane == 0){ atomicAdd(&lacc[ch], s); atomicAdd(&lacc[40+ch], q); }
  };

  if (half == 0){
    #pragma unroll
    for (int k = 0; k < 8; k++){ float s=0,q=0; conv_stats<3,1,30>(xc, lw      + k*3 , s,q); red(k,     s,q); }
    #pragma unroll
    for (int k = 0; k < 8; k++){ float s=0,q=0; conv_stats<5,1,28>(xc, lw + 24 + k*5 , s,q); red(8+k,   s,q); }
  } else {
    #pragma unroll
    for (int k = 0; k < 8; k++){ float s=0,q=0; conv_stats<3,2,28>(xc, lw + 64 + k*3 , s,q); red(16+k,  s,q); }
    #pragma unroll
    for (int k = 0; k < 8; k++){ float s=0,q=0; conv_stats<5,2,24>(xc, lw + 88 + k*5 , s,q); red(24+k,  s,q); }
    #pragma unroll
    for (int k = 0; k < 8; k++){ float s=0,q=0; conv_stats<32,1,1>(xc, lw + 128+ k*32, s,q); red(32+k,  s,q); }
  }

  __syncthreads();
  if (tid < 40)      atomicAdd(&gsum[tid],    lacc[tid]);
  else if (tid < 80) atomicAdd(&gsq [tid-40], lacc[tid]);
}

// count kernel with bn_fin folded in as the last block
__global__ void k_count(const int* __restrict__ ei, int* __restrict__ counts,
                        const float* __restrict__ gsum, const float* __restrict__ gsq,
                        float* __restrict__ sA, float* __restrict__ sB,
                        const float* g0, const float* g1, const float* g2, const float* g3, const float* g4,
                        const float* e0, const float* e1, const float* e2, const float* e3, const float* e4){
  if (blockIdx.x == 665){
    int t = threadIdx.x;
    if (t >= 40) return;
    int bi = t >> 3, k = t & 7;
    const int Ts[5] = {30,28,28,24,1};
    float cnt  = (float)NODES * (float)Ts[bi];
    float mean = gsum[t] / cnt;
    float var  = gsq[t] / cnt - mean*mean;
    const float* gp = bi==0?g0: bi==1?g1: bi==2?g2: bi==3?g3: g4;
    const float* ep = bi==0?e0: bi==1?e1: bi==2?e2: bi==3?e3: e4;
    float a = gp[k] * rsqrtf(fmaxf(var, 0.f) + 1e-5f);
    sA[t] = a;
    sB[t] = ep[k] - a*mean;
    return;
  }
  int e = blockIdx.x*blockDim.x + threadIdx.x;
  if (e >= NE_) return;
  int dst = (e < E_) ? ei[E_ + e] : (e - E_);
  atomicAdd(&counts[dst], 1);
}

__global__ void __launch_bounds__(1024) k_scan(const int* __restrict__ counts, int* __restrict__ offs){
  __shared__ int part[1024];
  int t = threadIdx.x;
  int loc[10]; int s = 0;
  #pragma unroll
  for (int i = 0; i < 10; i++){
    int idx = t*10 + i;
    int c = (idx < N0_) ? counts[idx] : 0;
    loc[i] = s; s += c;
  }
  part[t] = s;
  __syncthreads();
  for (int o = 1; o < 1024; o <<= 1){
    int v = (t >= o) ? part[t-o] : 0;
    __syncthreads();
    part[t] += v;
    __syncthreads();
  }
  int pre = (t == 0) ? 0 : part[t-1];
  #pragma unroll
  for (int i = 0; i < 10; i++){
    int idx = t*10 + i;
    if (idx < N0_) offs[idx] = pre + loc[i];
  }
  if (t == 0) offs[N0_] = part[1023];
}

// degree-sorted permutation (counting sort by degree, one block)
__global__ void __launch_bounds__(1024) k_perm(const int* __restrict__ counts, int* __restrict__ perm){
  __shared__ int hist[129];
  __shared__ int base[129];
  int t = threadIdx.x;
  if (t < 129) hist[t] = 0;
  __syncthreads();
  int dloc[10];
  #pragma unroll
  for (int i = 0; i < 10; i++){
    int idx = t*10 + i;
    if (idx < N0_){
      int d = min(counts[idx], 128);
      dloc[i] = d;
      atomicAdd(&hist[d], 1);
    }
  }
  __syncthreads();
  if (t == 0){
    int s = 0;
    for (int b = 0; b <= 128; b++){ base[b] = s; s += hist[b]; }
  }
  __syncthreads();
  #pragma unroll
  for (int i = 0; i < 10; i++){
    int idx = t*10 + i;
    if (idx < N0_){
      int pos = atomicAdd(&base[dloc[i]], 1);
      perm[pos] = idx;
    }
  }
}

__global__ void k_scatter(const int* __restrict__ ei, const int* __restrict__ offs,
                          int* __restrict__ cursor, int* __restrict__ srcl){
  int e = blockIdx.x*blockDim.x + threadIdx.x;
  if (e >= NE_) return;
  int src, dst;
  if (e < E_){ src = ei[e]; dst = ei[E_ + e]; } else { src = dst = e - E_; }
  int pos = atomicAdd(&cursor[dst], 1);
  srcl[offs[dst] + pos] = src;
}

template<int KS,int DIL,int T>
DEV void conv_pool4(const float* xc, const float* wk, float A, float Bc, float* o4){
  float y[T];
  #pragma unroll
  for (int t = 0; t < T; t++){
    float v = 0.f;
    #pragma unroll
    for (int j = 0; j < KS; j++) v = fmaf(wk[j], xc[t + j*DIL], v);
    y[t] = fmaf(A, v, Bc);
  }
  #pragma unroll
  for (int i = 0; i < 4; i++){
    const int lo = (i*T)/4, hi = ((i+1)*T + 3)/4;
    float m = y[lo];
    #pragma unroll
    for (int t = 0; t < T; t++){ if (t > lo && t < hi) m = fmaxf(m, y[t]); }
    o4[i] = m;
  }
}

// feat [m][160] bf16 (tanh) + featL (lrelu01) + fused layer-1 attention dots (float4 LDS)
__global__ void __launch_bounds__(256) k_feat(
    const float* __restrict__ x,
    const float* __restrict__ wl1, const float* __restrict__ wl2,
    const float* __restrict__ wp1, const float* __restrict__ wp2,
    const float* __restrict__ wg,
    const float* __restrict__ sA, const float* __restrict__ sB,
    const float* __restrict__ va1s, const float* __restrict__ va1d,
    u16* __restrict__ feat, u16* __restrict__ featL,
    float* __restrict__ asrc1, float* __restrict__ adst1,
    int base, int m)
{
  __shared__ float lw[384];
  __shared__ float lA[40], lB[40];
  __shared__ float4 lv4[136];
  __shared__ float sdt[128][4];
  const int tid = threadIdx.x;
  load_convw(lw, wl1, wl2, wp1, wp2, wg, tid, 256);
  if (tid < 40){ lA[tid] = sA[tid]; lB[tid] = sB[tid]; }
  for (int i = tid; i < 136; i += 256)
    lv4[i] = make_float4(va1s[i], va1d[i], va1s[136+i], va1d[136+i]);
  __syncthreads();

  const int lane = tid & 63, wv = tid >> 6;
  const int nodeLocal = (wv >> 1)*64 + lane;     // 0..127
  const int half = wv & 1;                       // wave-uniform
  const int nodeIdx = blockIdx.x*128 + nodeLocal;
  const bool act = nodeIdx < m;
  const int gcl = base + (act ? nodeIdx : (m-1));
  int b = gcl / N0_, n = gcl - b*N0_;
  float xc[P_];
  const float* xp = x + (size_t)b*P_*N0_ + n;
  #pragma unroll
  for (int p = 0; p < P_; p++) xc[p] = xp[(size_t)p*N0_];

  float dt[4] = {0.f,0.f,0.f,0.f};
  u32 pk[4], pkl[4];
  u16* orow  = feat  + (size_t)nodeIdx*160;
  u16* olrow = featL + (size_t)nodeIdx*160;
  auto emit = [&](int ch, float v){
    float t = fast_tanh(v);
    float4 vv = lv4[ch];
    dt[0] = fmaf(t, vv.x, dt[0]);
    dt[1] = fmaf(t, vv.y, dt[1]);
    dt[2] = fmaf(t, vv.z, dt[2]);
    dt[3] = fmaf(t, vv.w, dt[3]);
    u16 h  = f2u(t);
    u16 hl = f2u(lrelu01(t));
    int s = ch & 7;
    if ((s & 1) == 0){ pk[s>>1] = h;                pkl[s>>1] = hl; }
    else             { pk[s>>1] |= ((u32)h) << 16;  pkl[s>>1] |= ((u32)hl) << 16; }
    if (s == 7 && act){
      *(uint4*)(orow  + (ch - 7)) = make_uint4(pk[0],pk[1],pk[2],pk[3]);
      *(uint4*)(olrow + (ch - 7)) = make_uint4(pkl[0],pkl[1],pkl[2],pkl[3]);
    }
  };

  float o4[4];
  if (half == 0){
    #pragma unroll
    for (int k = 0; k < 8; k++){
      conv_pool4<3,1,30>(xc, lw + k*3, lA[k], lB[k], o4);
      #pragma unroll
      for (int i = 0; i < 4; i++) emit(k*4+i, o4[i]);
    }
    #pragma unroll
    for (int k = 0; k < 8; k++){
      conv_pool4<5,1,28>(xc, lw + 24 + k*5, lA[8+k], lB[8+k], o4);
      #pragma unroll
      for (int i = 0; i < 4; i++) emit(32 + k*4+i, o4[i]);
    }
  } else {
    #pragma unroll
    for (int k = 0; k < 8; k++){
      conv_pool4<3,2,28>(xc, lw + 64 + k*3, lA[16+k], lB[16+k], o4);
      #pragma unroll
      for (int i = 0; i < 4; i++) emit(64 + k*4+i, o4[i]);
    }
    #pragma unroll
    for (int k = 0; k < 8; k++){
      conv_pool4<5,2,24>(xc, lw + 88 + k*5, lA[24+k], lB[24+k], o4);
      #pragma unroll
      for (int i = 0; i < 4; i++) emit(96 + k*4+i, o4[i]);
    }
    #pragma unroll
    for (int k = 0; k < 8; k++){
      float v = 0.f;
      #pragma unroll
      for (int j = 0; j < 32; j++) v = fmaf(lw[128 + k*32 + j], xc[j], v);
      emit(128 + k, fmaf(lA[32+k], v, lB[32+k]));
    }
  }

  if (half == 1){
    sdt[nodeLocal][0] = dt[0]; sdt[nodeLocal][1] = dt[1];
    sdt[nodeLocal][2] = dt[2]; sdt[nodeLocal][3] = dt[3];
  }
  __syncthreads();
  if (half == 0 && act){
    asrc1[(size_t)nodeIdx*2]   = dt[0] + sdt[nodeLocal][0];
    asrc1[(size_t)nodeIdx*2+1] = dt[2] + sdt[nodeLocal][2];
    adst1[(size_t)nodeIdx*2]   = dt[1] + sdt[nodeLocal][1];
    adst1[(size_t)nodeIdx*2+1] = dt[3] + sdt[nodeLocal][3];
  }
}

// ---------------- MFMA GEMM ----------------
template<int KT1,int KT2,int NT,int EPI,int LR2>
__global__ void __launch_bounds__(256) k_mfma(
    const u16* __restrict__ A1, int sA1,
    const u16* __restrict__ A2, int sA2,
    const u16* __restrict__ BT, int sBT,
    u16* __restrict__ C, int sC, int nbase,
    const float* __restrict__ bias, int m,
    const float* __restrict__ w2v, const float* __restrict__ bo2p, float* __restrict__ fout)
{
  const int wv = threadIdx.x >> 6, lane = threadIdx.x & 63;
  const int quad = lane >> 4, l15 = lane & 15;
  const int mb = blockIdx.x*256 + wv*64;
  int ar[4];
  #pragma unroll
  for (int mt = 0; mt < 4; mt++) ar[mt] = min(mb + mt*16 + l15, m-1);

  v4f acc[4][NT];
  #pragma unroll
  for (int mt = 0; mt < 4; mt++)
    #pragma unroll
    for (int nt = 0; nt < NT; nt++)
      acc[mt][nt] = (v4f){0.f,0.f,0.f,0.f};

  for (int kt = 0; kt < KT1+KT2; kt++){
    const u16* ab; int sA, koff;
    if (KT2 == 0 || kt < KT1){ ab = A1; sA = sA1; koff = kt*32; }
    else { ab = A2; sA = sA2; koff = (kt-KT1)*32; }
    v8s a[4];
    #pragma unroll
    for (int mt = 0; mt < 4; mt++)
      a[mt] = *(const v8s*)(ab + (size_t)ar[mt]*sA + koff + quad*8);
    if (KT2 > 0 && LR2 && kt >= KT1){
      #pragma unroll
      for (int mt = 0; mt < 4; mt++)
        #pragma unroll
        for (int j = 0; j < 8; j++){
          float f = u2f((u16)a[mt][j]);
          f = f > 0.f ? f : 0.01f*f;
          a[mt][j] = (short)f2u(f);
        }
    }
    const int kb = kt*32 + quad*8;
    #pragma unroll
    for (int nt = 0; nt < NT; nt++){
      v8s b = *(const v8s*)(BT + (size_t)(nbase + nt*16 + l15)*sBT + kb);
      #pragma unroll
      for (int mt = 0; mt < 4; mt++)
        acc[mt][nt] = __builtin_amdgcn_mfma_f32_16x16x32_bf16(a[mt], b, acc[mt][nt], 0, 0, 0);
    }
  }

  if (EPI == 2){
    const float bo2v = bo2p[0];
    #pragma unroll
    for (int mt = 0; mt < 4; mt++){
      float part[4] = {0.f,0.f,0.f,0.f};
      #pragma unroll
      for (int nt = 0; nt < NT; nt++){
        const int col = nt*16 + l15;
        float wv2 = (col < 136) ? w2v[col] : 0.f;
        float bv  = bias[min(col,135)];
        #pragma unroll
        for (int i = 0; i < 4; i++){
          float xv = lrelu01(acc[mt][nt][i] + bv);
          part[i] = fmaf(xv, wv2, part[i]);
        }
      }
      #pragma unroll
      for (int i = 0; i < 4; i++){
        float v = part[i];
        v += __shfl_xor(v, 1, 64);
        v += __shfl_xor(v, 2, 64);
        v += __shfl_xor(v, 4, 64);
        v += __shfl_xor(v, 8, 64);
        int r = mb + mt*16 + quad*4 + i;
        if (l15 == 0 && r < m) fout[r] = v + bo2v;
      }
    }
    return;
  }

  #pragma unroll
  for (int mt = 0; mt < 4; mt++){
    const int r0 = mb + mt*16 + quad*4;
    #pragma unroll
    for (int nt = 0; nt < NT; nt++){
      const int col = nbase + nt*16 + l15;
      #pragma unroll
      for (int i = 0; i < 4; i++){
        int r = r0 + i;
        if (r < m){
          float xv = acc[mt][nt][i];
          if (EPI == 1){ xv += bias[min(col,135)]; xv = lrelu01(xv); }
          if (EPI == 3){ xv += bias[min(col,135)]; }
          C[(size_t)r*sC + col] = f2u(xv);
        }
      }
    }
  }
}

// ---------------- layer-1 GAT aggregation: two degree-paired dst per wave ----------------
__global__ void __launch_bounds__(256) k_agg1(const u16* __restrict__ feat,
    const float* __restrict__ asrc, const float* __restrict__ adst,
    const int* __restrict__ offs, const int* __restrict__ srcl,
    const int* __restrict__ perm,
    u16* __restrict__ aggF,
    const float* __restrict__ v2s, const float* __restrict__ v2d,
    const float* __restrict__ cc,
    float* __restrict__ as_out, float* __restrict__ ad_out,
    int cbMask, int cbShift)
{
  const int tid = threadIdx.x;
  const int wv = tid >> 6, lane = tid & 63;
  const int half = lane >> 5, l32 = lane & 31;
  const int hbase = lane & 32;
  const int id = blockIdx.x;
  const int bb = id & cbMask;
  const int q = (id >> cbShift)*4 + wv;       // pair index
  const int dst = perm[2*q + half];
  const int nbase = bb*N0_;
  const int node = nbase + dst;
  const int start = offs[dst], end = offs[dst+1];
  const int ne = end - start;

  const float ad0 = adst[(size_t)node*2], ad1v = adst[(size_t)node*2+1];
  const char* featB = (const char*)feat;

  float m0h0=0,m1h0=0,m2h0=0,m3h0=0;
  float m0h1=0,m1h1=0,m2h1=0,m3h1=0;
  float r0h0=0,r1h0=0,r0h1=0,r1h1=0;

  auto acc_edge = [&](int off, float c0, float c1){
    const u16* fp = (const u16*)(featB + off);
    const ushort4 hv = *(const ushort4*)(fp + 4*l32);
    float f0=u2f(hv.x), f1=u2f(hv.y), f2=u2f(hv.z), f3=u2f(hv.w);
    m0h0=fmaf(c0,f0,m0h0); m1h0=fmaf(c0,f1,m1h0); m2h0=fmaf(c0,f2,m2h0); m3h0=fmaf(c0,f3,m3h0);
    m0h1=fmaf(c1,f0,m0h1); m1h1=fmaf(c1,f1,m1h1); m2h1=fmaf(c1,f2,m2h1); m3h1=fmaf(c1,f3,m3h1);
    if (l32 < 4){
      const ushort2 hr = *(const ushort2*)(fp + 128 + 2*l32);
      float g0=u2f(hr.x), g1=u2f(hr.y);
      r0h0=fmaf(c0,g0,r0h0); r1h0=fmaf(c0,g1,r1h0);
      r0h1=fmaf(c1,g0,r0h1); r1h1=fmaf(c1,g1,r1h1);
    }
  };
  auto acc_edge2 = [&](int o0, int o1, float a0, float a1, float b0, float b1){
    const u16* p0 = (const u16*)(featB + o0);
    const u16* p1 = (const u16*)(featB + o1);
    const ushort4 v0 = *(const ushort4*)(p0 + 4*l32);
    const ushort4 v1 = *(const ushort4*)(p1 + 4*l32);
    ushort2 q0, q1;
    if (l32 < 4){
      q0 = *(const ushort2*)(p0 + 128 + 2*l32);
      q1 = *(const ushort2*)(p1 + 128 + 2*l32);
    }
    float f;
    f=u2f(v0.x); m0h0=fmaf(a0,f,m0h0); m0h1=fmaf(b0,f,m0h1);
    f=u2f(v0.y); m1h0=fmaf(a0,f,m1h0); m1h1=fmaf(b0,f,m1h1);
    f=u2f(v0.z); m2h0=fmaf(a0,f,m2h0); m2h1=fmaf(b0,f,m2h1);
    f=u2f(v0.w); m3h0=fmaf(a0,f,m3h0); m3h1=fmaf(b0,f,m3h1);
    f=u2f(v1.x); m0h0=fmaf(a1,f,m0h0); m0h1=fmaf(b1,f,m0h1);
    f=u2f(v1.y); m1h0=fmaf(a1,f,m1h0); m1h1=fmaf(b1,f,m1h1);
    f=u2f(v1.z); m2h0=fmaf(a1,f,m2h0); m2h1=fmaf(b1,f,m2h1);
    f=u2f(v1.w); m3h0=fmaf(a1,f,m3h0); m3h1=fmaf(b1,f,m3h1);
    if (l32 < 4){
      f=u2f(q0.x); r0h0=fmaf(a0,f,r0h0); r0h1=fmaf(b0,f,r0h1);
      f=u2f(q0.y); r1h0=fmaf(a0,f,r1h0); r1h1=fmaf(b0,f,r1h1);
      f=u2f(q1.x); r0h0=fmaf(a1,f,r0h0); r0h1=fmaf(b1,f,r0h1);
      f=u2f(q1.y); r1h0=fmaf(a1,f,r1h0); r1h1=fmaf(b1,f,r1h1);
    }
  };

  if (ne <= 32){
    const bool has = l32 < ne;
    const int sn = nbase + (has ? srcl[start + l32] : 0);
    const int offL = sn * 320;
    float al0 = has ? lrelu02(asrc[(size_t)sn*2]   + ad0)  : -1e30f;
    float al1 = has ? lrelu02(asrc[(size_t)sn*2+1] + ad1v) : -1e30f;
    float mm = wred_max32(al0);
    float p0 = has ? __expf(al0 - mm) : 0.f;
    float c0 = p0 * (1.f/(wred_sum32(p0) + 1e-16f));
    mm = wred_max32(al1);
    float p1 = has ? __expf(al1 - mm) : 0.f;
    float c1 = p1 * (1.f/(wred_sum32(p1) + 1e-16f));
    int j = 0;
    for (; j + 1 < ne; j += 2){
      int   o0 = __shfl(offL, hbase + j, 64), o1 = __shfl(offL, hbase + j + 1, 64);
      float a0 = __shfl(c0, hbase + j, 64),   a1 = __shfl(c0, hbase + j + 1, 64);
      float b0 = __shfl(c1, hbase + j, 64),   b1 = __shfl(c1, hbase + j + 1, 64);
      acc_edge2(o0, o1, a0, a1, b0, b1);
    }
    if (j < ne)
      acc_edge(__shfl(offL, hbase + j, 64), __shfl(c0, hbase + j, 64), __shfl(c1, hbase + j, 64));
  } else {
    float lm0 = -1e30f, lm1 = -1e30f;
    for (int e = start + l32; e < end; e += 32){
      int sn = nbase + srcl[e];
      lm0 = fmaxf(lm0, lrelu02(asrc[(size_t)sn*2]   + ad0));
      lm1 = fmaxf(lm1, lrelu02(asrc[(size_t)sn*2+1] + ad1v));
    }
    float m0 = wred_max32(lm0), m1 = wred_max32(lm1);
    float ls0 = 0.f, ls1 = 0.f;
    for (int e = start + l32; e < end; e += 32){
      int sn = nbase + srcl[e];
      ls0 += __expf(lrelu02(asrc[(size_t)sn*2]   + ad0)  - m0);
      ls1 += __expf(lrelu02(asrc[(size_t)sn*2+1] + ad1v) - m1);
    }
    float si0 = 1.f/(wred_sum32(ls0) + 1e-16f);
    float si1 = 1.f/(wred_sum32(ls1) + 1e-16f);
    for (int cs = start; cs < end; cs += 32){
      int cnt = min(32, end - cs);
      bool has = l32 < cnt;
      int sn = nbase + (has ? srcl[cs + l32] : 0);
      int offL = sn * 320;
      float c0 = 0.f, c1 = 0.f;
      if (has){
        c0 = __expf(lrelu02(asrc[(size_t)sn*2]   + ad0)  - m0) * si0;
        c1 = __expf(lrelu02(asrc[(size_t)sn*2+1] + ad1v) - m1) * si1;
      }
      for (int j = 0; j < cnt; j++)
        acc_edge(__shfl(offL, hbase + j, 64), __shfl(c0, hbase + j, 64), __shfl(c1, hbase + j, 64));
    }
  }

  u16* outp = aggF + (size_t)node*288;
  {
    ushort4 s0; s0.x=f2u(m0h0); s0.y=f2u(m1h0); s0.z=f2u(m2h0); s0.w=f2u(m3h0);
    *(ushort4*)(outp + 4*l32) = s0;
    ushort4 s1; s1.x=f2u(m0h1); s1.y=f2u(m1h1); s1.z=f2u(m2h1); s1.w=f2u(m3h1);
    *(ushort4*)(outp + 136 + 4*l32) = s1;
    if (l32 < 4){
      ushort2 t0; t0.x=f2u(r0h0); t0.y=f2u(r1h0);
      *(ushort2*)(outp + 128 + 2*l32) = t0;
      ushort2 t1; t1.x=f2u(r0h1); t1.y=f2u(r1h1);
      *(ushort2*)(outp + 136 + 128 + 2*l32) = t1;
    }
  }
  {
    int c = 4*l32;
    float s = m0h0*v2s[c] + m1h0*v2s[c+1] + m2h0*v2s[c+2] + m3h0*v2s[c+3]
            + m0h1*v2s[136+c] + m1h1*v2s[136+c+1] + m2h1*v2s[136+c+2] + m3h1*v2s[136+c+3];
    float d = m0h0*v2d[c] + m1h0*v2d[c+1] + m2h0*v2d[c+2] + m3h0*v2d[c+3]
            + m0h1*v2d[136+c] + m1h1*v2d[136+c+1] + m2h1*v2d[136+c+2] + m3h1*v2d[136+c+3];
    if (l32 < 4){
      int cr = 128 + 2*l32;
      s += r0h0*v2s[cr] + r1h0*v2s[cr+1] + r0h1*v2s[136+cr] + r1h1*v2s[136+cr+1];
      d += r0h0*v2d[cr] + r1h0*v2d[cr+1] + r0h1*v2d[136+cr] + r1h1*v2d[136+cr+1];
    }
    s = wred_sum32(s); d = wred_sum32(d);
    if (l32 == 0){ as_out[node] = s + cc[0]; ad_out[node] = d + cc[1]; }
  }
}

// ---------------- layer-2 GAT aggregation (H=1): two degree-paired dst per wave ----------------
__global__ void __launch_bounds__(256) k_agg2(const u16* __restrict__ h, int sh,
    const float* __restrict__ asrc, const float* __restrict__ adst,
    const int* __restrict__ offs, const int* __restrict__ srcl,
    const int* __restrict__ perm,
    const float* __restrict__ bias, u16* __restrict__ outp0, int so,
    int cbMask, int cbShift)
{
  const int tid = threadIdx.x;
  const int wv = tid >> 6, lane = tid & 63;
  const int half = lane >> 5, l32 = lane & 31;
  const int hbase = lane & 32;
  const int id = blockIdx.x;
  const int bb = id & cbMask;
  const int q = (id >> cbShift)*4 + wv;
  const int dst = perm[2*q + half];
  const int nbase = bb*N0_;
  const int node = nbase + dst;
  const int start = offs[dst], end = offs[dst+1];
  const int ne = end - start;
  const int bstride = 2*sh;

  const float adh = adst[node];
  const char* hB = (const char*)h;

  float a0=0, a1=0, a2=0, a3=0, rr0=0, rr1=0;

  auto acc_edge = [&](int off, float c0){
    const u16* hp = (const u16*)(hB + off);
    const ushort4 hv = *(const ushort4*)(hp + 4*l32);
    a0 = fmaf(c0, u2f(hv.x), a0); a1 = fmaf(c0, u2f(hv.y), a1);
    a2 = fmaf(c0, u2f(hv.z), a2); a3 = fmaf(c0, u2f(hv.w), a3);
    if (l32 < 4){
      const ushort2 hr = *(const ushort2*)(hp + 128 + 2*l32);
      rr0 = fmaf(c0, u2f(hr.x), rr0);
      rr1 = fmaf(c0, u2f(hr.y), rr1);
    }
  };
  auto acc_edge2 = [&](int o0, int o1, float c0, float c1){
    const u16* p0 = (const u16*)(hB + o0);
    const u16* p1 = (const u16*)(hB + o1);
    const ushort4 v0 = *(const ushort4*)(p0 + 4*l32);
    const ushort4 v1 = *(const ushort4*)(p1 + 4*l32);
    ushort2 q0, q1;
    if (l32 < 4){
      q0 = *(const ushort2*)(p0 + 128 + 2*l32);
      q1 = *(const ushort2*)(p1 + 128 + 2*l32);
    }
    a0 = fmaf(c0, u2f(v0.x), a0); a1 = fmaf(c0, u2f(v0.y), a1);
    a2 = fmaf(c0, u2f(v0.z), a2); a3 = fmaf(c0, u2f(v0.w), a3);
    a0 = fmaf(c1, u2f(v1.x), a0); a1 = fmaf(c1, u2f(v1.y), a1);
    a2 = fmaf(c1, u2f(v1.z), a2); a3 = fmaf(c1, u2f(v1.w), a3);
    if (l32 < 4){
      rr0 = fmaf(c0, u2f(q0.x), rr0); rr1 = fmaf(c0, u2f(q0.y), rr1);
      rr0 = fmaf(c1, u2f(q1.x), rr0); rr1 = fmaf(c1, u2f(q1.y), rr1);
    }
  };

  if (ne <= 32){
    const bool has = l32 < ne;
    const int sn = nbase + (has ? srcl[start + l32] : 0);
    const int offL = sn * bstride;
    float al = has ? lrelu02(asrc[sn] + adh) : -1e30f;
    float m = wred_max32(al);
    float p = has ? __expf(al - m) : 0.f;
    float c0 = p * (1.f/(wred_sum32(p) + 1e-16f));
    int j = 0;
    for (; j + 1 < ne; j += 2){
      int   o0 = __shfl(offL, hbase + j, 64), o1 = __shfl(offL, hbase + j + 1, 64);
      float e0 = __shfl(c0, hbase + j, 64),   e1 = __shfl(c0, hbase + j + 1, 64);
      acc_edge2(o0, o1, e0, e1);
    }
    if (j < ne)
      acc_edge(__shfl(offL, hbase + j, 64), __shfl(c0, hbase + j, 64));
  } else {
    float lm = -1e30f;
    for (int e = start + l32; e < end; e += 32){
      int sn = nbase + srcl[e];
      lm = fmaxf(lm, lrelu02(asrc[sn] + adh));
    }
    float m = wred_max32(lm);
    float ls = 0.f;
    for (int e = start + l32; e < end; e += 32){
      int sn = nbase + srcl[e];
      ls += __expf(lrelu02(asrc[sn] + adh) - m);
    }
    float si = 1.f/(wred_sum32(ls) + 1e-16f);
    for (int cs = start; cs < end; cs += 32){
      int cnt = min(32, end - cs);
      bool has = l32 < cnt;
      int sn = nbase + (has ? srcl[cs + l32] : 0);
      int offL = sn * bstride;
      float c0 = has ? __expf(lrelu02(asrc[sn] + adh) - m) * si : 0.f;
      for (int j = 0; j < cnt; j++)
        acc_edge(__shfl(offL, hbase + j, 64), __shfl(c0, hbase + j, 64));
    }
  }

  u16* outp = outp0 + (size_t)node*so;
  {
    int c = 4*l32;
    ushort4 st;
    st.x = f2u(lrelu01(a0 + bias[c]));
    st.y = f2u(lrelu01(a1 + bias[c+1]));
    st.z = f2u(lrelu01(a2 + bias[c+2]));
    st.w = f2u(lrelu01(a3 + bias[c+3]));
    *(ushort4*)(outp + c) = st;
    if (l32 < 4){
      int cr = 128 + 2*l32;
      ushort2 sr;
      sr.x = f2u(lrelu01(rr0 + bias[cr]));
      sr.y = f2u(lrelu01(rr1 + bias[cr+1]));
      *(ushort2*)(outp + cr) = sr;
    }
  }
}

// ---------------- launch ----------------
extern "C" void kernel_launch(void* const* d_in, const int* in_sizes, int n_in,
                              void* d_out, int out_size, void* d_ws, size_t ws_size,
                              hipStream_t stream)
{
  (void)in_sizes; (void)n_in; (void)out_size;
  const float* x    = (const float*)d_in[0];
  const float* wl1  = (const float*)d_in[1];
  const float* gl1  = (const float*)d_in[3];
  const float* bel1 = (const float*)d_in[4];
  const float* wl2  = (const float*)d_in[5];
  const float* gl2  = (const float*)d_in[7];
  const float* bel2 = (const float*)d_in[8];
  const float* wp1  = (const float*)d_in[9];
  const float* gp1  = (const float*)d_in[11];
  const float* bep1 = (const float*)d_in[12];
  const float* wp2  = (const float*)d_in[13];
  const float* gp2  = (const float*)d_in[15];
  const float* bep2 = (const float*)d_in[16];
  const float* wg   = (const float*)d_in[17];
  const float* gg   = (const float*)d_in[19];
  const float* beg  = (const float*)d_in[20];
  const float* W1   = (const float*)d_in[21];
  const float* as1  = (const float*)d_in[22];
  const float* ad1  = (const float*)d_in[23];
  const float* bb1  = (const float*)d_in[24];
  const float* W2   = (const float*)d_in[25];
  const float* as2  = (const float*)d_in[26];
  const float* ad2  = (const float*)d_in[27];
  const float* bb2  = (const float*)d_in[28];
  const float* Wo   = (const float*)d_in[29];
  const float* bo   = (const float*)d_in[30];
  const float* Wo2  = (const float*)d_in[31];
  const float* bo2  = (const float*)d_in[32];
  const int*   ei   = (const int*)d_in[33];

  const size_t STATIC_BYTES = 1250000;
  int nc = 1;
  while (nc < 8 && STATIC_BYTES + (size_t)1880*(NODES/nc) > ws_size) nc <<= 1;
  const int CB = B_/nc, CN = CB*N0_;
  int cbShift = 0; while ((1 << cbShift) < CB) cbShift++;
  const int cbMask = CB - 1;

  char* wsb = (char*)d_ws; size_t off = 0;
  auto alloc = [&](size_t nbytes)->void*{
    void* p = wsb + off; off = (off + nbytes + 255) & ~(size_t)255; return p;
  };
  int*   zbase  = (int*)  alloc(20080*sizeof(int));
  float* gsum   = (float*)zbase;
  float* gsq    = gsum + 40;
  int*   counts = zbase + 80;
  int*   cursor = counts + 10000;
  float* sA     = (float*)alloc(40*sizeof(float));
  float* sB     = (float*)alloc(40*sizeof(float));
  int*   offs   = (int*)  alloc(10001*sizeof(int));
  int*   srcl   = (int*)  alloc((size_t)NE_*sizeof(int));
  int*   perm   = (int*)  alloc((size_t)N0_*sizeof(int));
  u16*   W12T   = (u16*)  alloc((size_t)144*288*2);
  u16*   WoT    = (u16*)  alloc((size_t)144*320*2);
  float* va1s   = (float*)alloc(272*sizeof(float));
  float* va1d   = (float*)alloc(272*sizeof(float));
  float* v2ss   = (float*)alloc(272*sizeof(float));
  float* v2dd   = (float*)alloc(272*sizeof(float));
  float* ccv    = (float*)alloc(2*sizeof(float));
  float* b12    = (float*)alloc(136*sizeof(float));
  u16*   feat   = (u16*)  alloc((size_t)CN*160*2);
  u16*   featL  = (u16*)  alloc((size_t)CN*160*2);
  u16*   aggF   = (u16*)  alloc((size_t)CN*288*2);
  u16*   h2     = (u16*)  alloc((size_t)CN*144*2);
  u16*   g2l    = (u16*)  alloc((size_t)CN*160*2);
  float* asrc1  = (float*)alloc((size_t)CN*2*sizeof(float));
  float* adst1  = (float*)alloc((size_t)CN*2*sizeof(float));
  float* asrc2  = (float*)alloc((size_t)CN*sizeof(float));
  float* adst2  = (float*)alloc((size_t)CN*sizeof(float));

  k_setup<<<425,256,0,stream>>>(zbase, Wo, WoT, W1, W2, W12T,
                                as1, ad1, va1s, va1d, as2, ad2, bb1,
                                v2ss, v2dd, ccv, b12);

  k_bn_stats<<<625,256,0,stream>>>(x, wl1,wl2,wp1,wp2,wg, gsum, gsq);

  k_count  <<<666,256,0,stream>>>(ei, counts, gsum, gsq, sA, sB,
                                  gl1,gl2,gp1,gp2,gg, bel1,bel2,bep1,bep2,beg);
  k_scan   <<<1,1024,0,stream>>>(counts, offs);
  k_perm   <<<1,1024,0,stream>>>(counts, perm);
  k_scatter<<<665,256,0,stream>>>(ei, offs, cursor, srcl);

  const int gx  = (CN + 255)/256;
  const int gx2 = (CN + 127)/128;
  const int aggB = 1250*CB;
  for (int c = 0; c < nc; c++){
    const int base = c*CN;

    k_feat<<<gx2,256,0,stream>>>(x, wl1,wl2,wp1,wp2,wg, sA, sB, va1s, va1d,
                                 feat, featL, asrc1, adst1, base, CN);

    k_agg1<<<aggB,256,0,stream>>>(feat, asrc1, adst1, offs, srcl, perm, aggF,
                                  v2ss, v2dd, ccv, asrc2, adst2, cbMask, cbShift);

    k_mfma<9,0,9,3,0><<<gx,256,0,stream>>>(aggF,288, (const u16*)0,0, W12T,288, h2,144, 0, b12, CN,
                                           (const float*)0,(const float*)0,(float*)0);

    k_agg2<<<aggB,256,0,stream>>>(h2,144, asrc2, adst2, offs, srcl, perm, bb2, g2l,160,
                                  cbMask, cbShift);

    k_mfma<5,5,9,2,0><<<gx,256,0,stream>>>(g2l,160, featL,160, WoT,320, (u16*)0,0, 0, bo, CN,
                                           Wo2, bo2, (float*)d_out + base);
  }
}

// Round 15
// 479.217 us; speedup vs baseline: 1.8307x; 1.0149x over previous
//
#include <hip/hip_runtime.h>
#include <hip/hip_bf16.h>
#include <math.h>

typedef unsigned short u16;
typedef unsigned int   u32;
typedef short v8s __attribute__((ext_vector_type(8)));
typedef float v4f __attribute__((ext_vector_type(4)));
#define DEV static __device__ __forceinline__

DEV float u2f(u16 u){ union{u32 i; float f;} v; v.i = ((u32)u)<<16; return v.f; }
DEV u16   f2u(float f){ union{float ff; u32 i;} v; v.ff = f; u32 r = v.i + 0x7fffu + ((v.i>>16)&1u); return (u16)(r>>16); }
DEV float lrelu02(float x){ return x > 0.f ? x : 0.2f*x; }
DEV float lrelu01(float x){ return x > 0.f ? x : 0.01f*x; }
DEV float fast_tanh(float x){
  float cx = fminf(fmaxf(x, -15.f), 15.f);
  float e = __expf(2.f*cx);
  return (e - 1.f) * __builtin_amdgcn_rcpf(e + 1.f);
}
DEV float wred_sum(float v){
  #pragma unroll
  for (int o = 32; o > 0; o >>= 1) v += __shfl_xor(v, o, 64);
  return v;
}
DEV float wred_max32(float v){
  #pragma unroll
  for (int o = 16; o > 0; o >>= 1) v = fmaxf(v, __shfl_xor(v, o, 64));
  return v;
}
DEV float wred_sum32(float v){
  #pragma unroll
  for (int o = 16; o > 0; o >>= 1) v += __shfl_xor(v, o, 64);
  return v;
}

constexpr int B_   = 8;
constexpr int P_   = 32;
constexpr int N0_  = 10000;
constexpr int NODES = B_ * N0_;      // 80000
constexpr int E_   = 160000;
constexpr int NE_  = E_ + N0_;       // 170000

// ---------------- merged setup ----------------
__global__ void __launch_bounds__(256) k_setup(int* __restrict__ zbase,
    const float* __restrict__ Wo, u16* __restrict__ WoT,
    const float* __restrict__ W1, const float* __restrict__ W2, u16* __restrict__ W12T,
    const float* __restrict__ as1, const float* __restrict__ ad1,
    float* __restrict__ va1s, float* __restrict__ va1d,
    const float* __restrict__ as2, const float* __restrict__ ad2,
    const float* __restrict__ bb1,
    float* __restrict__ v2ss, float* __restrict__ v2dd,
    float* __restrict__ cc, float* __restrict__ b12)
{
  __shared__ float l2s[272], l2d[272];
  int blk = blockIdx.x, tid = threadIdx.x;
  if (blk < 79){ int i = blk*256 + tid; if (i < 20080) zbase[i] = 0; return; }
  blk -= 79;
  if (blk < 180){           // WoT[n][k] (144x320), head split
    int i = blk*256 + tid; if (i >= 144*320) return;
    int n = i/320, k = i - n*320; float v = 0.f;
    if (n < 136){
      if (k < 136) v = Wo[(size_t)k*136 + n];
      else if (k >= 160 && k < 296) v = Wo[(size_t)(k-24)*136 + n];
    }
    WoT[i] = f2u(v); return;
  }
  blk -= 180;
  if (blk < 162){           // W12T[n][kk] (144x288) = (W1@W2)^T per head-block
    int i = blk*256 + tid; if (i >= 144*288) return;
    int n = i/288, kk = i - n*288; float v = 0.f;
    if (n < 136 && kk < 272){
      int hh = kk/136, k = kk - hh*136;
      for (int c = 0; c < 136; c++)
        v = fmaf(W1[(size_t)k*272 + hh*136 + c], W2[(size_t)(hh*136+c)*136 + n], v);
    }
    W12T[i] = f2u(v); return;
  }
  blk -= 162;
  if (blk < 2){             // va1 = W1 a1 (272)
    int t = blk*256 + tid; if (t >= 272) return;
    int hh = t/136, k = t - hh*136; float s = 0.f, d = 0.f;
    for (int c = 0; c < 136; c++){
      float w = W1[(size_t)k*272 + hh*136 + c];
      s = fmaf(w, as1[hh*136+c], s);
      d = fmaf(w, ad1[hh*136+c], d);
    }
    va1s[t] = s; va1d[t] = d; return;
  }
  blk -= 2;
  {                         // v2'' = W1@(W2 a2); cc = bb1·(W2 a2); b12 = bb1@W2
    for (int m = tid; m < 272; m += 256){
      float vs = 0.f, vd = 0.f;
      for (int n2 = 0; n2 < 136; n2++){
        float w2 = W2[(size_t)m*136 + n2];
        vs = fmaf(w2, as2[n2], vs);
        vd = fmaf(w2, ad2[n2], vd);
      }
      l2s[m] = vs; l2d[m] = vd;
    }
    __syncthreads();
    int t0 = blk*256 + tid;
    if (t0 < 272){
      int hh = t0/136, k = t0 - hh*136; float s = 0.f, d = 0.f;
      for (int c = 0; c < 136; c++){
        float w = W1[(size_t)k*272 + hh*136 + c];
        s = fmaf(w, l2s[hh*136+c], s);
        d = fmaf(w, l2d[hh*136+c], d);
      }
      v2ss[t0] = s; v2dd[t0] = d;
    }
    if (blk == 1){
      if (tid < 64){
        float s = 0.f, d = 0.f;
        for (int m = tid; m < 272; m += 64){
          s = fmaf(bb1[m], l2s[m], s);
          d = fmaf(bb1[m], l2d[m], d);
        }
        s = wred_sum(s); d = wred_sum(d);
        if (tid == 0){ cc[0] = s; cc[1] = d; }
      } else if (tid < 200){
        int n2 = tid - 64; float v = 0.f;
        for (int m = 0; m < 272; m++) v = fmaf(bb1[m], W2[(size_t)m*136 + n2], v);
        b12[n2] = v;
      }
    }
  }
}

// ---------------- backbone ----------------
DEV void load_convw(float* lw, const float* wl1, const float* wl2, const float* wp1,
                    const float* wp2, const float* wg, int tid, int nth){
  for (int i = tid; i < 384; i += nth){
    float v;
    if      (i < 24)  v = wl1[i];
    else if (i < 64)  v = wl2[i-24];
    else if (i < 88)  v = wp1[i-64];
    else if (i < 128) v = wp2[i-88];
    else              v = wg [i-128];
    lw[i] = v;
  }
}

template<int KS,int DIL,int T>
DEV void conv_stats(const float* xc, const float* wk, float& s, float& q){
  #pragma unroll
  for (int t = 0; t < T; t++){
    float v = 0.f;
    #pragma unroll
    for (int j = 0; j < KS; j++) v = fmaf(wk[j], xc[t + j*DIL], v);
    s += v; q = fmaf(v, v, q);
  }
}

__global__ void __launch_bounds__(256) k_bn_stats(
    const float* __restrict__ x,
    const float* __restrict__ wl1, const float* __restrict__ wl2,
    const float* __restrict__ wp1, const float* __restrict__ wp2,
    const float* __restrict__ wg,
    float* __restrict__ gsum, float* __restrict__ gsq)
{
  __shared__ float lw[384];
  __shared__ float lacc[80];
  const int tid = threadIdx.x;
  load_convw(lw, wl1, wl2, wp1, wp2, wg, tid, 256);
  if (tid < 80) lacc[tid] = 0.f;
  __syncthreads();

  const int lane = tid & 63, wv = tid >> 6;
  const int nodeLocal = (wv >> 1)*64 + lane;
  const int half = wv & 1;
  const int gid = blockIdx.x*128 + nodeLocal;
  float xc[P_];
  if (gid < NODES){
    int b = gid / N0_, n = gid - b*N0_;
    const float* xp = x + (size_t)b*P_*N0_ + n;
    #pragma unroll
    for (int p = 0; p < P_; p++) xc[p] = xp[(size_t)p*N0_];
  } else {
    #pragma unroll
    for (int p = 0; p < P_; p++) xc[p] = 0.f;
  }

  auto red = [&](int ch, float s, float q){
    #pragma unroll
    for (int o = 32; o > 0; o >>= 1){ s += __shfl_down(s,o,64); q += __shfl_down(q,o,64); }
    if (lane == 0){ atomicAdd(&lacc[ch], s); atomicAdd(&lacc[40+ch], q); }
  };

  if (half == 0){
    #pragma unroll
    for (int k = 0; k < 8; k++){ float s=0,q=0; conv_stats<3,1,30>(xc, lw      + k*3 , s,q); red(k,     s,q); }
    #pragma unroll
    for (int k = 0; k < 8; k++){ float s=0,q=0; conv_stats<5,1,28>(xc, lw + 24 + k*5 , s,q); red(8+k,   s,q); }
  } else {
    #pragma unroll
    for (int k = 0; k < 8; k++){ float s=0,q=0; conv_stats<3,2,28>(xc, lw + 64 + k*3 , s,q); red(16+k,  s,q); }
    #pragma unroll
    for (int k = 0; k < 8; k++){ float s=0,q=0; conv_stats<5,2,24>(xc, lw + 88 + k*5 , s,q); red(24+k,  s,q); }
    #pragma unroll
    for (int k = 0; k < 8; k++){ float s=0,q=0; conv_stats<32,1,1>(xc, lw + 128+ k*32, s,q); red(32+k,  s,q); }
  }

  __syncthreads();
  if (tid < 40)      atomicAdd(&gsum[tid],    lacc[tid]);
  else if (tid < 80) atomicAdd(&gsq [tid-40], lacc[tid]);
}

// count kernel with bn_fin folded in as the last block
__global__ void k_count(const int* __restrict__ ei, int* __restrict__ counts,
                        const float* __restrict__ gsum, const float* __restrict__ gsq,
                        float* __restrict__ sA, float* __restrict__ sB,
                        const float* g0, const float* g1, const float* g2, const float* g3, const float* g4,
                        const float* e0, const float* e1, const float* e2, const float* e3, const float* e4){
  if (blockIdx.x == 665){
    int t = threadIdx.x;
    if (t >= 40) return;
    int bi = t >> 3, k = t & 7;
    const int Ts[5] = {30,28,28,24,1};
    float cnt  = (float)NODES * (float)Ts[bi];
    float mean = gsum[t] / cnt;
    float var  = gsq[t] / cnt - mean*mean;
    const float* gp = bi==0?g0: bi==1?g1: bi==2?g2: bi==3?g3: g4;
    const float* ep = bi==0?e0: bi==1?e1: bi==2?e2: bi==3?e3: e4;
    float a = gp[k] * rsqrtf(fmaxf(var, 0.f) + 1e-5f);
    sA[t] = a;
    sB[t] = ep[k] - a*mean;
    return;
  }
  int e = blockIdx.x*blockDim.x + threadIdx.x;
  if (e >= NE_) return;
  int dst = (e < E_) ? ei[E_ + e] : (e - E_);
  atomicAdd(&counts[dst], 1);
}

__global__ void __launch_bounds__(1024) k_scan(const int* __restrict__ counts, int* __restrict__ offs){
  __shared__ int part[1024];
  int t = threadIdx.x;
  int loc[10]; int s = 0;
  #pragma unroll
  for (int i = 0; i < 10; i++){
    int idx = t*10 + i;
    int c = (idx < N0_) ? counts[idx] : 0;
    loc[i] = s; s += c;
  }
  part[t] = s;
  __syncthreads();
  for (int o = 1; o < 1024; o <<= 1){
    int v = (t >= o) ? part[t-o] : 0;
    __syncthreads();
    part[t] += v;
    __syncthreads();
  }
  int pre = (t == 0) ? 0 : part[t-1];
  #pragma unroll
  for (int i = 0; i < 10; i++){
    int idx = t*10 + i;
    if (idx < N0_) offs[idx] = pre + loc[i];
  }
  if (t == 0) offs[N0_] = part[1023];
}

// degree-sorted permutation (counting sort by degree, one block)
__global__ void __launch_bounds__(1024) k_perm(const int* __restrict__ counts, int* __restrict__ perm){
  __shared__ int hist[129];
  __shared__ int base[129];
  int t = threadIdx.x;
  if (t < 129) hist[t] = 0;
  __syncthreads();
  int dloc[10];
  #pragma unroll
  for (int i = 0; i < 10; i++){
    int idx = t*10 + i;
    if (idx < N0_){
      int d = min(counts[idx], 128);
      dloc[i] = d;
      atomicAdd(&hist[d], 1);
    }
  }
  __syncthreads();
  if (t == 0){
    int s = 0;
    for (int b = 0; b <= 128; b++){ base[b] = s; s += hist[b]; }
  }
  __syncthreads();
  #pragma unroll
  for (int i = 0; i < 10; i++){
    int idx = t*10 + i;
    if (idx < N0_){
      int pos = atomicAdd(&base[dloc[i]], 1);
      perm[pos] = idx;
    }
  }
}

__global__ void k_scatter(const int* __restrict__ ei, const int* __restrict__ offs,
                          int* __restrict__ cursor, int* __restrict__ srcl){
  int e = blockIdx.x*blockDim.x + threadIdx.x;
  if (e >= NE_) return;
  int src, dst;
  if (e < E_){ src = ei[e]; dst = ei[E_ + e]; } else { src = dst = e - E_; }
  int pos = atomicAdd(&cursor[dst], 1);
  srcl[offs[dst] + pos] = src;
}

template<int KS,int DIL,int T>
DEV void conv_pool4(const float* xc, const float* wk, float A, float Bc, float* o4){
  float y[T];
  #pragma unroll
  for (int t = 0; t < T; t++){
    float v = 0.f;
    #pragma unroll
    for (int j = 0; j < KS; j++) v = fmaf(wk[j], xc[t + j*DIL], v);
    y[t] = fmaf(A, v, Bc);
  }
  #pragma unroll
  for (int i = 0; i < 4; i++){
    const int lo = (i*T)/4, hi = ((i+1)*T + 3)/4;
    float m = y[lo];
    #pragma unroll
    for (int t = 0; t < T; t++){ if (t > lo && t < hi) m = fmaxf(m, y[t]); }
    o4[i] = m;
  }
}

// feat [m][160] bf16 (tanh) + featL (lrelu01) + fused layer-1 attention dots (float4 LDS)
__global__ void __launch_bounds__(256) k_feat(
    const float* __restrict__ x,
    const float* __restrict__ wl1, const float* __restrict__ wl2,
    const float* __restrict__ wp1, const float* __restrict__ wp2,
    const float* __restrict__ wg,
    const float* __restrict__ sA, const float* __restrict__ sB,
    const float* __restrict__ va1s, const float* __restrict__ va1d,
    u16* __restrict__ feat, u16* __restrict__ featL,
    float* __restrict__ asrc1, float* __restrict__ adst1,
    int base, int m)
{
  __shared__ float lw[384];
  __shared__ float lA[40], lB[40];
  __shared__ float4 lv4[136];
  __shared__ float sdt[128][4];
  const int tid = threadIdx.x;
  load_convw(lw, wl1, wl2, wp1, wp2, wg, tid, 256);
  if (tid < 40){ lA[tid] = sA[tid]; lB[tid] = sB[tid]; }
  for (int i = tid; i < 136; i += 256)
    lv4[i] = make_float4(va1s[i], va1d[i], va1s[136+i], va1d[136+i]);
  __syncthreads();

  const int lane = tid & 63, wv = tid >> 6;
  const int nodeLocal = (wv >> 1)*64 + lane;     // 0..127
  const int half = wv & 1;                       // wave-uniform
  const int nodeIdx = blockIdx.x*128 + nodeLocal;
  const bool act = nodeIdx < m;
  const int gcl = base + (act ? nodeIdx : (m-1));
  int b = gcl / N0_, n = gcl - b*N0_;
  float xc[P_];
  const float* xp = x + (size_t)b*P_*N0_ + n;
  #pragma unroll
  for (int p = 0; p < P_; p++) xc[p] = xp[(size_t)p*N0_];

  float dt[4] = {0.f,0.f,0.f,0.f};
  u32 pk[4], pkl[4];
  u16* orow  = feat  + (size_t)nodeIdx*160;
  u16* olrow = featL + (size_t)nodeIdx*160;
  auto emit = [&](int ch, float v){
    float t = fast_tanh(v);
    float4 vv = lv4[ch];
    dt[0] = fmaf(t, vv.x, dt[0]);
    dt[1] = fmaf(t, vv.y, dt[1]);
    dt[2] = fmaf(t, vv.z, dt[2]);
    dt[3] = fmaf(t, vv.w, dt[3]);
    u16 h  = f2u(t);
    u16 hl = f2u(lrelu01(t));
    int s = ch & 7;
    if ((s & 1) == 0){ pk[s>>1] = h;                pkl[s>>1] = hl; }
    else             { pk[s>>1] |= ((u32)h) << 16;  pkl[s>>1] |= ((u32)hl) << 16; }
    if (s == 7 && act){
      *(uint4*)(orow  + (ch - 7)) = make_uint4(pk[0],pk[1],pk[2],pk[3]);
      *(uint4*)(olrow + (ch - 7)) = make_uint4(pkl[0],pkl[1],pkl[2],pkl[3]);
    }
  };

  float o4[4];
  if (half == 0){
    #pragma unroll
    for (int k = 0; k < 8; k++){
      conv_pool4<3,1,30>(xc, lw + k*3, lA[k], lB[k], o4);
      #pragma unroll
      for (int i = 0; i < 4; i++) emit(k*4+i, o4[i]);
    }
    #pragma unroll
    for (int k = 0; k < 8; k++){
      conv_pool4<5,1,28>(xc, lw + 24 + k*5, lA[8+k], lB[8+k], o4);
      #pragma unroll
      for (int i = 0; i < 4; i++) emit(32 + k*4+i, o4[i]);
    }
  } else {
    #pragma unroll
    for (int k = 0; k < 8; k++){
      conv_pool4<3,2,28>(xc, lw + 64 + k*3, lA[16+k], lB[16+k], o4);
      #pragma unroll
      for (int i = 0; i < 4; i++) emit(64 + k*4+i, o4[i]);
    }
    #pragma unroll
    for (int k = 0; k < 8; k++){
      conv_pool4<5,2,24>(xc, lw + 88 + k*5, lA[24+k], lB[24+k], o4);
      #pragma unroll
      for (int i = 0; i < 4; i++) emit(96 + k*4+i, o4[i]);
    }
    #pragma unroll
    for (int k = 0; k < 8; k++){
      float v = 0.f;
      #pragma unroll
      for (int j = 0; j < 32; j++) v = fmaf(lw[128 + k*32 + j], xc[j], v);
      emit(128 + k, fmaf(lA[32+k], v, lB[32+k]));
    }
  }

  if (half == 1){
    sdt[nodeLocal][0] = dt[0]; sdt[nodeLocal][1] = dt[1];
    sdt[nodeLocal][2] = dt[2]; sdt[nodeLocal][3] = dt[3];
  }
  __syncthreads();
  if (half == 0 && act){
    asrc1[(size_t)nodeIdx*2]   = dt[0] + sdt[nodeLocal][0];
    asrc1[(size_t)nodeIdx*2+1] = dt[2] + sdt[nodeLocal][2];
    adst1[(size_t)nodeIdx*2]   = dt[1] + sdt[nodeLocal][1];
    adst1[(size_t)nodeIdx*2+1] = dt[3] + sdt[nodeLocal][3];
  }
}

// ---------------- MFMA GEMM: MT m-tiles (16 rows each) per wave ----------------
template<int MT,int KT1,int KT2,int NT,int EPI,int LR2>
__global__ void __launch_bounds__(256) k_mfma(
    const u16* __restrict__ A1, int sA1,
    const u16* __restrict__ A2, int sA2,
    const u16* __restrict__ BT, int sBT,
    u16* __restrict__ C, int sC, int nbase,
    const float* __restrict__ bias, int m,
    const float* __restrict__ w2v, const float* __restrict__ bo2p, float* __restrict__ fout)
{
  const int wv = threadIdx.x >> 6, lane = threadIdx.x & 63;
  const int quad = lane >> 4, l15 = lane & 15;
  const int mb = blockIdx.x*(MT*64) + wv*(MT*16);
  int ar[MT];
  #pragma unroll
  for (int mt = 0; mt < MT; mt++) ar[mt] = min(mb + mt*16 + l15, m-1);

  v4f acc[MT][NT];
  #pragma unroll
  for (int mt = 0; mt < MT; mt++)
    #pragma unroll
    for (int nt = 0; nt < NT; nt++)
      acc[mt][nt] = (v4f){0.f,0.f,0.f,0.f};

  for (int kt = 0; kt < KT1+KT2; kt++){
    const u16* ab; int sA, koff;
    if (KT2 == 0 || kt < KT1){ ab = A1; sA = sA1; koff = kt*32; }
    else { ab = A2; sA = sA2; koff = (kt-KT1)*32; }
    v8s a[MT];
    #pragma unroll
    for (int mt = 0; mt < MT; mt++)
      a[mt] = *(const v8s*)(ab + (size_t)ar[mt]*sA + koff + quad*8);
    if (KT2 > 0 && LR2 && kt >= KT1){
      #pragma unroll
      for (int mt = 0; mt < MT; mt++)
        #pragma unroll
        for (int j = 0; j < 8; j++){
          float f = u2f((u16)a[mt][j]);
          f = f > 0.f ? f : 0.01f*f;
          a[mt][j] = (short)f2u(f);
        }
    }
    const int kb = kt*32 + quad*8;
    #pragma unroll
    for (int nt = 0; nt < NT; nt++){
      v8s b = *(const v8s*)(BT + (size_t)(nbase + nt*16 + l15)*sBT + kb);
      #pragma unroll
      for (int mt = 0; mt < MT; mt++)
        acc[mt][nt] = __builtin_amdgcn_mfma_f32_16x16x32_bf16(a[mt], b, acc[mt][nt], 0, 0, 0);
    }
  }

  if (EPI == 2){
    const float bo2v = bo2p[0];
    #pragma unroll
    for (int mt = 0; mt < MT; mt++){
      float part[4] = {0.f,0.f,0.f,0.f};
      #pragma unroll
      for (int nt = 0; nt < NT; nt++){
        const int col = nt*16 + l15;
        float wv2 = (col < 136) ? w2v[col] : 0.f;
        float bv  = bias[min(col,135)];
        #pragma unroll
        for (int i = 0; i < 4; i++){
          float xv = lrelu01(acc[mt][nt][i] + bv);
          part[i] = fmaf(xv, wv2, part[i]);
        }
      }
      #pragma unroll
      for (int i = 0; i < 4; i++){
        float v = part[i];
        v += __shfl_xor(v, 1, 64);
        v += __shfl_xor(v, 2, 64);
        v += __shfl_xor(v, 4, 64);
        v += __shfl_xor(v, 8, 64);
        int r = mb + mt*16 + quad*4 + i;
        if (l15 == 0 && r < m) fout[r] = v + bo2v;
      }
    }
    return;
  }

  #pragma unroll
  for (int mt = 0; mt < MT; mt++){
    const int r0 = mb + mt*16 + quad*4;
    #pragma unroll
    for (int nt = 0; nt < NT; nt++){
      const int col = nbase + nt*16 + l15;
      #pragma unroll
      for (int i = 0; i < 4; i++){
        int r = r0 + i;
        if (r < m){
          float xv = acc[mt][nt][i];
          if (EPI == 1){ xv += bias[min(col,135)]; xv = lrelu01(xv); }
          if (EPI == 3){ xv += bias[min(col,135)]; }
          C[(size_t)r*sC + col] = f2u(xv);
        }
      }
    }
  }
}

// ---------------- layer-1 GAT aggregation: two degree-paired dst per wave ----------------
__global__ void __launch_bounds__(256) k_agg1(const u16* __restrict__ feat,
    const float* __restrict__ asrc, const float* __restrict__ adst,
    const int* __restrict__ offs, const int* __restrict__ srcl,
    const int* __restrict__ perm,
    u16* __restrict__ aggF,
    const float* __restrict__ v2s, const float* __restrict__ v2d,
    const float* __restrict__ cc,
    float* __restrict__ as_out, float* __restrict__ ad_out,
    int cbMask, int cbShift)
{
  const int tid = threadIdx.x;
  const int wv = tid >> 6, lane = tid & 63;
  const int half = lane >> 5, l32 = lane & 31;
  const int hbase = lane & 32;
  const int id = blockIdx.x;
  const int bb = id & cbMask;
  const int q = (id >> cbShift)*4 + wv;       // pair index
  const int dst = perm[2*q + half];
  const int nbase = bb*N0_;
  const int node = nbase + dst;
  const int start = offs[dst], end = offs[dst+1];
  const int ne = end - start;

  const float ad0 = adst[(size_t)node*2], ad1v = adst[(size_t)node*2+1];
  const char* featB = (const char*)feat;

  float m0h0=0,m1h0=0,m2h0=0,m3h0=0;
  float m0h1=0,m1h1=0,m2h1=0,m3h1=0;
  float r0h0=0,r1h0=0,r0h1=0,r1h1=0;

  auto acc_edge = [&](int off, float c0, float c1){
    const u16* fp = (const u16*)(featB + off);
    const ushort4 hv = *(const ushort4*)(fp + 4*l32);
    float f0=u2f(hv.x), f1=u2f(hv.y), f2=u2f(hv.z), f3=u2f(hv.w);
    m0h0=fmaf(c0,f0,m0h0); m1h0=fmaf(c0,f1,m1h0); m2h0=fmaf(c0,f2,m2h0); m3h0=fmaf(c0,f3,m3h0);
    m0h1=fmaf(c1,f0,m0h1); m1h1=fmaf(c1,f1,m1h1); m2h1=fmaf(c1,f2,m2h1); m3h1=fmaf(c1,f3,m3h1);
    if (l32 < 4){
      const ushort2 hr = *(const ushort2*)(fp + 128 + 2*l32);
      float g0=u2f(hr.x), g1=u2f(hr.y);
      r0h0=fmaf(c0,g0,r0h0); r1h0=fmaf(c0,g1,r1h0);
      r0h1=fmaf(c1,g0,r0h1); r1h1=fmaf(c1,g1,r1h1);
    }
  };
  auto acc_edge2 = [&](int o0, int o1, float a0, float a1, float b0, float b1){
    const u16* p0 = (const u16*)(featB + o0);
    const u16* p1 = (const u16*)(featB + o1);
    const ushort4 v0 = *(const ushort4*)(p0 + 4*l32);
    const ushort4 v1 = *(const ushort4*)(p1 + 4*l32);
    ushort2 q0, q1;
    if (l32 < 4){
      q0 = *(const ushort2*)(p0 + 128 + 2*l32);
      q1 = *(const ushort2*)(p1 + 128 + 2*l32);
    }
    float f;
    f=u2f(v0.x); m0h0=fmaf(a0,f,m0h0); m0h1=fmaf(b0,f,m0h1);
    f=u2f(v0.y); m1h0=fmaf(a0,f,m1h0); m1h1=fmaf(b0,f,m1h1);
    f=u2f(v0.z); m2h0=fmaf(a0,f,m2h0); m2h1=fmaf(b0,f,m2h1);
    f=u2f(v0.w); m3h0=fmaf(a0,f,m3h0); m3h1=fmaf(b0,f,m3h1);
    f=u2f(v1.x); m0h0=fmaf(a1,f,m0h0); m0h1=fmaf(b1,f,m0h1);
    f=u2f(v1.y); m1h0=fmaf(a1,f,m1h0); m1h1=fmaf(b1,f,m1h1);
    f=u2f(v1.z); m2h0=fmaf(a1,f,m2h0); m2h1=fmaf(b1,f,m2h1);
    f=u2f(v1.w); m3h0=fmaf(a1,f,m3h0); m3h1=fmaf(b1,f,m3h1);
    if (l32 < 4){
      f=u2f(q0.x); r0h0=fmaf(a0,f,r0h0); r0h1=fmaf(b0,f,r0h1);
      f=u2f(q0.y); r1h0=fmaf(a0,f,r1h0); r1h1=fmaf(b0,f,r1h1);
      f=u2f(q1.x); r0h0=fmaf(a1,f,r0h0); r0h1=fmaf(b1,f,r0h1);
      f=u2f(q1.y); r1h0=fmaf(a1,f,r1h0); r1h1=fmaf(b1,f,r1h1);
    }
  };

  if (ne <= 32){
    const bool has = l32 < ne;
    const int sn = nbase + (has ? srcl[start + l32] : 0);
    const int offL = sn * 320;
    float al0 = has ? lrelu02(asrc[(size_t)sn*2]   + ad0)  : -1e30f;
    float al1 = has ? lrelu02(asrc[(size_t)sn*2+1] + ad1v) : -1e30f;
    float mm = wred_max32(al0);
    float p0 = has ? __expf(al0 - mm) : 0.f;
    float c0 = p0 * (1.f/(wred_sum32(p0) + 1e-16f));
    mm = wred_max32(al1);
    float p1 = has ? __expf(al1 - mm) : 0.f;
    float c1 = p1 * (1.f/(wred_sum32(p1) + 1e-16f));
    int j = 0;
    for (; j + 1 < ne; j += 2){
      int   o0 = __shfl(offL, hbase + j, 64), o1 = __shfl(offL, hbase + j + 1, 64);
      float a0 = __shfl(c0, hbase + j, 64),   a1 = __shfl(c0, hbase + j + 1, 64);
      float b0 = __shfl(c1, hbase + j, 64),   b1 = __shfl(c1, hbase + j + 1, 64);
      acc_edge2(o0, o1, a0, a1, b0, b1);
    }
    if (j < ne)
      acc_edge(__shfl(offL, hbase + j, 64), __shfl(c0, hbase + j, 64), __shfl(c1, hbase + j, 64));
  } else {
    float lm0 = -1e30f, lm1 = -1e30f;
    for (int e = start + l32; e < end; e += 32){
      int sn = nbase + srcl[e];
      lm0 = fmaxf(lm0, lrelu02(asrc[(size_t)sn*2]   + ad0));
      lm1 = fmaxf(lm1, lrelu02(asrc[(size_t)sn*2+1] + ad1v));
    }
    float m0 = wred_max32(lm0), m1 = wred_max32(lm1);
    float ls0 = 0.f, ls1 = 0.f;
    for (int e = start + l32; e < end; e += 32){
      int sn = nbase + srcl[e];
      ls0 += __expf(lrelu02(asrc[(size_t)sn*2]   + ad0)  - m0);
      ls1 += __expf(lrelu02(asrc[(size_t)sn*2+1] + ad1v) - m1);
    }
    float si0 = 1.f/(wred_sum32(ls0) + 1e-16f);
    float si1 = 1.f/(wred_sum32(ls1) + 1e-16f);
    for (int cs = start; cs < end; cs += 32){
      int cnt = min(32, end - cs);
      bool has = l32 < cnt;
      int sn = nbase + (has ? srcl[cs + l32] : 0);
      int offL = sn * 320;
      float c0 = 0.f, c1 = 0.f;
      if (has){
        c0 = __expf(lrelu02(asrc[(size_t)sn*2]   + ad0)  - m0) * si0;
        c1 = __expf(lrelu02(asrc[(size_t)sn*2+1] + ad1v) - m1) * si1;
      }
      for (int j = 0; j < cnt; j++)
        acc_edge(__shfl(offL, hbase + j, 64), __shfl(c0, hbase + j, 64), __shfl(c1, hbase + j, 64));
    }
  }

  u16* outp = aggF + (size_t)node*288;
  {
    ushort4 s0; s0.x=f2u(m0h0); s0.y=f2u(m1h0); s0.z=f2u(m2h0); s0.w=f2u(m3h0);
    *(ushort4*)(outp + 4*l32) = s0;
    ushort4 s1; s1.x=f2u(m0h1); s1.y=f2u(m1h1); s1.z=f2u(m2h1); s1.w=f2u(m3h1);
    *(ushort4*)(outp + 136 + 4*l32) = s1;
    if (l32 < 4){
      ushort2 t0; t0.x=f2u(r0h0); t0.y=f2u(r1h0);
      *(ushort2*)(outp + 128 + 2*l32) = t0;
      ushort2 t1; t1.x=f2u(r0h1); t1.y=f2u(r1h1);
      *(ushort2*)(outp + 136 + 128 + 2*l32) = t1;
    }
  }
  {
    int c = 4*l32;
    float s = m0h0*v2s[c] + m1h0*v2s[c+1] + m2h0*v2s[c+2] + m3h0*v2s[c+3]
            + m0h1*v2s[136+c] + m1h1*v2s[136+c+1] + m2h1*v2s[136+c+2] + m3h1*v2s[136+c+3];
    float d = m0h0*v2d[c] + m1h0*v2d[c+1] + m2h0*v2d[c+2] + m3h0*v2d[c+3]
            + m0h1*v2d[136+c] + m1h1*v2d[136+c+1] + m2h1*v2d[136+c+2] + m3h1*v2d[136+c+3];
    if (l32 < 4){
      int cr = 128 + 2*l32;
      s += r0h0*v2s[cr] + r1h0*v2s[cr+1] + r0h1*v2s[136+cr] + r1h1*v2s[136+cr+1];
      d += r0h0*v2d[cr] + r1h0*v2d[cr+1] + r0h1*v2d[136+cr] + r1h1*v2d[136+cr+1];
    }
    s = wred_sum32(s); d = wred_sum32(d);
    if (l32 == 0){ as_out[node] = s + cc[0]; ad_out[node] = d + cc[1]; }
  }
}

// ---------------- layer-2 GAT aggregation (H=1): two degree-paired dst per wave ----------------
__global__ void __launch_bounds__(256) k_agg2(const u16* __restrict__ h, int sh,
    const float* __restrict__ asrc, const float* __restrict__ adst,
    const int* __restrict__ offs, const int* __restrict__ srcl,
    const int* __restrict__ perm,
    const float* __restrict__ bias, u16* __restrict__ outp0, int so,
    int cbMask, int cbShift)
{
  const int tid = threadIdx.x;
  const int wv = tid >> 6, lane = tid & 63;
  const int half = lane >> 5, l32 = lane & 31;
  const int hbase = lane & 32;
  const int id = blockIdx.x;
  const int bb = id & cbMask;
  const int q = (id >> cbShift)*4 + wv;
  const int dst = perm[2*q + half];
  const int nbase = bb*N0_;
  const int node = nbase + dst;
  const int start = offs[dst], end = offs[dst+1];
  const int ne = end - start;
  const int bstride = 2*sh;

  const float adh = adst[node];
  const char* hB = (const char*)h;

  float a0=0, a1=0, a2=0, a3=0, rr0=0, rr1=0;

  auto acc_edge = [&](int off, float c0){
    const u16* hp = (const u16*)(hB + off);
    const ushort4 hv = *(const ushort4*)(hp + 4*l32);
    a0 = fmaf(c0, u2f(hv.x), a0); a1 = fmaf(c0, u2f(hv.y), a1);
    a2 = fmaf(c0, u2f(hv.z), a2); a3 = fmaf(c0, u2f(hv.w), a3);
    if (l32 < 4){
      const ushort2 hr = *(const ushort2*)(hp + 128 + 2*l32);
      rr0 = fmaf(c0, u2f(hr.x), rr0);
      rr1 = fmaf(c0, u2f(hr.y), rr1);
    }
  };
  auto acc_edge2 = [&](int o0, int o1, float c0, float c1){
    const u16* p0 = (const u16*)(hB + o0);
    const u16* p1 = (const u16*)(hB + o1);
    const ushort4 v0 = *(const ushort4*)(p0 + 4*l32);
    const ushort4 v1 = *(const ushort4*)(p1 + 4*l32);
    ushort2 q0, q1;
    if (l32 < 4){
      q0 = *(const ushort2*)(p0 + 128 + 2*l32);
      q1 = *(const ushort2*)(p1 + 128 + 2*l32);
    }
    a0 = fmaf(c0, u2f(v0.x), a0); a1 = fmaf(c0, u2f(v0.y), a1);
    a2 = fmaf(c0, u2f(v0.z), a2); a3 = fmaf(c0, u2f(v0.w), a3);
    a0 = fmaf(c1, u2f(v1.x), a0); a1 = fmaf(c1, u2f(v1.y), a1);
    a2 = fmaf(c1, u2f(v1.z), a2); a3 = fmaf(c1, u2f(v1.w), a3);
    if (l32 < 4){
      rr0 = fmaf(c0, u2f(q0.x), rr0); rr1 = fmaf(c0, u2f(q0.y), rr1);
      rr0 = fmaf(c1, u2f(q1.x), rr0); rr1 = fmaf(c1, u2f(q1.y), rr1);
    }
  };

  if (ne <= 32){
    const bool has = l32 < ne;
    const int sn = nbase + (has ? srcl[start + l32] : 0);
    const int offL = sn * bstride;
    float al = has ? lrelu02(asrc[sn] + adh) : -1e30f;
    float m = wred_max32(al);
    float p = has ? __expf(al - m) : 0.f;
    float c0 = p * (1.f/(wred_sum32(p) + 1e-16f));
    int j = 0;
    for (; j + 1 < ne; j += 2){
      int   o0 = __shfl(offL, hbase + j, 64), o1 = __shfl(offL, hbase + j + 1, 64);
      float e0 = __shfl(c0, hbase + j, 64),   e1 = __shfl(c0, hbase + j + 1, 64);
      acc_edge2(o0, o1, e0, e1);
    }
    if (j < ne)
      acc_edge(__shfl(offL, hbase + j, 64), __shfl(c0, hbase + j, 64));
  } else {
    float lm = -1e30f;
    for (int e = start + l32; e < end; e += 32){
      int sn = nbase + srcl[e];
      lm = fmaxf(lm, lrelu02(asrc[sn] + adh));
    }
    float m = wred_max32(lm);
    float ls = 0.f;
    for (int e = start + l32; e < end; e += 32){
      int sn = nbase + srcl[e];
      ls += __expf(lrelu02(asrc[sn] + adh) - m);
    }
    float si = 1.f/(wred_sum32(ls) + 1e-16f);
    for (int cs = start; cs < end; cs += 32){
      int cnt = min(32, end - cs);
      bool has = l32 < cnt;
      int sn = nbase + (has ? srcl[cs + l32] : 0);
      int offL = sn * bstride;
      float c0 = has ? __expf(lrelu02(asrc[sn] + adh) - m) * si : 0.f;
      for (int j = 0; j < cnt; j++)
        acc_edge(__shfl(offL, hbase + j, 64), __shfl(c0, hbase + j, 64));
    }
  }

  u16* outp = outp0 + (size_t)node*so;
  {
    int c = 4*l32;
    ushort4 st;
    st.x = f2u(lrelu01(a0 + bias[c]));
    st.y = f2u(lrelu01(a1 + bias[c+1]));
    st.z = f2u(lrelu01(a2 + bias[c+2]));
    st.w = f2u(lrelu01(a3 + bias[c+3]));
    *(ushort4*)(outp + c) = st;
    if (l32 < 4){
      int cr = 128 + 2*l32;
      ushort2 sr;
      sr.x = f2u(lrelu01(rr0 + bias[cr]));
      sr.y = f2u(lrelu01(rr1 + bias[cr+1]));
      *(ushort2*)(outp + cr) = sr;
    }
  }
}

// ---------------- launch ----------------
extern "C" void kernel_launch(void* const* d_in, const int* in_sizes, int n_in,
                              void* d_out, int out_size, void* d_ws, size_t ws_size,
                              hipStream_t stream)
{
  (void)in_sizes; (void)n_in; (void)out_size;
  const float* x    = (const float*)d_in[0];
  const float* wl1  = (const float*)d_in[1];
  const float* gl1  = (const float*)d_in[3];
  const float* bel1 = (const float*)d_in[4];
  const float* wl2  = (const float*)d_in[5];
  const float* gl2  = (const float*)d_in[7];
  const float* bel2 = (const float*)d_in[8];
  const float* wp1  = (const float*)d_in[9];
  const float* gp1  = (const float*)d_in[11];
  const float* bep1 = (const float*)d_in[12];
  const float* wp2  = (const float*)d_in[13];
  const float* gp2  = (const float*)d_in[15];
  const float* bep2 = (const float*)d_in[16];
  const float* wg   = (const float*)d_in[17];
  const float* gg   = (const float*)d_in[19];
  const float* beg  = (const float*)d_in[20];
  const float* W1   = (const float*)d_in[21];
  const float* as1  = (const float*)d_in[22];
  const float* ad1  = (const float*)d_in[23];
  const float* bb1  = (const float*)d_in[24];
  const float* W2   = (const float*)d_in[25];
  const float* as2  = (const float*)d_in[26];
  const float* ad2  = (const float*)d_in[27];
  const float* bb2  = (const float*)d_in[28];
  const float* Wo   = (const float*)d_in[29];
  const float* bo   = (const float*)d_in[30];
  const float* Wo2  = (const float*)d_in[31];
  const float* bo2  = (const float*)d_in[32];
  const int*   ei   = (const int*)d_in[33];

  const size_t STATIC_BYTES = 1250000;
  int nc = 1;
  while (nc < 8 && STATIC_BYTES + (size_t)1880*(NODES/nc) > ws_size) nc <<= 1;
  const int CB = B_/nc, CN = CB*N0_;
  int cbShift = 0; while ((1 << cbShift) < CB) cbShift++;
  const int cbMask = CB - 1;

  char* wsb = (char*)d_ws; size_t off = 0;
  auto alloc = [&](size_t nbytes)->void*{
    void* p = wsb + off; off = (off + nbytes + 255) & ~(size_t)255; return p;
  };
  int*   zbase  = (int*)  alloc(20080*sizeof(int));
  float* gsum   = (float*)zbase;
  float* gsq    = gsum + 40;
  int*   counts = zbase + 80;
  int*   cursor = counts + 10000;
  float* sA     = (float*)alloc(40*sizeof(float));
  float* sB     = (float*)alloc(40*sizeof(float));
  int*   offs   = (int*)  alloc(10001*sizeof(int));
  int*   srcl   = (int*)  alloc((size_t)NE_*sizeof(int));
  int*   perm   = (int*)  alloc((size_t)N0_*sizeof(int));
  u16*   W12T   = (u16*)  alloc((size_t)144*288*2);
  u16*   WoT    = (u16*)  alloc((size_t)144*320*2);
  float* va1s   = (float*)alloc(272*sizeof(float));
  float* va1d   = (float*)alloc(272*sizeof(float));
  float* v2ss   = (float*)alloc(272*sizeof(float));
  float* v2dd   = (float*)alloc(272*sizeof(float));
  float* ccv    = (float*)alloc(2*sizeof(float));
  float* b12    = (float*)alloc(136*sizeof(float));
  u16*   feat   = (u16*)  alloc((size_t)CN*160*2);
  u16*   featL  = (u16*)  alloc((size_t)CN*160*2);
  u16*   aggF   = (u16*)  alloc((size_t)CN*288*2);
  u16*   h2     = (u16*)  alloc((size_t)CN*144*2);
  u16*   g2l    = (u16*)  alloc((size_t)CN*160*2);
  float* asrc1  = (float*)alloc((size_t)CN*2*sizeof(float));
  float* adst1  = (float*)alloc((size_t)CN*2*sizeof(float));
  float* asrc2  = (float*)alloc((size_t)CN*sizeof(float));
  float* adst2  = (float*)alloc((size_t)CN*sizeof(float));

  k_setup<<<425,256,0,stream>>>(zbase, Wo, WoT, W1, W2, W12T,
                                as1, ad1, va1s, va1d, as2, ad2, bb1,
                                v2ss, v2dd, ccv, b12);

  k_bn_stats<<<625,256,0,stream>>>(x, wl1,wl2,wp1,wp2,wg, gsum, gsq);

  k_count  <<<666,256,0,stream>>>(ei, counts, gsum, gsq, sA, sB,
                                  gl1,gl2,gp1,gp2,gg, bel1,bel2,bep1,bep2,beg);
  k_scan   <<<1,1024,0,stream>>>(counts, offs);
  k_perm   <<<1,1024,0,stream>>>(counts, perm);
  k_scatter<<<665,256,0,stream>>>(ei, offs, cursor, srcl);

  const int gxm = (CN + 127)/128;     // MT=2: 128 rows/block
  const int gx2 = (CN + 127)/128;
  const int aggB = 1250*CB;
  for (int c = 0; c < nc; c++){
    const int base = c*CN;

    k_feat<<<gx2,256,0,stream>>>(x, wl1,wl2,wp1,wp2,wg, sA, sB, va1s, va1d,
                                 feat, featL, asrc1, adst1, base, CN);

    k_agg1<<<aggB,256,0,stream>>>(feat, asrc1, adst1, offs, srcl, perm, aggF,
                                  v2ss, v2dd, ccv, asrc2, adst2, cbMask, cbShift);

    k_mfma<2,9,0,9,3,0><<<gxm,256,0,stream>>>(aggF,288, (const u16*)0,0, W12T,288, h2,144, 0, b12, CN,
                                              (const float*)0,(const float*)0,(float*)0);

    k_agg2<<<aggB,256,0,stream>>>(h2,144, asrc2, adst2, offs, srcl, perm, bb2, g2l,160,
                                  cbMask, cbShift);

    k_mfma<2,5,5,9,2,0><<<gxm,256,0,stream>>>(g2l,160, featL,160, WoT,320, (u16*)0,0, 0, bo, CN,
                                              Wo2, bo2, (float*)d_out + base);
  }
}

// Round 16
// 478.354 us; speedup vs baseline: 1.8340x; 1.0018x over previous
//
#include <hip/hip_runtime.h>
#include <hip/hip_bf16.h>
#include <math.h>

typedef unsigned short u16;
typedef unsigned int   u32;
typedef short v8s __attribute__((ext_vector_type(8)));
typedef float v4f __attribute__((ext_vector_type(4)));
#define DEV static __device__ __forceinline__

DEV float u2f(u16 u){ union{u32 i; float f;} v; v.i = ((u32)u)<<16; return v.f; }
DEV u16   f2u(float f){ union{float ff; u32 i;} v; v.ff = f; u32 r = v.i + 0x7fffu + ((v.i>>16)&1u); return (u16)(r>>16); }
DEV float lrelu02(float x){ return x > 0.f ? x : 0.2f*x; }
DEV float lrelu01(float x){ return x > 0.f ? x : 0.01f*x; }
DEV float fast_tanh(float x){
  float cx = fminf(fmaxf(x, -15.f), 15.f);
  float e = __expf(2.f*cx);
  return (e - 1.f) * __builtin_amdgcn_rcpf(e + 1.f);
}
DEV float wred_sum(float v){
  #pragma unroll
  for (int o = 32; o > 0; o >>= 1) v += __shfl_xor(v, o, 64);
  return v;
}
DEV float wred_max32(float v){
  #pragma unroll
  for (int o = 16; o > 0; o >>= 1) v = fmaxf(v, __shfl_xor(v, o, 64));
  return v;
}
DEV float wred_sum32(float v){
  #pragma unroll
  for (int o = 16; o > 0; o >>= 1) v += __shfl_xor(v, o, 64);
  return v;
}

constexpr int B_   = 8;
constexpr int P_   = 32;
constexpr int N0_  = 10000;
constexpr int NODES = B_ * N0_;      // 80000
constexpr int E_   = 160000;
constexpr int NE_  = E_ + N0_;       // 170000

// ---------------- merged setup ----------------
__global__ void __launch_bounds__(256) k_setup(int* __restrict__ zbase,
    const float* __restrict__ Wo, u16* __restrict__ WoT,
    const float* __restrict__ W1, const float* __restrict__ W2, u16* __restrict__ W12T,
    const float* __restrict__ as1, const float* __restrict__ ad1,
    float* __restrict__ va1s, float* __restrict__ va1d,
    const float* __restrict__ as2, const float* __restrict__ ad2,
    const float* __restrict__ bb1,
    float* __restrict__ v2ss, float* __restrict__ v2dd,
    float* __restrict__ cc, float* __restrict__ b12)
{
  __shared__ float l2s[272], l2d[272];
  int blk = blockIdx.x, tid = threadIdx.x;
  if (blk < 79){ int i = blk*256 + tid; if (i < 20080) zbase[i] = 0; return; }
  blk -= 79;
  if (blk < 180){           // WoT[n][k] (144x320), head split
    int i = blk*256 + tid; if (i >= 144*320) return;
    int n = i/320, k = i - n*320; float v = 0.f;
    if (n < 136){
      if (k < 136) v = Wo[(size_t)k*136 + n];
      else if (k >= 160 && k < 296) v = Wo[(size_t)(k-24)*136 + n];
    }
    WoT[i] = f2u(v); return;
  }
  blk -= 180;
  if (blk < 162){           // W12T[n][kk] (144x288) = (W1@W2)^T per head-block
    int i = blk*256 + tid; if (i >= 144*288) return;
    int n = i/288, kk = i - n*288; float v = 0.f;
    if (n < 136 && kk < 272){
      int hh = kk/136, k = kk - hh*136;
      for (int c = 0; c < 136; c++)
        v = fmaf(W1[(size_t)k*272 + hh*136 + c], W2[(size_t)(hh*136+c)*136 + n], v);
    }
    W12T[i] = f2u(v); return;
  }
  blk -= 162;
  if (blk < 2){             // va1 = W1 a1 (272)
    int t = blk*256 + tid; if (t >= 272) return;
    int hh = t/136, k = t - hh*136; float s = 0.f, d = 0.f;
    for (int c = 0; c < 136; c++){
      float w = W1[(size_t)k*272 + hh*136 + c];
      s = fmaf(w, as1[hh*136+c], s);
      d = fmaf(w, ad1[hh*136+c], d);
    }
    va1s[t] = s; va1d[t] = d; return;
  }
  blk -= 2;
  {                         // v2'' = W1@(W2 a2); cc = bb1·(W2 a2); b12 = bb1@W2
    for (int m = tid; m < 272; m += 256){
      float vs = 0.f, vd = 0.f;
      for (int n2 = 0; n2 < 136; n2++){
        float w2 = W2[(size_t)m*136 + n2];
        vs = fmaf(w2, as2[n2], vs);
        vd = fmaf(w2, ad2[n2], vd);
      }
      l2s[m] = vs; l2d[m] = vd;
    }
    __syncthreads();
    int t0 = blk*256 + tid;
    if (t0 < 272){
      int hh = t0/136, k = t0 - hh*136; float s = 0.f, d = 0.f;
      for (int c = 0; c < 136; c++){
        float w = W1[(size_t)k*272 + hh*136 + c];
        s = fmaf(w, l2s[hh*136+c], s);
        d = fmaf(w, l2d[hh*136+c], d);
      }
      v2ss[t0] = s; v2dd[t0] = d;
    }
    if (blk == 1){
      if (tid < 64){
        float s = 0.f, d = 0.f;
        for (int m = tid; m < 272; m += 64){
          s = fmaf(bb1[m], l2s[m], s);
          d = fmaf(bb1[m], l2d[m], d);
        }
        s = wred_sum(s); d = wred_sum(d);
        if (tid == 0){ cc[0] = s; cc[1] = d; }
      } else if (tid < 200){
        int n2 = tid - 64; float v = 0.f;
        for (int m = 0; m < 272; m++) v = fmaf(bb1[m], W2[(size_t)m*136 + n2], v);
        b12[n2] = v;
      }
    }
  }
}

// ---------------- backbone ----------------
DEV void load_convw(float* lw, const float* wl1, const float* wl2, const float* wp1,
                    const float* wp2, const float* wg, int tid, int nth){
  for (int i = tid; i < 384; i += nth){
    float v;
    if      (i < 24)  v = wl1[i];
    else if (i < 64)  v = wl2[i-24];
    else if (i < 88)  v = wp1[i-64];
    else if (i < 128) v = wp2[i-88];
    else              v = wg [i-128];
    lw[i] = v;
  }
}

template<int KS,int DIL,int T>
DEV void conv_stats(const float* xc, const float* wk, float& s, float& q){
  #pragma unroll
  for (int t = 0; t < T; t++){
    float v = 0.f;
    #pragma unroll
    for (int j = 0; j < KS; j++) v = fmaf(wk[j], xc[t + j*DIL], v);
    s += v; q = fmaf(v, v, q);
  }
}

__global__ void __launch_bounds__(256) k_bn_stats(
    const float* __restrict__ x,
    const float* __restrict__ wl1, const float* __restrict__ wl2,
    const float* __restrict__ wp1, const float* __restrict__ wp2,
    const float* __restrict__ wg,
    float* __restrict__ gsum, float* __restrict__ gsq)
{
  __shared__ float lw[384];
  __shared__ float lacc[80];
  const int tid = threadIdx.x;
  load_convw(lw, wl1, wl2, wp1, wp2, wg, tid, 256);
  if (tid < 80) lacc[tid] = 0.f;
  __syncthreads();

  const int lane = tid & 63, wv = tid >> 6;
  const int nodeLocal = (wv >> 1)*64 + lane;
  const int half = wv & 1;
  const int gid = blockIdx.x*128 + nodeLocal;
  float xc[P_];
  if (gid < NODES){
    int b = gid / N0_, n = gid - b*N0_;
    const float* xp = x + (size_t)b*P_*N0_ + n;
    #pragma unroll
    for (int p = 0; p < P_; p++) xc[p] = xp[(size_t)p*N0_];
  } else {
    #pragma unroll
    for (int p = 0; p < P_; p++) xc[p] = 0.f;
  }

  auto red = [&](int ch, float s, float q){
    #pragma unroll
    for (int o = 32; o > 0; o >>= 1){ s += __shfl_down(s,o,64); q += __shfl_down(q,o,64); }
    if (lane == 0){ atomicAdd(&lacc[ch], s); atomicAdd(&lacc[40+ch], q); }
  };

  if (half == 0){
    #pragma unroll
    for (int k = 0; k < 8; k++){ float s=0,q=0; conv_stats<3,1,30>(xc, lw      + k*3 , s,q); red(k,     s,q); }
    #pragma unroll
    for (int k = 0; k < 8; k++){ float s=0,q=0; conv_stats<5,1,28>(xc, lw + 24 + k*5 , s,q); red(8+k,   s,q); }
  } else {
    #pragma unroll
    for (int k = 0; k < 8; k++){ float s=0,q=0; conv_stats<3,2,28>(xc, lw + 64 + k*3 , s,q); red(16+k,  s,q); }
    #pragma unroll
    for (int k = 0; k < 8; k++){ float s=0,q=0; conv_stats<5,2,24>(xc, lw + 88 + k*5 , s,q); red(24+k,  s,q); }
    #pragma unroll
    for (int k = 0; k < 8; k++){ float s=0,q=0; conv_stats<32,1,1>(xc, lw + 128+ k*32, s,q); red(32+k,  s,q); }
  }

  __syncthreads();
  if (tid < 40)      atomicAdd(&gsum[tid],    lacc[tid]);
  else if (tid < 80) atomicAdd(&gsq [tid-40], lacc[tid]);
}

// count kernel with bn_fin folded in as the last block
__global__ void k_count(const int* __restrict__ ei, int* __restrict__ counts,
                        const float* __restrict__ gsum, const float* __restrict__ gsq,
                        float* __restrict__ sA, float* __restrict__ sB,
                        const float* g0, const float* g1, const float* g2, const float* g3, const float* g4,
                        const float* e0, const float* e1, const float* e2, const float* e3, const float* e4){
  if (blockIdx.x == 665){
    int t = threadIdx.x;
    if (t >= 40) return;
    int bi = t >> 3, k = t & 7;
    const int Ts[5] = {30,28,28,24,1};
    float cnt  = (float)NODES * (float)Ts[bi];
    float mean = gsum[t] / cnt;
    float var  = gsq[t] / cnt - mean*mean;
    const float* gp = bi==0?g0: bi==1?g1: bi==2?g2: bi==3?g3: g4;
    const float* ep = bi==0?e0: bi==1?e1: bi==2?e2: bi==3?e3: e4;
    float a = gp[k] * rsqrtf(fmaxf(var, 0.f) + 1e-5f);
    sA[t] = a;
    sB[t] = ep[k] - a*mean;
    return;
  }
  int e = blockIdx.x*blockDim.x + threadIdx.x;
  if (e >= NE_) return;
  int dst = (e < E_) ? ei[E_ + e] : (e - E_);
  atomicAdd(&counts[dst], 1);
}

__global__ void __launch_bounds__(1024) k_scan(const int* __restrict__ counts, int* __restrict__ offs){
  __shared__ int part[1024];
  int t = threadIdx.x;
  int loc[10]; int s = 0;
  #pragma unroll
  for (int i = 0; i < 10; i++){
    int idx = t*10 + i;
    int c = (idx < N0_) ? counts[idx] : 0;
    loc[i] = s; s += c;
  }
  part[t] = s;
  __syncthreads();
  for (int o = 1; o < 1024; o <<= 1){
    int v = (t >= o) ? part[t-o] : 0;
    __syncthreads();
    part[t] += v;
    __syncthreads();
  }
  int pre = (t == 0) ? 0 : part[t-1];
  #pragma unroll
  for (int i = 0; i < 10; i++){
    int idx = t*10 + i;
    if (idx < N0_) offs[idx] = pre + loc[i];
  }
  if (t == 0) offs[N0_] = part[1023];
}

// degree-sorted permutation (counting sort by degree, one block)
__global__ void __launch_bounds__(1024) k_perm(const int* __restrict__ counts, int* __restrict__ perm){
  __shared__ int hist[129];
  __shared__ int base[129];
  int t = threadIdx.x;
  if (t < 129) hist[t] = 0;
  __syncthreads();
  int dloc[10];
  #pragma unroll
  for (int i = 0; i < 10; i++){
    int idx = t*10 + i;
    if (idx < N0_){
      int d = min(counts[idx], 128);
      dloc[i] = d;
      atomicAdd(&hist[d], 1);
    }
  }
  __syncthreads();
  if (t == 0){
    int s = 0;
    for (int b = 0; b <= 128; b++){ base[b] = s; s += hist[b]; }
  }
  __syncthreads();
  #pragma unroll
  for (int i = 0; i < 10; i++){
    int idx = t*10 + i;
    if (idx < N0_){
      int pos = atomicAdd(&base[dloc[i]], 1);
      perm[pos] = idx;
    }
  }
}

__global__ void k_scatter(const int* __restrict__ ei, const int* __restrict__ offs,
                          int* __restrict__ cursor, int* __restrict__ srcl){
  int e = blockIdx.x*blockDim.x + threadIdx.x;
  if (e >= NE_) return;
  int src, dst;
  if (e < E_){ src = ei[e]; dst = ei[E_ + e]; } else { src = dst = e - E_; }
  int pos = atomicAdd(&cursor[dst], 1);
  srcl[offs[dst] + pos] = src;
}

template<int KS,int DIL,int T>
DEV void conv_pool4(const float* xc, const float* wk, float A, float Bc, float* o4){
  float y[T];
  #pragma unroll
  for (int t = 0; t < T; t++){
    float v = 0.f;
    #pragma unroll
    for (int j = 0; j < KS; j++) v = fmaf(wk[j], xc[t + j*DIL], v);
    y[t] = fmaf(A, v, Bc);
  }
  #pragma unroll
  for (int i = 0; i < 4; i++){
    const int lo = (i*T)/4, hi = ((i+1)*T + 3)/4;
    float m = y[lo];
    #pragma unroll
    for (int t = 0; t < T; t++){ if (t > lo && t < hi) m = fmaxf(m, y[t]); }
    o4[i] = m;
  }
}

// feat [m][160] bf16 (tanh) + featL (lrelu01) + fused layer-1 attention dots (float4 LDS)
__global__ void __launch_bounds__(256) k_feat(
    const float* __restrict__ x,
    const float* __restrict__ wl1, const float* __restrict__ wl2,
    const float* __restrict__ wp1, const float* __restrict__ wp2,
    const float* __restrict__ wg,
    const float* __restrict__ sA, const float* __restrict__ sB,
    const float* __restrict__ va1s, const float* __restrict__ va1d,
    u16* __restrict__ feat, u16* __restrict__ featL,
    float* __restrict__ asrc1, float* __restrict__ adst1,
    int base, int m)
{
  __shared__ float lw[384];
  __shared__ float lA[40], lB[40];
  __shared__ float4 lv4[136];
  __shared__ float sdt[128][4];
  const int tid = threadIdx.x;
  load_convw(lw, wl1, wl2, wp1, wp2, wg, tid, 256);
  if (tid < 40){ lA[tid] = sA[tid]; lB[tid] = sB[tid]; }
  for (int i = tid; i < 136; i += 256)
    lv4[i] = make_float4(va1s[i], va1d[i], va1s[136+i], va1d[136+i]);
  __syncthreads();

  const int lane = tid & 63, wv = tid >> 6;
  const int nodeLocal = (wv >> 1)*64 + lane;     // 0..127
  const int half = wv & 1;                       // wave-uniform
  const int nodeIdx = blockIdx.x*128 + nodeLocal;
  const bool act = nodeIdx < m;
  const int gcl = base + (act ? nodeIdx : (m-1));
  int b = gcl / N0_, n = gcl - b*N0_;
  float xc[P_];
  const float* xp = x + (size_t)b*P_*N0_ + n;
  #pragma unroll
  for (int p = 0; p < P_; p++) xc[p] = xp[(size_t)p*N0_];

  float dt[4] = {0.f,0.f,0.f,0.f};
  u32 pk[4], pkl[4];
  u16* orow  = feat  + (size_t)nodeIdx*160;
  u16* olrow = featL + (size_t)nodeIdx*160;
  auto emit = [&](int ch, float v){
    float t = fast_tanh(v);
    float4 vv = lv4[ch];
    dt[0] = fmaf(t, vv.x, dt[0]);
    dt[1] = fmaf(t, vv.y, dt[1]);
    dt[2] = fmaf(t, vv.z, dt[2]);
    dt[3] = fmaf(t, vv.w, dt[3]);
    u16 h  = f2u(t);
    u16 hl = f2u(lrelu01(t));
    int s = ch & 7;
    if ((s & 1) == 0){ pk[s>>1] = h;                pkl[s>>1] = hl; }
    else             { pk[s>>1] |= ((u32)h) << 16;  pkl[s>>1] |= ((u32)hl) << 16; }
    if (s == 7 && act){
      *(uint4*)(orow  + (ch - 7)) = make_uint4(pk[0],pk[1],pk[2],pk[3]);
      *(uint4*)(olrow + (ch - 7)) = make_uint4(pkl[0],pkl[1],pkl[2],pkl[3]);
    }
  };

  float o4[4];
  if (half == 0){
    #pragma unroll
    for (int k = 0; k < 8; k++){
      conv_pool4<3,1,30>(xc, lw + k*3, lA[k], lB[k], o4);
      #pragma unroll
      for (int i = 0; i < 4; i++) emit(k*4+i, o4[i]);
    }
    #pragma unroll
    for (int k = 0; k < 8; k++){
      conv_pool4<5,1,28>(xc, lw + 24 + k*5, lA[8+k], lB[8+k], o4);
      #pragma unroll
      for (int i = 0; i < 4; i++) emit(32 + k*4+i, o4[i]);
    }
  } else {
    #pragma unroll
    for (int k = 0; k < 8; k++){
      conv_pool4<3,2,28>(xc, lw + 64 + k*3, lA[16+k], lB[16+k], o4);
      #pragma unroll
      for (int i = 0; i < 4; i++) emit(64 + k*4+i, o4[i]);
    }
    #pragma unroll
    for (int k = 0; k < 8; k++){
      conv_pool4<5,2,24>(xc, lw + 88 + k*5, lA[24+k], lB[24+k], o4);
      #pragma unroll
      for (int i = 0; i < 4; i++) emit(96 + k*4+i, o4[i]);
    }
    #pragma unroll
    for (int k = 0; k < 8; k++){
      float v = 0.f;
      #pragma unroll
      for (int j = 0; j < 32; j++) v = fmaf(lw[128 + k*32 + j], xc[j], v);
      emit(128 + k, fmaf(lA[32+k], v, lB[32+k]));
    }
  }

  if (half == 1){
    sdt[nodeLocal][0] = dt[0]; sdt[nodeLocal][1] = dt[1];
    sdt[nodeLocal][2] = dt[2]; sdt[nodeLocal][3] = dt[3];
  }
  __syncthreads();
  if (half == 0 && act){
    asrc1[(size_t)nodeIdx*2]   = dt[0] + sdt[nodeLocal][0];
    asrc1[(size_t)nodeIdx*2+1] = dt[2] + sdt[nodeLocal][2];
    adst1[(size_t)nodeIdx*2]   = dt[1] + sdt[nodeLocal][1];
    adst1[(size_t)nodeIdx*2+1] = dt[3] + sdt[nodeLocal][3];
  }
}

// ---------------- MFMA GEMM: MT m-tiles (16 rows each) per wave ----------------
template<int MT,int KT1,int KT2,int NT,int EPI,int LR2>
__global__ void __launch_bounds__(256) k_mfma(
    const u16* __restrict__ A1, int sA1,
    const u16* __restrict__ A2, int sA2,
    const u16* __restrict__ BT, int sBT,
    u16* __restrict__ C, int sC, int nbase,
    const float* __restrict__ bias, int m,
    const float* __restrict__ w2v, const float* __restrict__ bo2p, float* __restrict__ fout)
{
  const int wv = threadIdx.x >> 6, lane = threadIdx.x & 63;
  const int quad = lane >> 4, l15 = lane & 15;
  const int mb = blockIdx.x*(MT*64) + wv*(MT*16);
  int ar[MT];
  #pragma unroll
  for (int mt = 0; mt < MT; mt++) ar[mt] = min(mb + mt*16 + l15, m-1);

  v4f acc[MT][NT];
  #pragma unroll
  for (int mt = 0; mt < MT; mt++)
    #pragma unroll
    for (int nt = 0; nt < NT; nt++)
      acc[mt][nt] = (v4f){0.f,0.f,0.f,0.f};

  for (int kt = 0; kt < KT1+KT2; kt++){
    const u16* ab; int sA, koff;
    if (KT2 == 0 || kt < KT1){ ab = A1; sA = sA1; koff = kt*32; }
    else { ab = A2; sA = sA2; koff = (kt-KT1)*32; }
    v8s a[MT];
    #pragma unroll
    for (int mt = 0; mt < MT; mt++)
      a[mt] = *(const v8s*)(ab + (size_t)ar[mt]*sA + koff + quad*8);
    if (KT2 > 0 && LR2 && kt >= KT1){
      #pragma unroll
      for (int mt = 0; mt < MT; mt++)
        #pragma unroll
        for (int j = 0; j < 8; j++){
          float f = u2f((u16)a[mt][j]);
          f = f > 0.f ? f : 0.01f*f;
          a[mt][j] = (short)f2u(f);
        }
    }
    const int kb = kt*32 + quad*8;
    #pragma unroll
    for (int nt = 0; nt < NT; nt++){
      v8s b = *(const v8s*)(BT + (size_t)(nbase + nt*16 + l15)*sBT + kb);
      #pragma unroll
      for (int mt = 0; mt < MT; mt++)
        acc[mt][nt] = __builtin_amdgcn_mfma_f32_16x16x32_bf16(a[mt], b, acc[mt][nt], 0, 0, 0);
    }
  }

  if (EPI == 2){
    const float bo2v = bo2p[0];
    #pragma unroll
    for (int mt = 0; mt < MT; mt++){
      float part[4] = {0.f,0.f,0.f,0.f};
      #pragma unroll
      for (int nt = 0; nt < NT; nt++){
        const int col = nt*16 + l15;
        float wv2 = (col < 136) ? w2v[col] : 0.f;
        float bv  = bias[min(col,135)];
        #pragma unroll
        for (int i = 0; i < 4; i++){
          float xv = lrelu01(acc[mt][nt][i] + bv);
          part[i] = fmaf(xv, wv2, part[i]);
        }
      }
      #pragma unroll
      for (int i = 0; i < 4; i++){
        float v = part[i];
        v += __shfl_xor(v, 1, 64);
        v += __shfl_xor(v, 2, 64);
        v += __shfl_xor(v, 4, 64);
        v += __shfl_xor(v, 8, 64);
        int r = mb + mt*16 + quad*4 + i;
        if (l15 == 0 && r < m) fout[r] = v + bo2v;
      }
    }
    return;
  }

  #pragma unroll
  for (int mt = 0; mt < MT; mt++){
    const int r0 = mb + mt*16 + quad*4;
    #pragma unroll
    for (int nt = 0; nt < NT; nt++){
      const int col = nbase + nt*16 + l15;
      #pragma unroll
      for (int i = 0; i < 4; i++){
        int r = r0 + i;
        if (r < m){
          float xv = acc[mt][nt][i];
          if (EPI == 1){ xv += bias[min(col,135)]; xv = lrelu01(xv); }
          if (EPI == 3){ xv += bias[min(col,135)]; }
          C[(size_t)r*sC + col] = f2u(xv);
        }
      }
    }
  }
}

// ---------------- layer-1 GAT aggregation: two degree-paired dst per wave, unroll-4 ----------------
__global__ void __launch_bounds__(256) k_agg1(const u16* __restrict__ feat,
    const float* __restrict__ asrc, const float* __restrict__ adst,
    const int* __restrict__ offs, const int* __restrict__ srcl,
    const int* __restrict__ perm,
    u16* __restrict__ aggF,
    const float* __restrict__ v2s, const float* __restrict__ v2d,
    const float* __restrict__ cc,
    float* __restrict__ as_out, float* __restrict__ ad_out,
    int cbMask, int cbShift)
{
  const int tid = threadIdx.x;
  const int wv = tid >> 6, lane = tid & 63;
  const int half = lane >> 5, l32 = lane & 31;
  const int hbase = lane & 32;
  const int id = blockIdx.x;
  const int bb = id & cbMask;
  const int q = (id >> cbShift)*4 + wv;       // pair index
  const int dst = perm[2*q + half];
  const int nbase = bb*N0_;
  const int node = nbase + dst;
  const int start = offs[dst], end = offs[dst+1];
  const int ne = end - start;

  const float ad0 = adst[(size_t)node*2], ad1v = adst[(size_t)node*2+1];
  const char* featB = (const char*)feat;

  float m0h0=0,m1h0=0,m2h0=0,m3h0=0;
  float m0h1=0,m1h1=0,m2h1=0,m3h1=0;
  float r0h0=0,r1h0=0,r0h1=0,r1h1=0;

  auto acc_edge = [&](int off, float c0, float c1){
    const u16* fp = (const u16*)(featB + off);
    const ushort4 hv = *(const ushort4*)(fp + 4*l32);
    float f0=u2f(hv.x), f1=u2f(hv.y), f2=u2f(hv.z), f3=u2f(hv.w);
    m0h0=fmaf(c0,f0,m0h0); m1h0=fmaf(c0,f1,m1h0); m2h0=fmaf(c0,f2,m2h0); m3h0=fmaf(c0,f3,m3h0);
    m0h1=fmaf(c1,f0,m0h1); m1h1=fmaf(c1,f1,m1h1); m2h1=fmaf(c1,f2,m2h1); m3h1=fmaf(c1,f3,m3h1);
    if (l32 < 4){
      const ushort2 hr = *(const ushort2*)(fp + 128 + 2*l32);
      float g0=u2f(hr.x), g1=u2f(hr.y);
      r0h0=fmaf(c0,g0,r0h0); r1h0=fmaf(c0,g1,r1h0);
      r0h1=fmaf(c1,g0,r0h1); r1h1=fmaf(c1,g1,r1h1);
    }
  };
  auto acc_edge4 = [&](int o0, int o1, int o2, int o3,
                       float a0, float a1, float a2, float a3,
                       float b0, float b1, float b2, float b3){
    const u16* p0 = (const u16*)(featB + o0);
    const u16* p1 = (const u16*)(featB + o1);
    const u16* p2 = (const u16*)(featB + o2);
    const u16* p3 = (const u16*)(featB + o3);
    const ushort4 v0 = *(const ushort4*)(p0 + 4*l32);
    const ushort4 v1 = *(const ushort4*)(p1 + 4*l32);
    const ushort4 v2 = *(const ushort4*)(p2 + 4*l32);
    const ushort4 v3 = *(const ushort4*)(p3 + 4*l32);
    ushort2 q0, q1, q2, q3;
    if (l32 < 4){
      q0 = *(const ushort2*)(p0 + 128 + 2*l32);
      q1 = *(const ushort2*)(p1 + 128 + 2*l32);
      q2 = *(const ushort2*)(p2 + 128 + 2*l32);
      q3 = *(const ushort2*)(p3 + 128 + 2*l32);
    }
    float f;
    f=u2f(v0.x); m0h0=fmaf(a0,f,m0h0); m0h1=fmaf(b0,f,m0h1);
    f=u2f(v0.y); m1h0=fmaf(a0,f,m1h0); m1h1=fmaf(b0,f,m1h1);
    f=u2f(v0.z); m2h0=fmaf(a0,f,m2h0); m2h1=fmaf(b0,f,m2h1);
    f=u2f(v0.w); m3h0=fmaf(a0,f,m3h0); m3h1=fmaf(b0,f,m3h1);
    f=u2f(v1.x); m0h0=fmaf(a1,f,m0h0); m0h1=fmaf(b1,f,m0h1);
    f=u2f(v1.y); m1h0=fmaf(a1,f,m1h0); m1h1=fmaf(b1,f,m1h1);
    f=u2f(v1.z); m2h0=fmaf(a1,f,m2h0); m2h1=fmaf(b1,f,m2h1);
    f=u2f(v1.w); m3h0=fmaf(a1,f,m3h0); m3h1=fmaf(b1,f,m3h1);
    f=u2f(v2.x); m0h0=fmaf(a2,f,m0h0); m0h1=fmaf(b2,f,m0h1);
    f=u2f(v2.y); m1h0=fmaf(a2,f,m1h0); m1h1=fmaf(b2,f,m1h1);
    f=u2f(v2.z); m2h0=fmaf(a2,f,m2h0); m2h1=fmaf(b2,f,m2h1);
    f=u2f(v2.w); m3h0=fmaf(a2,f,m3h0); m3h1=fmaf(b2,f,m3h1);
    f=u2f(v3.x); m0h0=fmaf(a3,f,m0h0); m0h1=fmaf(b3,f,m0h1);
    f=u2f(v3.y); m1h0=fmaf(a3,f,m1h0); m1h1=fmaf(b3,f,m1h1);
    f=u2f(v3.z); m2h0=fmaf(a3,f,m2h0); m2h1=fmaf(b3,f,m2h1);
    f=u2f(v3.w); m3h0=fmaf(a3,f,m3h0); m3h1=fmaf(b3,f,m3h1);
    if (l32 < 4){
      f=u2f(q0.x); r0h0=fmaf(a0,f,r0h0); r0h1=fmaf(b0,f,r0h1);
      f=u2f(q0.y); r1h0=fmaf(a0,f,r1h0); r1h1=fmaf(b0,f,r1h1);
      f=u2f(q1.x); r0h0=fmaf(a1,f,r0h0); r0h1=fmaf(b1,f,r0h1);
      f=u2f(q1.y); r1h0=fmaf(a1,f,r1h0); r1h1=fmaf(b1,f,r1h1);
      f=u2f(q2.x); r0h0=fmaf(a2,f,r0h0); r0h1=fmaf(b2,f,r0h1);
      f=u2f(q2.y); r1h0=fmaf(a2,f,r1h0); r1h1=fmaf(b2,f,r1h1);
      f=u2f(q3.x); r0h0=fmaf(a3,f,r0h0); r0h1=fmaf(b3,f,r0h1);
      f=u2f(q3.y); r1h0=fmaf(a3,f,r1h0); r1h1=fmaf(b3,f,r1h1);
    }
  };

  if (ne <= 32){
    const bool has = l32 < ne;
    const int sn = nbase + (has ? srcl[start + l32] : 0);
    const int offL = sn * 320;
    float al0 = has ? lrelu02(asrc[(size_t)sn*2]   + ad0)  : -1e30f;
    float al1 = has ? lrelu02(asrc[(size_t)sn*2+1] + ad1v) : -1e30f;
    float mm = wred_max32(al0);
    float p0 = has ? __expf(al0 - mm) : 0.f;
    float c0 = p0 * (1.f/(wred_sum32(p0) + 1e-16f));
    mm = wred_max32(al1);
    float p1 = has ? __expf(al1 - mm) : 0.f;
    float c1 = p1 * (1.f/(wred_sum32(p1) + 1e-16f));
    int j = 0;
    for (; j + 3 < ne; j += 4){
      int   o0 = __shfl(offL, hbase + j,     64), o1 = __shfl(offL, hbase + j + 1, 64);
      int   o2 = __shfl(offL, hbase + j + 2, 64), o3 = __shfl(offL, hbase + j + 3, 64);
      float a0 = __shfl(c0, hbase + j,     64),   a1 = __shfl(c0, hbase + j + 1, 64);
      float a2 = __shfl(c0, hbase + j + 2, 64),   a3 = __shfl(c0, hbase + j + 3, 64);
      float b0 = __shfl(c1, hbase + j,     64),   b1 = __shfl(c1, hbase + j + 1, 64);
      float b2 = __shfl(c1, hbase + j + 2, 64),   b3 = __shfl(c1, hbase + j + 3, 64);
      acc_edge4(o0,o1,o2,o3, a0,a1,a2,a3, b0,b1,b2,b3);
    }
    for (; j < ne; j++)
      acc_edge(__shfl(offL, hbase + j, 64), __shfl(c0, hbase + j, 64), __shfl(c1, hbase + j, 64));
  } else {
    float lm0 = -1e30f, lm1 = -1e30f;
    for (int e = start + l32; e < end; e += 32){
      int sn = nbase + srcl[e];
      lm0 = fmaxf(lm0, lrelu02(asrc[(size_t)sn*2]   + ad0));
      lm1 = fmaxf(lm1, lrelu02(asrc[(size_t)sn*2+1] + ad1v));
    }
    float m0 = wred_max32(lm0), m1 = wred_max32(lm1);
    float ls0 = 0.f, ls1 = 0.f;
    for (int e = start + l32; e < end; e += 32){
      int sn = nbase + srcl[e];
      ls0 += __expf(lrelu02(asrc[(size_t)sn*2]   + ad0)  - m0);
      ls1 += __expf(lrelu02(asrc[(size_t)sn*2+1] + ad1v) - m1);
    }
    float si0 = 1.f/(wred_sum32(ls0) + 1e-16f);
    float si1 = 1.f/(wred_sum32(ls1) + 1e-16f);
    for (int cs = start; cs < end; cs += 32){
      int cnt = min(32, end - cs);
      bool has = l32 < cnt;
      int sn = nbase + (has ? srcl[cs + l32] : 0);
      int offL = sn * 320;
      float c0 = 0.f, c1 = 0.f;
      if (has){
        c0 = __expf(lrelu02(asrc[(size_t)sn*2]   + ad0)  - m0) * si0;
        c1 = __expf(lrelu02(asrc[(size_t)sn*2+1] + ad1v) - m1) * si1;
      }
      for (int j = 0; j < cnt; j++)
        acc_edge(__shfl(offL, hbase + j, 64), __shfl(c0, hbase + j, 64), __shfl(c1, hbase + j, 64));
    }
  }

  u16* outp = aggF + (size_t)node*288;
  {
    ushort4 s0; s0.x=f2u(m0h0); s0.y=f2u(m1h0); s0.z=f2u(m2h0); s0.w=f2u(m3h0);
    *(ushort4*)(outp + 4*l32) = s0;
    ushort4 s1; s1.x=f2u(m0h1); s1.y=f2u(m1h1); s1.z=f2u(m2h1); s1.w=f2u(m3h1);
    *(ushort4*)(outp + 136 + 4*l32) = s1;
    if (l32 < 4){
      ushort2 t0; t0.x=f2u(r0h0); t0.y=f2u(r1h0);
      *(ushort2*)(outp + 128 + 2*l32) = t0;
      ushort2 t1; t1.x=f2u(r0h1); t1.y=f2u(r1h1);
      *(ushort2*)(outp + 136 + 128 + 2*l32) = t1;
    }
  }
  {
    int c = 4*l32;
    float s = m0h0*v2s[c] + m1h0*v2s[c+1] + m2h0*v2s[c+2] + m3h0*v2s[c+3]
            + m0h1*v2s[136+c] + m1h1*v2s[136+c+1] + m2h1*v2s[136+c+2] + m3h1*v2s[136+c+3];
    float d = m0h0*v2d[c] + m1h0*v2d[c+1] + m2h0*v2d[c+2] + m3h0*v2d[c+3]
            + m0h1*v2d[136+c] + m1h1*v2d[136+c+1] + m2h1*v2d[136+c+2] + m3h1*v2d[136+c+3];
    if (l32 < 4){
      int cr = 128 + 2*l32;
      s += r0h0*v2s[cr] + r1h0*v2s[cr+1] + r0h1*v2s[136+cr] + r1h1*v2s[136+cr+1];
      d += r0h0*v2d[cr] + r1h0*v2d[cr+1] + r0h1*v2d[136+cr] + r1h1*v2d[136+cr+1];
    }
    s = wred_sum32(s); d = wred_sum32(d);
    if (l32 == 0){ as_out[node] = s + cc[0]; ad_out[node] = d + cc[1]; }
  }
}

// ---------------- layer-2 GAT aggregation (H=1): two degree-paired dst per wave, unroll-4 ----------------
__global__ void __launch_bounds__(256) k_agg2(const u16* __restrict__ h, int sh,
    const float* __restrict__ asrc, const float* __restrict__ adst,
    const int* __restrict__ offs, const int* __restrict__ srcl,
    const int* __restrict__ perm,
    const float* __restrict__ bias, u16* __restrict__ outp0, int so,
    int cbMask, int cbShift)
{
  const int tid = threadIdx.x;
  const int wv = tid >> 6, lane = tid & 63;
  const int half = lane >> 5, l32 = lane & 31;
  const int hbase = lane & 32;
  const int id = blockIdx.x;
  const int bb = id & cbMask;
  const int q = (id >> cbShift)*4 + wv;
  const int dst = perm[2*q + half];
  const int nbase = bb*N0_;
  const int node = nbase + dst;
  const int start = offs[dst], end = offs[dst+1];
  const int ne = end - start;
  const int bstride = 2*sh;

  const float adh = adst[node];
  const char* hB = (const char*)h;

  float a0=0, a1=0, a2=0, a3=0, rr0=0, rr1=0;

  auto acc_edge = [&](int off, float c0){
    const u16* hp = (const u16*)(hB + off);
    const ushort4 hv = *(const ushort4*)(hp + 4*l32);
    a0 = fmaf(c0, u2f(hv.x), a0); a1 = fmaf(c0, u2f(hv.y), a1);
    a2 = fmaf(c0, u2f(hv.z), a2); a3 = fmaf(c0, u2f(hv.w), a3);
    if (l32 < 4){
      const ushort2 hr = *(const ushort2*)(hp + 128 + 2*l32);
      rr0 = fmaf(c0, u2f(hr.x), rr0);
      rr1 = fmaf(c0, u2f(hr.y), rr1);
    }
  };
  auto acc_edge4 = [&](int o0, int o1, int o2, int o3,
                       float c0, float c1, float c2, float c3){
    const u16* p0 = (const u16*)(hB + o0);
    const u16* p1 = (const u16*)(hB + o1);
    const u16* p2 = (const u16*)(hB + o2);
    const u16* p3 = (const u16*)(hB + o3);
    const ushort4 v0 = *(const ushort4*)(p0 + 4*l32);
    const ushort4 v1 = *(const ushort4*)(p1 + 4*l32);
    const ushort4 v2 = *(const ushort4*)(p2 + 4*l32);
    const ushort4 v3 = *(const ushort4*)(p3 + 4*l32);
    ushort2 q0, q1, q2, q3;
    if (l32 < 4){
      q0 = *(const ushort2*)(p0 + 128 + 2*l32);
      q1 = *(const ushort2*)(p1 + 128 + 2*l32);
      q2 = *(const ushort2*)(p2 + 128 + 2*l32);
      q3 = *(const ushort2*)(p3 + 128 + 2*l32);
    }
    a0 = fmaf(c0, u2f(v0.x), a0); a1 = fmaf(c0, u2f(v0.y), a1);
    a2 = fmaf(c0, u2f(v0.z), a2); a3 = fmaf(c0, u2f(v0.w), a3);
    a0 = fmaf(c1, u2f(v1.x), a0); a1 = fmaf(c1, u2f(v1.y), a1);
    a2 = fmaf(c1, u2f(v1.z), a2); a3 = fmaf(c1, u2f(v1.w), a3);
    a0 = fmaf(c2, u2f(v2.x), a0); a1 = fmaf(c2, u2f(v2.y), a1);
    a2 = fmaf(c2, u2f(v2.z), a2); a3 = fmaf(c2, u2f(v2.w), a3);
    a0 = fmaf(c3, u2f(v3.x), a0); a1 = fmaf(c3, u2f(v3.y), a1);
    a2 = fmaf(c3, u2f(v3.z), a2); a3 = fmaf(c3, u2f(v3.w), a3);
    if (l32 < 4){
      rr0 = fmaf(c0, u2f(q0.x), rr0); rr1 = fmaf(c0, u2f(q0.y), rr1);
      rr0 = fmaf(c1, u2f(q1.x), rr0); rr1 = fmaf(c1, u2f(q1.y), rr1);
      rr0 = fmaf(c2, u2f(q2.x), rr0); rr1 = fmaf(c2, u2f(q2.y), rr1);
      rr0 = fmaf(c3, u2f(q3.x), rr0); rr1 = fmaf(c3, u2f(q3.y), rr1);
    }
  };

  if (ne <= 32){
    const bool has = l32 < ne;
    const int sn = nbase + (has ? srcl[start + l32] : 0);
    const int offL = sn * bstride;
    float al = has ? lrelu02(asrc[sn] + adh) : -1e30f;
    float m = wred_max32(al);
    float p = has ? __expf(al - m) : 0.f;
    float c0 = p * (1.f/(wred_sum32(p) + 1e-16f));
    int j = 0;
    for (; j + 3 < ne; j += 4){
      int   o0 = __shfl(offL, hbase + j,     64), o1 = __shfl(offL, hbase + j + 1, 64);
      int   o2 = __shfl(offL, hbase + j + 2, 64), o3 = __shfl(offL, hbase + j + 3, 64);
      float e0 = __shfl(c0, hbase + j,     64),   e1 = __shfl(c0, hbase + j + 1, 64);
      float e2 = __shfl(c0, hbase + j + 2, 64),   e3 = __shfl(c0, hbase + j + 3, 64);
      acc_edge4(o0, o1, o2, o3, e0, e1, e2, e3);
    }
    for (; j < ne; j++)
      acc_edge(__shfl(offL, hbase + j, 64), __shfl(c0, hbase + j, 64));
  } else {
    float lm = -1e30f;
    for (int e = start + l32; e < end; e += 32){
      int sn = nbase + srcl[e];
      lm = fmaxf(lm, lrelu02(asrc[sn] + adh));
    }
    float m = wred_max32(lm);
    float ls = 0.f;
    for (int e = start + l32; e < end; e += 32){
      int sn = nbase + srcl[e];
      ls += __expf(lrelu02(asrc[sn] + adh) - m);
    }
    float si = 1.f/(wred_sum32(ls) + 1e-16f);
    for (int cs = start; cs < end; cs += 32){
      int cnt = min(32, end - cs);
      bool has = l32 < cnt;
      int sn = nbase + (has ? srcl[cs + l32] : 0);
      int offL = sn * bstride;
      float c0 = has ? __expf(lrelu02(asrc[sn] + adh) - m) * si : 0.f;
      for (int j = 0; j < cnt; j++)
        acc_edge(__shfl(offL, hbase + j, 64), __shfl(c0, hbase + j, 64));
    }
  }

  u16* outp = outp0 + (size_t)node*so;
  {
    int c = 4*l32;
    ushort4 st;
    st.x = f2u(lrelu01(a0 + bias[c]));
    st.y = f2u(lrelu01(a1 + bias[c+1]));
    st.z = f2u(lrelu01(a2 + bias[c+2]));
    st.w = f2u(lrelu01(a3 + bias[c+3]));
    *(ushort4*)(outp + c) = st;
    if (l32 < 4){
      int cr = 128 + 2*l32;
      ushort2 sr;
      sr.x = f2u(lrelu01(rr0 + bias[cr]));
      sr.y = f2u(lrelu01(rr1 + bias[cr+1]));
      *(ushort2*)(outp + cr) = sr;
    }
  }
}

// ---------------- launch ----------------
extern "C" void kernel_launch(void* const* d_in, const int* in_sizes, int n_in,
                              void* d_out, int out_size, void* d_ws, size_t ws_size,
                              hipStream_t stream)
{
  (void)in_sizes; (void)n_in; (void)out_size;
  const float* x    = (const float*)d_in[0];
  const float* wl1  = (const float*)d_in[1];
  const float* gl1  = (const float*)d_in[3];
  const float* bel1 = (const float*)d_in[4];
  const float* wl2  = (const float*)d_in[5];
  const float* gl2  = (const float*)d_in[7];
  const float* bel2 = (const float*)d_in[8];
  const float* wp1  = (const float*)d_in[9];
  const float* gp1  = (const float*)d_in[11];
  const float* bep1 = (const float*)d_in[12];
  const float* wp2  = (const float*)d_in[13];
  const float* gp2  = (const float*)d_in[15];
  const float* bep2 = (const float*)d_in[16];
  const float* wg   = (const float*)d_in[17];
  const float* gg   = (const float*)d_in[19];
  const float* beg  = (const float*)d_in[20];
  const float* W1   = (const float*)d_in[21];
  const float* as1  = (const float*)d_in[22];
  const float* ad1  = (const float*)d_in[23];
  const float* bb1  = (const float*)d_in[24];
  const float* W2   = (const float*)d_in[25];
  const float* as2  = (const float*)d_in[26];
  const float* ad2  = (const float*)d_in[27];
  const float* bb2  = (const float*)d_in[28];
  const float* Wo   = (const float*)d_in[29];
  const float* bo   = (const float*)d_in[30];
  const float* Wo2  = (const float*)d_in[31];
  const float* bo2  = (const float*)d_in[32];
  const int*   ei   = (const int*)d_in[33];

  const size_t STATIC_BYTES = 1250000;
  int nc = 1;
  while (nc < 8 && STATIC_BYTES + (size_t)1880*(NODES/nc) > ws_size) nc <<= 1;
  const int CB = B_/nc, CN = CB*N0_;
  int cbShift = 0; while ((1 << cbShift) < CB) cbShift++;
  const int cbMask = CB - 1;

  char* wsb = (char*)d_ws; size_t off = 0;
  auto alloc = [&](size_t nbytes)->void*{
    void* p = wsb + off; off = (off + nbytes + 255) & ~(size_t)255; return p;
  };
  int*   zbase  = (int*)  alloc(20080*sizeof(int));
  float* gsum   = (float*)zbase;
  float* gsq    = gsum + 40;
  int*   counts = zbase + 80;
  int*   cursor = counts + 10000;
  float* sA     = (float*)alloc(40*sizeof(float));
  float* sB     = (float*)alloc(40*sizeof(float));
  int*   offs   = (int*)  alloc(10001*sizeof(int));
  int*   srcl   = (int*)  alloc((size_t)NE_*sizeof(int));
  int*   perm   = (int*)  alloc((size_t)N0_*sizeof(int));
  u16*   W12T   = (u16*)  alloc((size_t)144*288*2);
  u16*   WoT    = (u16*)  alloc((size_t)144*320*2);
  float* va1s   = (float*)alloc(272*sizeof(float));
  float* va1d   = (float*)alloc(272*sizeof(float));
  float* v2ss   = (float*)alloc(272*sizeof(float));
  float* v2dd   = (float*)alloc(272*sizeof(float));
  float* ccv    = (float*)alloc(2*sizeof(float));
  float* b12    = (float*)alloc(136*sizeof(float));
  u16*   feat   = (u16*)  alloc((size_t)CN*160*2);
  u16*   featL  = (u16*)  alloc((size_t)CN*160*2);
  u16*   aggF   = (u16*)  alloc((size_t)CN*288*2);
  u16*   h2     = (u16*)  alloc((size_t)CN*144*2);
  u16*   g2l    = (u16*)  alloc((size_t)CN*160*2);
  float* asrc1  = (float*)alloc((size_t)CN*2*sizeof(float));
  float* adst1  = (float*)alloc((size_t)CN*2*sizeof(float));
  float* asrc2  = (float*)alloc((size_t)CN*sizeof(float));
  float* adst2  = (float*)alloc((size_t)CN*sizeof(float));

  k_setup<<<425,256,0,stream>>>(zbase, Wo, WoT, W1, W2, W12T,
                                as1, ad1, va1s, va1d, as2, ad2, bb1,
                                v2ss, v2dd, ccv, b12);

  k_bn_stats<<<625,256,0,stream>>>(x, wl1,wl2,wp1,wp2,wg, gsum, gsq);

  k_count  <<<666,256,0,stream>>>(ei, counts, gsum, gsq, sA, sB,
                                  gl1,gl2,gp1,gp2,gg, bel1,bel2,bep1,bep2,beg);
  k_scan   <<<1,1024,0,stream>>>(counts, offs);
  k_perm   <<<1,1024,0,stream>>>(counts, perm);
  k_scatter<<<665,256,0,stream>>>(ei, offs, cursor, srcl);

  const int gxm = (CN + 127)/128;     // MT=2: 128 rows/block
  const int gx2 = (CN + 127)/128;
  const int aggB = 1250*CB;
  for (int c = 0; c < nc; c++){
    const int base = c*CN;

    k_feat<<<gx2,256,0,stream>>>(x, wl1,wl2,wp1,wp2,wg, sA, sB, va1s, va1d,
                                 feat, featL, asrc1, adst1, base, CN);

    k_agg1<<<aggB,256,0,stream>>>(feat, asrc1, adst1, offs, srcl, perm, aggF,
                                  v2ss, v2dd, ccv, asrc2, adst2, cbMask, cbShift);

    k_mfma<2,9,0,9,3,0><<<gxm,256,0,stream>>>(aggF,288, (const u16*)0,0, W12T,288, h2,144, 0, b12, CN,
                                              (const float*)0,(const float*)0,(float*)0);

    k_agg2<<<aggB,256,0,stream>>>(h2,144, asrc2, adst2, offs, srcl, perm, bb2, g2l,160,
                                  cbMask, cbShift);

    k_mfma<2,5,5,9,2,0><<<gxm,256,0,stream>>>(g2l,160, featL,160, WoT,320, (u16*)0,0, 0, bo, CN,
                                              Wo2, bo2, (float*)d_out + base);
  }
}